// Round 2
// baseline (10090.436 us; speedup 1.0000x reference)
//
#include <hip/hip_runtime.h>
#include <hip/hip_bf16.h>
#include <math.h>

#define EMBED 768
#define QKVD 2304
#define HEADS 12
#define HD 64
#define HIDDEN 3072
#define NPATCH 196
#define SEQMAX 784
#define NB 8
#define IMGSZ 224
#define GRID 14
#define PATCH 16

typedef __hip_bfloat16 bf16;

__device__ __forceinline__ float b2f(bf16 v) { return __bfloat162float(v); }
__device__ __forceinline__ float geluf(float x) {
    return 0.5f * x * (1.0f + erff(x * 0.70710678118654752f));
}

// ---------------------------------------------------------------------------
// Dtype detection: read first 8192 uint16 halves of img0 as bf16. True bf16
// N(0,1) data never exceeds ~6; fp32 data read this way produces huge/NaN
// values with high probability. flag=1 => source buffers are fp32.
// ---------------------------------------------------------------------------
__global__ __launch_bounds__(256)
void detect_kernel(const unsigned short* __restrict__ raw, int* __restrict__ flag)
{
    __shared__ int bad;
    if (threadIdx.x == 0) bad = 0;
    __syncthreads();
    for (int i = threadIdx.x; i < 8192; i += 256) {
        unsigned int u = (unsigned int)raw[i] << 16;
        float v = __uint_as_float(u);
        if (!(fabsf(v) <= 1e4f)) bad = 1;   // catches Inf/NaN too; benign race
    }
    __syncthreads();
    if (threadIdx.x == 0) *flag = bad;
}

// Canonicalize an input array to fp32, branching on detected source dtype.
__global__ __launch_bounds__(256)
void convert_kernel(const void* __restrict__ src, float* __restrict__ dst,
                    int n, const int* __restrict__ flag)
{
    int f = *flag;
    for (int i = blockIdx.x * 256 + threadIdx.x; i < n; i += gridDim.x * 256) {
        dst[i] = f ? ((const float*)src)[i] : b2f(((const bf16*)src)[i]);
    }
}

// ---------------------------------------------------------------------------
// Generic GEMM: C[m,n] = sum_k A[m,k] * W[n,k] + bias[n] (+ add[m,n]) (gelu?)
// 64x64 tile, 256 threads, 4x4 microtile, fp32 accumulate.
// ---------------------------------------------------------------------------
__global__ __launch_bounds__(256)
void gemm_kernel(const float* __restrict__ A, const float* __restrict__ W,
                 const float* __restrict__ bias, const float* __restrict__ add,
                 float* __restrict__ C, int M, int N, int K,
                 int Ntok, int rowStride, int dogelu)
{
    __shared__ __align__(16) float As[16][68];
    __shared__ __align__(16) float Ws[16][68];
    int tid = threadIdx.x;
    int tx = tid & 15, ty = tid >> 4;
    int n0 = blockIdx.x * 64, m0 = blockIdx.y * 64;

    int lrow = tid >> 2;          // 0..63
    int lk   = (tid & 3) << 2;    // 0,4,8,12

    int am = m0 + lrow;
    bool aok = (am < M);
    const float* Arow = A;
    if (aok) {
        int pr = (am / Ntok) * rowStride + (am % Ntok);
        Arow = A + (size_t)pr * K;
    }
    int wn = n0 + lrow;
    const float* Wrow = (wn < N) ? (W + (size_t)wn * K) : nullptr;

    float acc[4][4] = {};

    for (int kk = 0; kk < K; kk += 16) {
        float4 av = make_float4(0.f, 0.f, 0.f, 0.f);
        if (aok) av = *(const float4*)(Arow + kk + lk);
        float4 wv = make_float4(0.f, 0.f, 0.f, 0.f);
        if (Wrow) wv = *(const float4*)(Wrow + kk + lk);
        __syncthreads();
        As[lk+0][lrow] = av.x; As[lk+1][lrow] = av.y;
        As[lk+2][lrow] = av.z; As[lk+3][lrow] = av.w;
        Ws[lk+0][lrow] = wv.x; Ws[lk+1][lrow] = wv.y;
        Ws[lk+2][lrow] = wv.z; Ws[lk+3][lrow] = wv.w;
        __syncthreads();
        #pragma unroll
        for (int k = 0; k < 16; ++k) {
            float4 a = *(const float4*)&As[k][ty << 2];
            float4 w = *(const float4*)&Ws[k][tx << 2];
            acc[0][0] += a.x*w.x; acc[0][1] += a.x*w.y; acc[0][2] += a.x*w.z; acc[0][3] += a.x*w.w;
            acc[1][0] += a.y*w.x; acc[1][1] += a.y*w.y; acc[1][2] += a.y*w.z; acc[1][3] += a.y*w.w;
            acc[2][0] += a.z*w.x; acc[2][1] += a.z*w.y; acc[2][2] += a.z*w.z; acc[2][3] += a.z*w.w;
            acc[3][0] += a.w*w.x; acc[3][1] += a.w*w.y; acc[3][2] += a.w*w.z; acc[3][3] += a.w*w.w;
        }
    }

    #pragma unroll
    for (int i = 0; i < 4; ++i) {
        int m = m0 + (ty << 2) + i;
        if (m >= M) continue;
        int pr = (m / Ntok) * rowStride + (m % Ntok);
        float* crow = C + (size_t)pr * N;
        const float* addrow = add ? (add + (size_t)pr * N) : nullptr;
        #pragma unroll
        for (int j = 0; j < 4; ++j) {
            int n = n0 + (tx << 2) + j;
            float v = acc[i][j] + bias[n];
            if (addrow) v += addrow[n];
            if (dogelu) v = geluf(v);
            crow[n] = v;
        }
    }
}

// ---------------------------------------------------------------------------
// LayerNorm over EMBED=768, one block (256 thr) per token. Buffer stride 784.
// ---------------------------------------------------------------------------
__global__ __launch_bounds__(256)
void ln_kernel(const float* __restrict__ src, float* __restrict__ dst,
               const float* __restrict__ g, const float* __restrict__ bta, int Ntok)
{
    __shared__ float red[256];
    int blk = blockIdx.x;
    int t = blk % Ntok, b = blk / Ntok;
    size_t row = ((size_t)b * SEQMAX + t) * EMBED;
    int tid = threadIdx.x;
    float v0 = src[row + tid], v1 = src[row + tid + 256], v2 = src[row + tid + 512];
    red[tid] = v0 + v1 + v2;
    __syncthreads();
    for (int off = 128; off; off >>= 1) { if (tid < off) red[tid] += red[tid + off]; __syncthreads(); }
    float mu = red[0] * (1.0f / EMBED);
    __syncthreads();
    float d0 = v0 - mu, d1 = v1 - mu, d2 = v2 - mu;
    red[tid] = d0*d0 + d1*d1 + d2*d2;
    __syncthreads();
    for (int off = 128; off; off >>= 1) { if (tid < off) red[tid] += red[tid + off]; __syncthreads(); }
    float rs = rsqrtf(red[0] * (1.0f / EMBED) + 1e-5f);
    dst[row + tid]       = d0 * rs * g[tid]       + bta[tid];
    dst[row + tid + 256] = d1 * rs * g[tid + 256] + bta[tid + 256];
    dst[row + tid + 512] = d2 * rs * g[tid + 512] + bta[tid + 512];
}

// ---------------------------------------------------------------------------
// Attention: one block per (b, head, query token). Softmax in LDS.
// ---------------------------------------------------------------------------
__global__ __launch_bounds__(256)
void attn_kernel(const float* __restrict__ QKV, float* __restrict__ O, int Ntok)
{
    __shared__ __align__(16) float qs[HD];
    __shared__ float sc[SEQMAX];
    __shared__ float red[256];
    __shared__ float part[4][HD];
    int blk = blockIdx.x;
    int t = blk % Ntok;
    int hb = blk / Ntok;
    int h = hb % HEADS, b = hb / HEADS;
    int tid = threadIdx.x;

    const float* qp = QKV + ((size_t)b * SEQMAX + t) * QKVD + h * HD;
    if (tid < HD) qs[tid] = qp[tid];
    __syncthreads();

    float lmax = -1e30f;
    for (int t2 = tid; t2 < Ntok; t2 += 256) {
        const float* kp = QKV + ((size_t)b * SEQMAX + t2) * QKVD + EMBED + h * HD;
        float d = 0.f;
        #pragma unroll
        for (int i = 0; i < HD; i += 4) {
            float4 k4 = *(const float4*)(kp + i);
            float4 q4 = *(const float4*)(qs + i);
            d += k4.x*q4.x + k4.y*q4.y + k4.z*q4.z + k4.w*q4.w;
        }
        d *= 0.125f;
        sc[t2] = d;
        lmax = fmaxf(lmax, d);
    }
    red[tid] = lmax;
    __syncthreads();
    for (int off = 128; off; off >>= 1) { if (tid < off) red[tid] = fmaxf(red[tid], red[tid + off]); __syncthreads(); }
    float m = red[0];
    __syncthreads();

    float lsum = 0.f;
    for (int t2 = tid; t2 < Ntok; t2 += 256) {
        float p = expf(sc[t2] - m);
        sc[t2] = p;
        lsum += p;
    }
    red[tid] = lsum;
    __syncthreads();
    for (int off = 128; off; off >>= 1) { if (tid < off) red[tid] += red[tid + off]; __syncthreads(); }
    float inv = 1.0f / red[0];

    int d = tid & 63, grp = tid >> 6;
    float acc = 0.f;
    for (int t2 = grp; t2 < Ntok; t2 += 4) {
        const float* vp = QKV + ((size_t)b * SEQMAX + t2) * QKVD + 2 * EMBED + h * HD;
        acc += sc[t2] * vp[d];
    }
    part[grp][d] = acc;
    __syncthreads();
    if (tid < HD) {
        float o = (part[0][tid] + part[1][tid] + part[2][tid] + part[3][tid]) * inv;
        O[((size_t)b * SEQMAX + t) * EMBED + h * HD + tid] = o;
    }
}

// ---------------------------------------------------------------------------
// im2row patch gather (dtype-adaptive source).
// ---------------------------------------------------------------------------
__global__ __launch_bounds__(256)
void patch_gather(const void* __restrict__ img, float* __restrict__ Ap,
                  const int* __restrict__ flag)
{
    int f = *flag;
    int idx = blockIdx.x * 256 + threadIdx.x;
    if (idx >= NB * NPATCH * EMBED) return;
    int col = idx % EMBED;
    int row = idx / EMBED;
    int t = row % NPATCH, b = row / NPATCH;
    int c = col >> 8;
    int pr = (col >> 4) & 15;
    int pc = col & 15;
    int gr = t / GRID, gc = t % GRID;
    size_t off = ((size_t)(b * 3 + c) * IMGSZ + gr * PATCH + pr) * IMGSZ + gc * PATCH + pc;
    Ap[idx] = f ? ((const float*)img)[off] : b2f(((const bf16*)img)[off]);
}

// Add positional encodings, scatter into X at sequence offset imgIdx*196.
__global__ __launch_bounds__(256)
void posadd_kernel(const float* __restrict__ PEO, const float* __restrict__ sp,
                   const float* __restrict__ ip, float* __restrict__ X, int imgIdx)
{
    int idx = blockIdx.x * 256 + threadIdx.x;
    if (idx >= NB * NPATCH * EMBED) return;
    int e = idx % EMBED;
    int row = idx / EMBED;
    int t = row % NPATCH, b = row / NPATCH;
    float pos = (e < 384) ? sp[t * 384 + e] : ip[imgIdx * 384 + (e - 384)];
    X[((size_t)b * SEQMAX + imgIdx * NPATCH + t) * EMBED + e] = PEO[idx] + pos;
}

// Mean over 784 tokens.
__global__ __launch_bounds__(768)
void mean_kernel(const float* __restrict__ H, float* __restrict__ Mn)
{
    int b = blockIdx.x;
    int e = threadIdx.x;
    float s = 0.f;
    for (int t = 0; t < SEQMAX; ++t) s += H[((size_t)b * SEQMAX + t) * EMBED + e];
    Mn[b * EMBED + e] = s * (1.0f / SEQMAX);
}

// Broadcast 16x16 patch image over the 14x14 grid (dtype-adaptive output).
__global__ __launch_bounds__(256)
void bcast_kernel(const float* __restrict__ P, void* __restrict__ out,
                  const int* __restrict__ flag)
{
    int f = *flag;
    int idx = blockIdx.x * 256 + threadIdx.x;
    if (idx >= NB * IMGSZ * IMGSZ) return;
    int c = idx % IMGSZ;
    int r = (idx / IMGSZ) % IMGSZ;
    int b = idx / (IMGSZ * IMGSZ);
    float v = P[b * 256 + (r & 15) * 16 + (c & 15)];
    if (f) ((float*)out)[idx] = v;
    else   ((bf16*)out)[idx] = __float2bfloat16(v);
}

// ---------------------------------------------------------------------------
extern "C" void kernel_launch(void* const* d_in, const int* in_sizes, int n_in,
                              void* d_out, int out_size, void* d_ws, size_t ws_size,
                              hipStream_t stream)
{
    (void)n_in; (void)out_size; (void)ws_size;
    const void* img[4] = {d_in[0], d_in[1], d_in[2], d_in[3]};

    float* ws = (float*)d_ws;
    int* flag = (int*)ws;
    float* arena = ws + 16;

    detect_kernel<<<1, 256, 0, stream>>>((const unsigned short*)d_in[0], flag);
    float* wptr[28];
    {
        float* p = arena;
        for (int i = 4; i < 28; ++i) {
            wptr[i] = p;
            int n = in_sizes[i];
            int g = (n + 255) / 256; if (g > 4096) g = 4096;
            convert_kernel<<<g, 256, 0, stream>>>(d_in[i], p, n, flag);
            p += n;
        }
        arena = p;
    }
    const float* pe_w      = wptr[4];
    const float* pe_b      = wptr[5];
    const float* sp        = wptr[6];
    const float* ip        = wptr[7];
    const float* ln_attn_g = wptr[8];
    const float* ln_attn_b = wptr[9];
    const float* qkv_w     = wptr[10];
    const float* qkv_b     = wptr[11];
    const float* proj_w    = wptr[12];
    const float* proj_b    = wptr[13];
    const float* ln1_g     = wptr[14];
    const float* ln1_b     = wptr[15];
    const float* fc1_w     = wptr[16];
    const float* fc1_b     = wptr[17];
    const float* fc2_w     = wptr[18];
    const float* fc2_b     = wptr[19];
    const float* ln2_g     = wptr[20];
    const float* ln2_b     = wptr[21];
    const float* final_g   = wptr[22];
    const float* final_b   = wptr[23];
    const float* head_w1   = wptr[24];
    const float* head_b1   = wptr[25];
    const float* head_w2   = wptr[26];
    const float* head_b2   = wptr[27];

    const size_t SEQ_ELEMS = (size_t)NB * SEQMAX * EMBED;
    float* X    = arena;
    float* H    = X + SEQ_ELEMS;
    float* O    = H + SEQ_ELEMS;
    float* BIG  = O + SEQ_ELEMS;
    float* MEAN = BIG + (size_t)NB * SEQMAX * HIDDEN;
    float* HH   = MEAN + NB * EMBED;
    float* PTCH = HH + NB * EMBED;
    float* PE   = BIG;
    float* PEO  = BIG + (size_t)NB * NPATCH * EMBED;

    const int nEmb = NB * NPATCH * EMBED;

    auto embed = [&](int i) {
        patch_gather<<<(nEmb + 255) / 256, 256, 0, stream>>>(img[i], PE, flag);
        dim3 g(EMBED / 64, (NB * NPATCH + 63) / 64);
        gemm_kernel<<<g, 256, 0, stream>>>(PE, pe_w + (size_t)i * EMBED * EMBED,
                                           pe_b + i * EMBED, nullptr, PEO,
                                           NB * NPATCH, EMBED, EMBED,
                                           NB * NPATCH, NB * NPATCH, 0);
        posadd_kernel<<<(nEmb + 255) / 256, 256, 0, stream>>>(PEO, sp, ip, X, i);
    };

    auto block = [&](int i, int Ntok) {
        int M = NB * Ntok;
        int gy = (M + 63) / 64;
        ln_kernel<<<M, 256, 0, stream>>>(X, H, ln_attn_g + i * EMBED, ln_attn_b + i * EMBED, Ntok);
        gemm_kernel<<<dim3(QKVD / 64, gy), 256, 0, stream>>>(
            H, qkv_w + (size_t)i * QKVD * EMBED, qkv_b + i * QKVD, nullptr, BIG,
            M, QKVD, EMBED, Ntok, SEQMAX, 0);
        attn_kernel<<<NB * HEADS * Ntok, 256, 0, stream>>>(BIG, O, Ntok);
        gemm_kernel<<<dim3(EMBED / 64, gy), 256, 0, stream>>>(
            O, proj_w + (size_t)i * EMBED * EMBED, proj_b + i * EMBED, X, X,
            M, EMBED, EMBED, Ntok, SEQMAX, 0);
        ln_kernel<<<M, 256, 0, stream>>>(X, H, ln1_g + i * EMBED, ln1_b + i * EMBED, Ntok);
        gemm_kernel<<<dim3(HIDDEN / 64, gy), 256, 0, stream>>>(
            H, fc1_w + (size_t)i * HIDDEN * EMBED, fc1_b + i * HIDDEN, nullptr, BIG,
            M, HIDDEN, EMBED, Ntok, SEQMAX, 1);
        gemm_kernel<<<dim3(EMBED / 64, gy), 256, 0, stream>>>(
            BIG, fc2_w + (size_t)i * EMBED * HIDDEN, fc2_b + i * EMBED, X, O,
            M, EMBED, HIDDEN, Ntok, SEQMAX, 0);
        ln_kernel<<<M, 256, 0, stream>>>(O, X, ln2_g + i * EMBED, ln2_b + i * EMBED, Ntok);
    };

    embed(0);
    embed(1);
    block(0, 392);
    embed(2);
    block(1, 588);
    embed(3);
    block(2, 784);

    ln_kernel<<<NB * SEQMAX, 256, 0, stream>>>(X, H, final_g, final_b, SEQMAX);
    mean_kernel<<<NB, 768, 0, stream>>>(H, MEAN);
    gemm_kernel<<<dim3(EMBED / 64, 1), 256, 0, stream>>>(
        MEAN, head_w1, head_b1, nullptr, HH, NB, EMBED, EMBED, NB, NB, 1);
    gemm_kernel<<<dim3(256 / 64, 1), 256, 0, stream>>>(
        HH, head_w2, head_b2, nullptr, PTCH, NB, 256, EMBED, NB, NB, 0);
    bcast_kernel<<<(NB * IMGSZ * IMGSZ + 255) / 256, 256, 0, stream>>>(PTCH, d_out, flag);
}

// Round 3
// 4418.417 us; speedup vs baseline: 2.2837x; 2.2837x over previous
//
#include <hip/hip_runtime.h>
#include <hip/hip_bf16.h>
#include <math.h>

#define EMBED 768
#define QKVD 2304
#define HEADS 12
#define HD 64
#define HIDDEN 3072
#define NPATCH 196
#define SEQMAX 784
#define NB 8
#define IMGSZ 224
#define GRID 14
#define PATCH 16

typedef __hip_bfloat16 bf16;

__device__ __forceinline__ float b2f(bf16 v) { return __bfloat162float(v); }
__device__ __forceinline__ float geluf(float x) {
    return 0.5f * x * (1.0f + erff(x * 0.70710678118654752f));
}

// ---------------------------------------------------------------------------
// Dtype detection (bf16 vs fp32 inputs) — see round 1.
// ---------------------------------------------------------------------------
__global__ __launch_bounds__(256)
void detect_kernel(const unsigned short* __restrict__ raw, int* __restrict__ flag)
{
    __shared__ int bad;
    if (threadIdx.x == 0) bad = 0;
    __syncthreads();
    for (int i = threadIdx.x; i < 8192; i += 256) {
        unsigned int u = (unsigned int)raw[i] << 16;
        float v = __uint_as_float(u);
        if (!(fabsf(v) <= 1e4f)) bad = 1;
    }
    __syncthreads();
    if (threadIdx.x == 0) *flag = bad;
}

__global__ __launch_bounds__(256)
void convert_kernel(const void* __restrict__ src, float* __restrict__ dst,
                    int n, const int* __restrict__ flag)
{
    int f = *flag;
    for (int i = blockIdx.x * 256 + threadIdx.x; i < n; i += gridDim.x * 256) {
        dst[i] = f ? ((const float*)src)[i] : b2f(((const bf16*)src)[i]);
    }
}

// ---------------------------------------------------------------------------
// Generic GEMM: C[m,n] = sum_k A[m,k] * W[n,k] + bias[n] (+ add[m,n]) (gelu?)
// 64x64 tile, 256 threads, 4x4 microtile, fp32 accumulate.
// ---------------------------------------------------------------------------
__global__ __launch_bounds__(256)
void gemm_kernel(const float* __restrict__ A, const float* __restrict__ W,
                 const float* __restrict__ bias, const float* __restrict__ add,
                 float* __restrict__ C, int M, int N, int K,
                 int Ntok, int rowStride, int dogelu)
{
    __shared__ __align__(16) float As[16][68];
    __shared__ __align__(16) float Ws[16][68];
    int tid = threadIdx.x;
    int tx = tid & 15, ty = tid >> 4;
    int n0 = blockIdx.x * 64, m0 = blockIdx.y * 64;

    int lrow = tid >> 2;
    int lk   = (tid & 3) << 2;

    int am = m0 + lrow;
    bool aok = (am < M);
    const float* Arow = A;
    if (aok) {
        int pr = (am / Ntok) * rowStride + (am % Ntok);
        Arow = A + (size_t)pr * K;
    }
    int wn = n0 + lrow;
    const float* Wrow = (wn < N) ? (W + (size_t)wn * K) : nullptr;

    float acc[4][4] = {};

    for (int kk = 0; kk < K; kk += 16) {
        float4 av = make_float4(0.f, 0.f, 0.f, 0.f);
        if (aok) av = *(const float4*)(Arow + kk + lk);
        float4 wv = make_float4(0.f, 0.f, 0.f, 0.f);
        if (Wrow) wv = *(const float4*)(Wrow + kk + lk);
        __syncthreads();
        As[lk+0][lrow] = av.x; As[lk+1][lrow] = av.y;
        As[lk+2][lrow] = av.z; As[lk+3][lrow] = av.w;
        Ws[lk+0][lrow] = wv.x; Ws[lk+1][lrow] = wv.y;
        Ws[lk+2][lrow] = wv.z; Ws[lk+3][lrow] = wv.w;
        __syncthreads();
        #pragma unroll
        for (int k = 0; k < 16; ++k) {
            float4 a = *(const float4*)&As[k][ty << 2];
            float4 w = *(const float4*)&Ws[k][tx << 2];
            acc[0][0] += a.x*w.x; acc[0][1] += a.x*w.y; acc[0][2] += a.x*w.z; acc[0][3] += a.x*w.w;
            acc[1][0] += a.y*w.x; acc[1][1] += a.y*w.y; acc[1][2] += a.y*w.z; acc[1][3] += a.y*w.w;
            acc[2][0] += a.z*w.x; acc[2][1] += a.z*w.y; acc[2][2] += a.z*w.z; acc[2][3] += a.z*w.w;
            acc[3][0] += a.w*w.x; acc[3][1] += a.w*w.y; acc[3][2] += a.w*w.z; acc[3][3] += a.w*w.w;
        }
    }

    #pragma unroll
    for (int i = 0; i < 4; ++i) {
        int m = m0 + (ty << 2) + i;
        if (m >= M) continue;
        int pr = (m / Ntok) * rowStride + (m % Ntok);
        float* crow = C + (size_t)pr * N;
        const float* addrow = add ? (add + (size_t)pr * N) : nullptr;
        #pragma unroll
        for (int j = 0; j < 4; ++j) {
            int n = n0 + (tx << 2) + j;
            float v = acc[i][j] + bias[n];
            if (addrow) v += addrow[n];
            if (dogelu) v = geluf(v);
            crow[n] = v;
        }
    }
}

// ---------------------------------------------------------------------------
// LayerNorm over EMBED=768, one block (256 thr) per token. Buffer stride 784.
// ---------------------------------------------------------------------------
__global__ __launch_bounds__(256)
void ln_kernel(const float* __restrict__ src, float* __restrict__ dst,
               const float* __restrict__ g, const float* __restrict__ bta, int Ntok)
{
    __shared__ float red[256];
    int blk = blockIdx.x;
    int t = blk % Ntok, b = blk / Ntok;
    size_t row = ((size_t)b * SEQMAX + t) * EMBED;
    int tid = threadIdx.x;
    float v0 = src[row + tid], v1 = src[row + tid + 256], v2 = src[row + tid + 512];
    red[tid] = v0 + v1 + v2;
    __syncthreads();
    for (int off = 128; off; off >>= 1) { if (tid < off) red[tid] += red[tid + off]; __syncthreads(); }
    float mu = red[0] * (1.0f / EMBED);
    __syncthreads();
    float d0 = v0 - mu, d1 = v1 - mu, d2 = v2 - mu;
    red[tid] = d0*d0 + d1*d1 + d2*d2;
    __syncthreads();
    for (int off = 128; off; off >>= 1) { if (tid < off) red[tid] += red[tid + off]; __syncthreads(); }
    float rs = rsqrtf(red[0] * (1.0f / EMBED) + 1e-5f);
    dst[row + tid]       = d0 * rs * g[tid]       + bta[tid];
    dst[row + tid + 256] = d1 * rs * g[tid + 256] + bta[tid + 256];
    dst[row + tid + 512] = d2 * rs * g[tid + 512] + bta[tid + 512];
}

// ---------------------------------------------------------------------------
// QKV split: BIG [b*784+t][2304] -> Qh/Kh/Vh [(b*12+h)*784 + t][64]
// ---------------------------------------------------------------------------
__global__ __launch_bounds__(256)
void qkv_split(const float* __restrict__ QKV, float* __restrict__ Qh,
               float* __restrict__ Kh, float* __restrict__ Vh, int Ntok)
{
    int idx = blockIdx.x * 256 + threadIdx.x;
    int total = NB * Ntok * (QKVD / 4);
    if (idx >= total) return;
    int c4 = (idx % (QKVD / 4)) * 4;
    int row = idx / (QKVD / 4);
    int t = row % Ntok, b = row / Ntok;
    float4 v = *(const float4*)(QKV + ((size_t)b * SEQMAX + t) * QKVD + c4);
    int which = c4 / EMBED;
    int h = (c4 % EMBED) / HD;
    int d = c4 % HD;
    float* dst = which == 0 ? Qh : which == 1 ? Kh : Vh;
    *(float4*)(dst + ((size_t)(b * HEADS + h) * SEQMAX + t) * HD + d) = v;
}

// ---------------------------------------------------------------------------
// Flash attention: block = (b*h, 64-query tile). 64-row K/V tiles in LDS,
// 4x4 register microtiles for S=QK^T and O+=PV, online softmax via shfl.
// ---------------------------------------------------------------------------
__global__ __launch_bounds__(256)
void flash_kernel(const float* __restrict__ Qh, const float* __restrict__ Kh,
                  const float* __restrict__ Vh, float* __restrict__ O, int Ntok)
{
    __shared__ __align__(16) float Qs[64][68];
    __shared__ __align__(16) float KPs[64][68];   // K tile, then reused as P^T
    __shared__ __align__(16) float Vs[64][68];
    int bh = blockIdx.x;
    int b = bh / HEADS, h = bh % HEADS;
    int t0 = blockIdx.y * 64;
    int tid = threadIdx.x;
    int tx = tid & 15, ty = tid >> 4;

    const float* Qb = Qh + (size_t)bh * SEQMAX * HD;
    const float* Kb = Kh + (size_t)bh * SEQMAX * HD;
    const float* Vb = Vh + (size_t)bh * SEQMAX * HD;

    // load Q tile (zero-padded beyond Ntok)
    for (int e = tid; e < 64 * 16; e += 256) {
        int r = e >> 4, c4 = (e & 15) << 2;
        float4 v = make_float4(0.f, 0.f, 0.f, 0.f);
        if (t0 + r < Ntok) v = *(const float4*)(Qb + (size_t)(t0 + r) * HD + c4);
        *(float4*)&Qs[r][c4] = v;
    }

    float m[4], l[4], Oa[4][4];
    #pragma unroll
    for (int i = 0; i < 4; ++i) {
        m[i] = -1e30f; l[i] = 0.f;
        #pragma unroll
        for (int j = 0; j < 4; ++j) Oa[i][j] = 0.f;
    }

    for (int k0 = 0; k0 < Ntok; k0 += 64) {
        __syncthreads();   // protect KPs/Vs from previous iteration's PV
        for (int e = tid; e < 64 * 16; e += 256) {
            int r = e >> 4, c4 = (e & 15) << 2;
            float4 kv = make_float4(0.f, 0.f, 0.f, 0.f);
            float4 vv = make_float4(0.f, 0.f, 0.f, 0.f);
            if (k0 + r < Ntok) {
                kv = *(const float4*)(Kb + (size_t)(k0 + r) * HD + c4);
                vv = *(const float4*)(Vb + (size_t)(k0 + r) * HD + c4);
            }
            *(float4*)&KPs[r][c4] = kv;
            *(float4*)&Vs[r][c4] = vv;
        }
        __syncthreads();

        // S = Q K^T, 4x4 per thread: rows 4ty+ii, cols 4tx+jj
        float S[4][4] = {};
        for (int d = 0; d < HD; d += 4) {
            float4 q[4], kk[4];
            #pragma unroll
            for (int ii = 0; ii < 4; ++ii) q[ii] = *(const float4*)&Qs[4*ty+ii][d];
            #pragma unroll
            for (int jj = 0; jj < 4; ++jj) kk[jj] = *(const float4*)&KPs[4*tx+jj][d];
            #pragma unroll
            for (int ii = 0; ii < 4; ++ii)
                #pragma unroll
                for (int jj = 0; jj < 4; ++jj)
                    S[ii][jj] += q[ii].x*kk[jj].x + q[ii].y*kk[jj].y
                               + q[ii].z*kk[jj].z + q[ii].w*kk[jj].w;
        }
        #pragma unroll
        for (int ii = 0; ii < 4; ++ii)
            #pragma unroll
            for (int jj = 0; jj < 4; ++jj) {
                float s = S[ii][jj] * 0.125f;
                S[ii][jj] = (k0 + 4*tx + jj < Ntok) ? s : -1e30f;
            }

        // online softmax: row reductions across the 16 tx lanes
        #pragma unroll
        for (int ii = 0; ii < 4; ++ii) {
            float rm = fmaxf(fmaxf(S[ii][0], S[ii][1]), fmaxf(S[ii][2], S[ii][3]));
            rm = fmaxf(rm, __shfl_xor(rm, 1));
            rm = fmaxf(rm, __shfl_xor(rm, 2));
            rm = fmaxf(rm, __shfl_xor(rm, 4));
            rm = fmaxf(rm, __shfl_xor(rm, 8));
            float mnew = fmaxf(m[ii], rm);
            float alpha = __expf(m[ii] - mnew);
            m[ii] = mnew;
            float s0 = 0.f;
            #pragma unroll
            for (int jj = 0; jj < 4; ++jj) {
                float p = __expf(S[ii][jj] - mnew);
                S[ii][jj] = p; s0 += p;
            }
            s0 += __shfl_xor(s0, 1); s0 += __shfl_xor(s0, 2);
            s0 += __shfl_xor(s0, 4); s0 += __shfl_xor(s0, 8);
            l[ii] = l[ii] * alpha + s0;
            #pragma unroll
            for (int jj = 0; jj < 4; ++jj) Oa[ii][jj] *= alpha;
        }

        __syncthreads();   // before overwriting KPs with P^T
        #pragma unroll
        for (int ii = 0; ii < 4; ++ii)
            #pragma unroll
            for (int jj = 0; jj < 4; ++jj)
                KPs[4*tx+jj][4*ty+ii] = S[ii][jj];
        __syncthreads();

        // O += P V : P^T in KPs[kc][i], V in Vs[kc][d]
        for (int kc = 0; kc < 64; ++kc) {
            float4 pp = *(const float4*)&KPs[kc][4*ty];
            float4 vv = *(const float4*)&Vs[kc][4*tx];
            Oa[0][0] += pp.x*vv.x; Oa[0][1] += pp.x*vv.y; Oa[0][2] += pp.x*vv.z; Oa[0][3] += pp.x*vv.w;
            Oa[1][0] += pp.y*vv.x; Oa[1][1] += pp.y*vv.y; Oa[1][2] += pp.y*vv.z; Oa[1][3] += pp.y*vv.w;
            Oa[2][0] += pp.z*vv.x; Oa[2][1] += pp.z*vv.y; Oa[2][2] += pp.z*vv.z; Oa[2][3] += pp.z*vv.w;
            Oa[3][0] += pp.w*vv.x; Oa[3][1] += pp.w*vv.y; Oa[3][2] += pp.w*vv.z; Oa[3][3] += pp.w*vv.w;
        }
    }

    #pragma unroll
    for (int ii = 0; ii < 4; ++ii) {
        int t = t0 + 4*ty + ii;
        if (t >= Ntok) continue;
        float inv = 1.0f / l[ii];
        float4 o = make_float4(Oa[ii][0]*inv, Oa[ii][1]*inv, Oa[ii][2]*inv, Oa[ii][3]*inv);
        *(float4*)(O + ((size_t)b * SEQMAX + t) * EMBED + h * HD + 4*tx) = o;
    }
}

// ---------------------------------------------------------------------------
__global__ __launch_bounds__(256)
void patch_gather(const void* __restrict__ img, float* __restrict__ Ap,
                  const int* __restrict__ flag)
{
    int f = *flag;
    int idx = blockIdx.x * 256 + threadIdx.x;
    if (idx >= NB * NPATCH * EMBED) return;
    int col = idx % EMBED;
    int row = idx / EMBED;
    int t = row % NPATCH, b = row / NPATCH;
    int c = col >> 8;
    int pr = (col >> 4) & 15;
    int pc = col & 15;
    int gr = t / GRID, gc = t % GRID;
    size_t off = ((size_t)(b * 3 + c) * IMGSZ + gr * PATCH + pr) * IMGSZ + gc * PATCH + pc;
    Ap[idx] = f ? ((const float*)img)[off] : b2f(((const bf16*)img)[off]);
}

__global__ __launch_bounds__(256)
void posadd_kernel(const float* __restrict__ PEO, const float* __restrict__ sp,
                   const float* __restrict__ ip, float* __restrict__ X, int imgIdx)
{
    int idx = blockIdx.x * 256 + threadIdx.x;
    if (idx >= NB * NPATCH * EMBED) return;
    int e = idx % EMBED;
    int row = idx / EMBED;
    int t = row % NPATCH, b = row / NPATCH;
    float pos = (e < 384) ? sp[t * 384 + e] : ip[imgIdx * 384 + (e - 384)];
    X[((size_t)b * SEQMAX + imgIdx * NPATCH + t) * EMBED + e] = PEO[idx] + pos;
}

__global__ __launch_bounds__(768)
void mean_kernel(const float* __restrict__ H, float* __restrict__ Mn)
{
    int b = blockIdx.x;
    int e = threadIdx.x;
    float s = 0.f;
    for (int t = 0; t < SEQMAX; ++t) s += H[((size_t)b * SEQMAX + t) * EMBED + e];
    Mn[b * EMBED + e] = s * (1.0f / SEQMAX);
}

__global__ __launch_bounds__(256)
void bcast_kernel(const float* __restrict__ P, void* __restrict__ out,
                  const int* __restrict__ flag)
{
    int f = *flag;
    int idx = blockIdx.x * 256 + threadIdx.x;
    if (idx >= NB * IMGSZ * IMGSZ) return;
    int c = idx % IMGSZ;
    int r = (idx / IMGSZ) % IMGSZ;
    int b = idx / (IMGSZ * IMGSZ);
    float v = P[b * 256 + (r & 15) * 16 + (c & 15)];
    if (f) ((float*)out)[idx] = v;
    else   ((bf16*)out)[idx] = __float2bfloat16(v);
}

// ---------------------------------------------------------------------------
extern "C" void kernel_launch(void* const* d_in, const int* in_sizes, int n_in,
                              void* d_out, int out_size, void* d_ws, size_t ws_size,
                              hipStream_t stream)
{
    (void)n_in; (void)out_size; (void)ws_size;
    const void* img[4] = {d_in[0], d_in[1], d_in[2], d_in[3]};

    float* ws = (float*)d_ws;
    int* flag = (int*)ws;
    float* arena = ws + 16;

    detect_kernel<<<1, 256, 0, stream>>>((const unsigned short*)d_in[0], flag);
    float* wptr[28];
    {
        float* p = arena;
        for (int i = 4; i < 28; ++i) {
            wptr[i] = p;
            int n = in_sizes[i];
            int g = (n + 255) / 256; if (g > 4096) g = 4096;
            convert_kernel<<<g, 256, 0, stream>>>(d_in[i], p, n, flag);
            p += n;
        }
        arena = p;
    }
    const float* pe_w      = wptr[4];
    const float* pe_b      = wptr[5];
    const float* sp        = wptr[6];
    const float* ip        = wptr[7];
    const float* ln_attn_g = wptr[8];
    const float* ln_attn_b = wptr[9];
    const float* qkv_w     = wptr[10];
    const float* qkv_b     = wptr[11];
    const float* proj_w    = wptr[12];
    const float* proj_b    = wptr[13];
    const float* ln1_g     = wptr[14];
    const float* ln1_b     = wptr[15];
    const float* fc1_w     = wptr[16];
    const float* fc1_b     = wptr[17];
    const float* fc2_w     = wptr[18];
    const float* fc2_b     = wptr[19];
    const float* ln2_g     = wptr[20];
    const float* ln2_b     = wptr[21];
    const float* final_g   = wptr[22];
    const float* final_b   = wptr[23];
    const float* head_w1   = wptr[24];
    const float* head_b1   = wptr[25];
    const float* head_w2   = wptr[26];
    const float* head_b2   = wptr[27];

    const size_t SEQ_ELEMS = (size_t)NB * SEQMAX * EMBED;     // 4,816,896
    float* X    = arena;
    float* H    = X + SEQ_ELEMS;
    float* O    = H + SEQ_ELEMS;
    float* BIG  = O + SEQ_ELEMS;                              // 19.27M floats
    float* MEAN = BIG + (size_t)NB * SEQMAX * HIDDEN;
    float* HH   = MEAN + NB * EMBED;
    float* PTCH = HH + NB * EMBED;
    float* PE   = BIG;
    float* PEO  = BIG + (size_t)NB * NPATCH * EMBED;

    // attention aliases (all dead regions at time of use):
    float* Qh   = O;                                          // O dead pre-attn
    float* Kh   = H;                                          // H dead post-QKV gemm
    float* Vh   = BIG + (size_t)NB * SEQMAX * QKVD;           // BIG tail (19.27M-14.45M)
    float* Oatt = BIG;                                        // QKV output dead post-split

    const int nEmb = NB * NPATCH * EMBED;

    auto embed = [&](int i) {
        patch_gather<<<(nEmb + 255) / 256, 256, 0, stream>>>(img[i], PE, flag);
        dim3 g(EMBED / 64, (NB * NPATCH + 63) / 64);
        gemm_kernel<<<g, 256, 0, stream>>>(PE, pe_w + (size_t)i * EMBED * EMBED,
                                           pe_b + i * EMBED, nullptr, PEO,
                                           NB * NPATCH, EMBED, EMBED,
                                           NB * NPATCH, NB * NPATCH, 0);
        posadd_kernel<<<(nEmb + 255) / 256, 256, 0, stream>>>(PEO, sp, ip, X, i);
    };

    auto block = [&](int i, int Ntok) {
        int M = NB * Ntok;
        int gy = (M + 63) / 64;
        ln_kernel<<<M, 256, 0, stream>>>(X, H, ln_attn_g + i * EMBED, ln_attn_b + i * EMBED, Ntok);
        gemm_kernel<<<dim3(QKVD / 64, gy), 256, 0, stream>>>(
            H, qkv_w + (size_t)i * QKVD * EMBED, qkv_b + i * QKVD, nullptr, BIG,
            M, QKVD, EMBED, Ntok, SEQMAX, 0);
        int tot4 = NB * Ntok * (QKVD / 4);
        qkv_split<<<(tot4 + 255) / 256, 256, 0, stream>>>(BIG, Qh, Kh, Vh, Ntok);
        dim3 fg(NB * HEADS, (Ntok + 63) / 64);
        flash_kernel<<<fg, 256, 0, stream>>>(Qh, Kh, Vh, Oatt, Ntok);
        gemm_kernel<<<dim3(EMBED / 64, gy), 256, 0, stream>>>(
            Oatt, proj_w + (size_t)i * EMBED * EMBED, proj_b + i * EMBED, X, X,
            M, EMBED, EMBED, Ntok, SEQMAX, 0);
        ln_kernel<<<M, 256, 0, stream>>>(X, H, ln1_g + i * EMBED, ln1_b + i * EMBED, Ntok);
        gemm_kernel<<<dim3(HIDDEN / 64, gy), 256, 0, stream>>>(
            H, fc1_w + (size_t)i * HIDDEN * EMBED, fc1_b + i * HIDDEN, nullptr, BIG,
            M, HIDDEN, EMBED, Ntok, SEQMAX, 1);
        gemm_kernel<<<dim3(EMBED / 64, gy), 256, 0, stream>>>(
            BIG, fc2_w + (size_t)i * EMBED * HIDDEN, fc2_b + i * EMBED, X, O,
            M, EMBED, HIDDEN, Ntok, SEQMAX, 0);
        ln_kernel<<<M, 256, 0, stream>>>(O, X, ln2_g + i * EMBED, ln2_b + i * EMBED, Ntok);
    };

    embed(0);
    embed(1);
    block(0, 392);
    embed(2);
    block(1, 588);
    embed(3);
    block(2, 784);

    ln_kernel<<<NB * SEQMAX, 256, 0, stream>>>(X, H, final_g, final_b, SEQMAX);
    mean_kernel<<<NB, 768, 0, stream>>>(H, MEAN);
    gemm_kernel<<<dim3(EMBED / 64, 1), 256, 0, stream>>>(
        MEAN, head_w1, head_b1, nullptr, HH, NB, EMBED, EMBED, NB, NB, 1);
    gemm_kernel<<<dim3(256 / 64, 1), 256, 0, stream>>>(
        HH, head_w2, head_b2, nullptr, PTCH, NB, 256, EMBED, NB, NB, 0);
    bcast_kernel<<<(NB * IMGSZ * IMGSZ + 255) / 256, 256, 0, stream>>>(PTCH, d_out, flag);
}

// Round 4
// 2096.569 us; speedup vs baseline: 4.8128x; 2.1075x over previous
//
#include <hip/hip_runtime.h>
#include <hip/hip_bf16.h>
#include <math.h>

#define EMBED 768
#define QKVD 2304
#define HEADS 12
#define HD 64
#define HIDDEN 3072
#define NPATCH 196
#define SEQMAX 784
#define NB 8
#define IMGSZ 224
#define GRID 14
#define PATCH 16

typedef __hip_bfloat16 bf16;
typedef __attribute__((ext_vector_type(8))) short short8;
typedef __attribute__((ext_vector_type(4))) float f32x4;

__device__ __forceinline__ float b2f(bf16 v) { return __bfloat162float(v); }
__device__ __forceinline__ float geluf(float x) {
    return 0.5f * x * (1.0f + erff(x * 0.70710678118654752f));
}

// async global->LDS, 16B per lane. LDS dest is wave-uniform base + lane*16.
__device__ __forceinline__ void async16(const bf16* g, bf16* l) {
    __builtin_amdgcn_global_load_lds(
        (const __attribute__((address_space(1))) unsigned int*)g,
        (__attribute__((address_space(3))) unsigned int*)l,
        16, 0, 0);
}

// ---------------------------------------------------------------------------
// Dtype detection (bf16 vs fp32 inputs).
// ---------------------------------------------------------------------------
__global__ __launch_bounds__(256)
void detect_kernel(const unsigned short* __restrict__ raw, int* __restrict__ flag)
{
    __shared__ int bad;
    if (threadIdx.x == 0) bad = 0;
    __syncthreads();
    for (int i = threadIdx.x; i < 8192; i += 256) {
        unsigned int u = (unsigned int)raw[i] << 16;
        float v = __uint_as_float(u);
        if (!(fabsf(v) <= 1e4f)) bad = 1;
    }
    __syncthreads();
    if (threadIdx.x == 0) *flag = bad;
}

__global__ __launch_bounds__(256)
void convert_f32(const void* __restrict__ src, float* __restrict__ dst,
                 int n, const int* __restrict__ flag)
{
    int f = *flag;
    for (int i = blockIdx.x * 256 + threadIdx.x; i < n; i += gridDim.x * 256)
        dst[i] = f ? ((const float*)src)[i] : b2f(((const bf16*)src)[i]);
}

__global__ __launch_bounds__(256)
void convert_bf16(const void* __restrict__ src, bf16* __restrict__ dst,
                  int n, const int* __restrict__ flag)
{
    int f = *flag;
    for (int i = blockIdx.x * 256 + threadIdx.x; i < n; i += gridDim.x * 256)
        dst[i] = f ? __float2bfloat16(((const float*)src)[i]) : ((const bf16*)src)[i];
}

// ---------------------------------------------------------------------------
// MFMA bf16 GEMM: C[m,n] = sum_k A[m,k]*W[n,k] + bias[n], 128x128 tile, BK=32.
// 4 waves; wave computes 64x64 via 4x4 grid of mfma_f32_16x16x32_bf16.
// A rows remapped (m/Ntok)*rowStride + m%Ntok. N must be multiple of 128? no:
// N multiple of 128 required (all call sites satisfy: 768/2304/3072).
// mode: 0 = fp32 out; 1 = fp32 out + residual add; 2 = bf16 out + gelu;
//       3 = qkv head-split to Qh/Kh/Vh (fp32).
// ---------------------------------------------------------------------------
__global__ __launch_bounds__(256)
void mfma_gemm(const bf16* __restrict__ A, const bf16* __restrict__ W,
               const float* __restrict__ bias, const float* __restrict__ add,
               float* __restrict__ outF, bf16* __restrict__ outB,
               float* __restrict__ Qh, float* __restrict__ Kh, float* __restrict__ Vh,
               int M, int N, int K, int Ntok, int rowStride, int mode)
{
    __shared__ __align__(16) bf16 As[128 * 32];
    __shared__ __align__(16) bf16 Bs[128 * 32];
    int tid = threadIdx.x;
    int lane = tid & 63;
    int wave = tid >> 6;
    int wm = wave & 1, wn = wave >> 1;
    int m0 = blockIdx.y * 128, n0 = blockIdx.x * 128;

    // staging: wave stages rows [32w,32w+32) of both tiles; 2 loads each of 16
    // rows (lane: row = lr = lane/4, chunk = lane%4 -> 8 bf16 = 16B).
    int lr = lane >> 2;
    int lc = lane & 3;
    int ar0 = 32 * wave + lr;
    int ar1 = ar0 + 16;
    int ma0 = m0 + ar0; if (ma0 >= M) ma0 = M - 1;
    int ma1 = m0 + ar1; if (ma1 >= M) ma1 = M - 1;
    const bf16* aSrc0 = A + (size_t)((ma0 / Ntok) * rowStride + ma0 % Ntok) * K + lc * 8;
    const bf16* aSrc1 = A + (size_t)((ma1 / Ntok) * rowStride + ma1 % Ntok) * K + lc * 8;
    const bf16* bSrc0 = W + (size_t)(n0 + ar0) * K + lc * 8;
    const bf16* bSrc1 = W + (size_t)(n0 + ar1) * K + lc * 8;
    bf16* aDst0 = As + (32 * wave) * 32;
    bf16* aDst1 = As + (32 * wave + 16) * 32;
    bf16* bDst0 = Bs + (32 * wave) * 32;
    bf16* bDst1 = Bs + (32 * wave + 16) * 32;

    // fragment read addresses: a: row = wm*64 + mi*16 + (lane&15), k = (lane>>4)*8
    int fr = lane & 15;
    int fq = lane >> 4;
    const bf16* aRead = As + (wm * 64 + fr) * 32 + fq * 8;
    const bf16* bRead = Bs + (wn * 64 + fr) * 32 + fq * 8;

    f32x4 acc[4][4] = {};

    for (int kk = 0; kk < K; kk += 32) {
        __syncthreads();
        async16(aSrc0, aDst0);
        async16(aSrc1, aDst1);
        async16(bSrc0, bDst0);
        async16(bSrc1, bDst1);
        aSrc0 += 32; aSrc1 += 32; bSrc0 += 32; bSrc1 += 32;
        __builtin_amdgcn_s_waitcnt(0xF70);   // vmcnt(0), ignore exp/lgkm
        __syncthreads();
        short8 af[4], bfr[4];
        #pragma unroll
        for (int mi = 0; mi < 4; ++mi) af[mi] = *(const short8*)(aRead + mi * 16 * 32);
        #pragma unroll
        for (int ni = 0; ni < 4; ++ni) bfr[ni] = *(const short8*)(bRead + ni * 16 * 32);
        #pragma unroll
        for (int mi = 0; mi < 4; ++mi)
            #pragma unroll
            for (int ni = 0; ni < 4; ++ni)
                acc[mi][ni] = __builtin_amdgcn_mfma_f32_16x16x32_bf16(
                    af[mi], bfr[ni], acc[mi][ni], 0, 0, 0);
    }

    // epilogue: C/D layout col = lane&15, row = (lane>>4)*4 + r
    #pragma unroll
    for (int mi = 0; mi < 4; ++mi) {
        #pragma unroll
        for (int ni = 0; ni < 4; ++ni) {
            int n = n0 + wn * 64 + ni * 16 + fr;
            float bs = bias[n];
            #pragma unroll
            for (int r = 0; r < 4; ++r) {
                int m = m0 + wm * 64 + mi * 16 + fq * 4 + r;
                if (m >= M) continue;
                int bidx = m / Ntok, t = m - bidx * Ntok;
                size_t pr = (size_t)bidx * rowStride + t;
                float v = acc[mi][ni][r] + bs;
                if (mode == 0) {
                    outF[pr * N + n] = v;
                } else if (mode == 1) {
                    outF[pr * N + n] = v + add[pr * N + n];
                } else if (mode == 2) {
                    outB[pr * N + n] = __float2bfloat16(geluf(v));
                } else {
                    int which = n >= 1536 ? 2 : (n >= 768 ? 1 : 0);
                    int nn = n - which * 768;
                    int hh = nn >> 6, d = nn & 63;
                    float* dst = which == 0 ? Qh : which == 1 ? Kh : Vh;
                    dst[((size_t)(bidx * HEADS + hh) * SEQMAX + t) * HD + d] = v;
                }
            }
        }
    }
}

// ---------------------------------------------------------------------------
// Legacy fp32 GEMM (head only; tiny M).
// ---------------------------------------------------------------------------
__global__ __launch_bounds__(256)
void gemm_kernel(const float* __restrict__ A, const float* __restrict__ W,
                 const float* __restrict__ bias, const float* __restrict__ add,
                 float* __restrict__ C, int M, int N, int K,
                 int Ntok, int rowStride, int dogelu)
{
    __shared__ __align__(16) float As[16][68];
    __shared__ __align__(16) float Ws[16][68];
    int tid = threadIdx.x;
    int tx = tid & 15, ty = tid >> 4;
    int n0 = blockIdx.x * 64, m0 = blockIdx.y * 64;
    int lrow = tid >> 2;
    int lk   = (tid & 3) << 2;
    int am = m0 + lrow;
    bool aok = (am < M);
    const float* Arow = A;
    if (aok) {
        int pr = (am / Ntok) * rowStride + (am % Ntok);
        Arow = A + (size_t)pr * K;
    }
    int wn = n0 + lrow;
    const float* Wrow = (wn < N) ? (W + (size_t)wn * K) : nullptr;
    float acc[4][4] = {};
    for (int kk = 0; kk < K; kk += 16) {
        float4 av = make_float4(0.f, 0.f, 0.f, 0.f);
        if (aok) av = *(const float4*)(Arow + kk + lk);
        float4 wv = make_float4(0.f, 0.f, 0.f, 0.f);
        if (Wrow) wv = *(const float4*)(Wrow + kk + lk);
        __syncthreads();
        As[lk+0][lrow] = av.x; As[lk+1][lrow] = av.y;
        As[lk+2][lrow] = av.z; As[lk+3][lrow] = av.w;
        Ws[lk+0][lrow] = wv.x; Ws[lk+1][lrow] = wv.y;
        Ws[lk+2][lrow] = wv.z; Ws[lk+3][lrow] = wv.w;
        __syncthreads();
        #pragma unroll
        for (int k = 0; k < 16; ++k) {
            float4 a = *(const float4*)&As[k][ty << 2];
            float4 w = *(const float4*)&Ws[k][tx << 2];
            acc[0][0] += a.x*w.x; acc[0][1] += a.x*w.y; acc[0][2] += a.x*w.z; acc[0][3] += a.x*w.w;
            acc[1][0] += a.y*w.x; acc[1][1] += a.y*w.y; acc[1][2] += a.y*w.z; acc[1][3] += a.y*w.w;
            acc[2][0] += a.z*w.x; acc[2][1] += a.z*w.y; acc[2][2] += a.z*w.z; acc[2][3] += a.z*w.w;
            acc[3][0] += a.w*w.x; acc[3][1] += a.w*w.y; acc[3][2] += a.w*w.z; acc[3][3] += a.w*w.w;
        }
    }
    #pragma unroll
    for (int i = 0; i < 4; ++i) {
        int m = m0 + (ty << 2) + i;
        if (m >= M) continue;
        int pr = (m / Ntok) * rowStride + (m % Ntok);
        float* crow = C + (size_t)pr * N;
        const float* addrow = add ? (add + (size_t)pr * N) : nullptr;
        #pragma unroll
        for (int j = 0; j < 4; ++j) {
            int n = n0 + (tx << 2) + j;
            float v = acc[i][j] + bias[n];
            if (addrow) v += addrow[n];
            if (dogelu) v = geluf(v);
            crow[n] = v;
        }
    }
}

// ---------------------------------------------------------------------------
// LayerNorm fp32->bf16 (feeds MFMA GEMMs).
// ---------------------------------------------------------------------------
__global__ __launch_bounds__(256)
void ln_bf16_kernel(const float* __restrict__ src, bf16* __restrict__ dst,
                    const float* __restrict__ g, const float* __restrict__ bta, int Ntok)
{
    __shared__ float red[256];
    int blk = blockIdx.x;
    int t = blk % Ntok, b = blk / Ntok;
    size_t row = ((size_t)b * SEQMAX + t) * EMBED;
    int tid = threadIdx.x;
    float v0 = src[row + tid], v1 = src[row + tid + 256], v2 = src[row + tid + 512];
    red[tid] = v0 + v1 + v2;
    __syncthreads();
    for (int off = 128; off; off >>= 1) { if (tid < off) red[tid] += red[tid + off]; __syncthreads(); }
    float mu = red[0] * (1.0f / EMBED);
    __syncthreads();
    float d0 = v0 - mu, d1 = v1 - mu, d2 = v2 - mu;
    red[tid] = d0*d0 + d1*d1 + d2*d2;
    __syncthreads();
    for (int off = 128; off; off >>= 1) { if (tid < off) red[tid] += red[tid + off]; __syncthreads(); }
    float rs = rsqrtf(red[0] * (1.0f / EMBED) + 1e-5f);
    dst[row + tid]       = __float2bfloat16(d0 * rs * g[tid]       + bta[tid]);
    dst[row + tid + 256] = __float2bfloat16(d1 * rs * g[tid + 256] + bta[tid + 256]);
    dst[row + tid + 512] = __float2bfloat16(d2 * rs * g[tid + 512] + bta[tid + 512]);
}

// LayerNorm fp32->fp32 (ln2 / final).
__global__ __launch_bounds__(256)
void ln_kernel(const float* __restrict__ src, float* __restrict__ dst,
               const float* __restrict__ g, const float* __restrict__ bta, int Ntok)
{
    __shared__ float red[256];
    int blk = blockIdx.x;
    int t = blk % Ntok, b = blk / Ntok;
    size_t row = ((size_t)b * SEQMAX + t) * EMBED;
    int tid = threadIdx.x;
    float v0 = src[row + tid], v1 = src[row + tid + 256], v2 = src[row + tid + 512];
    red[tid] = v0 + v1 + v2;
    __syncthreads();
    for (int off = 128; off; off >>= 1) { if (tid < off) red[tid] += red[tid + off]; __syncthreads(); }
    float mu = red[0] * (1.0f / EMBED);
    __syncthreads();
    float d0 = v0 - mu, d1 = v1 - mu, d2 = v2 - mu;
    red[tid] = d0*d0 + d1*d1 + d2*d2;
    __syncthreads();
    for (int off = 128; off; off >>= 1) { if (tid < off) red[tid] += red[tid + off]; __syncthreads(); }
    float rs = rsqrtf(red[0] * (1.0f / EMBED) + 1e-5f);
    dst[row + tid]       = d0 * rs * g[tid]       + bta[tid];
    dst[row + tid + 256] = d1 * rs * g[tid + 256] + bta[tid + 256];
    dst[row + tid + 512] = d2 * rs * g[tid + 512] + bta[tid + 512];
}

// ---------------------------------------------------------------------------
// Flash attention (fp32), bf16 output.
// ---------------------------------------------------------------------------
__global__ __launch_bounds__(256)
void flash_kernel(const float* __restrict__ Qh, const float* __restrict__ Kh,
                  const float* __restrict__ Vh, bf16* __restrict__ O, int Ntok)
{
    __shared__ __align__(16) float Qs[64][68];
    __shared__ __align__(16) float KPs[64][68];
    __shared__ __align__(16) float Vs[64][68];
    int bh = blockIdx.x;
    int b = bh / HEADS, h = bh % HEADS;
    int t0 = blockIdx.y * 64;
    int tid = threadIdx.x;
    int tx = tid & 15, ty = tid >> 4;

    const float* Qb = Qh + (size_t)bh * SEQMAX * HD;
    const float* Kb = Kh + (size_t)bh * SEQMAX * HD;
    const float* Vb = Vh + (size_t)bh * SEQMAX * HD;

    for (int e = tid; e < 64 * 16; e += 256) {
        int r = e >> 4, c4 = (e & 15) << 2;
        float4 v = make_float4(0.f, 0.f, 0.f, 0.f);
        if (t0 + r < Ntok) v = *(const float4*)(Qb + (size_t)(t0 + r) * HD + c4);
        *(float4*)&Qs[r][c4] = v;
    }

    float m[4], l[4], Oa[4][4];
    #pragma unroll
    for (int i = 0; i < 4; ++i) {
        m[i] = -1e30f; l[i] = 0.f;
        #pragma unroll
        for (int j = 0; j < 4; ++j) Oa[i][j] = 0.f;
    }

    for (int k0 = 0; k0 < Ntok; k0 += 64) {
        __syncthreads();
        for (int e = tid; e < 64 * 16; e += 256) {
            int r = e >> 4, c4 = (e & 15) << 2;
            float4 kv = make_float4(0.f, 0.f, 0.f, 0.f);
            float4 vv = make_float4(0.f, 0.f, 0.f, 0.f);
            if (k0 + r < Ntok) {
                kv = *(const float4*)(Kb + (size_t)(k0 + r) * HD + c4);
                vv = *(const float4*)(Vb + (size_t)(k0 + r) * HD + c4);
            }
            *(float4*)&KPs[r][c4] = kv;
            *(float4*)&Vs[r][c4] = vv;
        }
        __syncthreads();

        float S[4][4] = {};
        for (int d = 0; d < HD; d += 4) {
            float4 q[4], kk[4];
            #pragma unroll
            for (int ii = 0; ii < 4; ++ii) q[ii] = *(const float4*)&Qs[4*ty+ii][d];
            #pragma unroll
            for (int jj = 0; jj < 4; ++jj) kk[jj] = *(const float4*)&KPs[4*tx+jj][d];
            #pragma unroll
            for (int ii = 0; ii < 4; ++ii)
                #pragma unroll
                for (int jj = 0; jj < 4; ++jj)
                    S[ii][jj] += q[ii].x*kk[jj].x + q[ii].y*kk[jj].y
                               + q[ii].z*kk[jj].z + q[ii].w*kk[jj].w;
        }
        #pragma unroll
        for (int ii = 0; ii < 4; ++ii)
            #pragma unroll
            for (int jj = 0; jj < 4; ++jj) {
                float s = S[ii][jj] * 0.125f;
                S[ii][jj] = (k0 + 4*tx + jj < Ntok) ? s : -1e30f;
            }

        #pragma unroll
        for (int ii = 0; ii < 4; ++ii) {
            float rm = fmaxf(fmaxf(S[ii][0], S[ii][1]), fmaxf(S[ii][2], S[ii][3]));
            rm = fmaxf(rm, __shfl_xor(rm, 1));
            rm = fmaxf(rm, __shfl_xor(rm, 2));
            rm = fmaxf(rm, __shfl_xor(rm, 4));
            rm = fmaxf(rm, __shfl_xor(rm, 8));
            float mnew = fmaxf(m[ii], rm);
            float alpha = __expf(m[ii] - mnew);
            m[ii] = mnew;
            float s0 = 0.f;
            #pragma unroll
            for (int jj = 0; jj < 4; ++jj) {
                float p = __expf(S[ii][jj] - mnew);
                S[ii][jj] = p; s0 += p;
            }
            s0 += __shfl_xor(s0, 1); s0 += __shfl_xor(s0, 2);
            s0 += __shfl_xor(s0, 4); s0 += __shfl_xor(s0, 8);
            l[ii] = l[ii] * alpha + s0;
            #pragma unroll
            for (int jj = 0; jj < 4; ++jj) Oa[ii][jj] *= alpha;
        }

        __syncthreads();
        #pragma unroll
        for (int ii = 0; ii < 4; ++ii)
            #pragma unroll
            for (int jj = 0; jj < 4; ++jj)
                KPs[4*tx+jj][4*ty+ii] = S[ii][jj];
        __syncthreads();

        for (int kc = 0; kc < 64; ++kc) {
            float4 pp = *(const float4*)&KPs[kc][4*ty];
            float4 vv = *(const float4*)&Vs[kc][4*tx];
            Oa[0][0] += pp.x*vv.x; Oa[0][1] += pp.x*vv.y; Oa[0][2] += pp.x*vv.z; Oa[0][3] += pp.x*vv.w;
            Oa[1][0] += pp.y*vv.x; Oa[1][1] += pp.y*vv.y; Oa[1][2] += pp.y*vv.z; Oa[1][3] += pp.y*vv.w;
            Oa[2][0] += pp.z*vv.x; Oa[2][1] += pp.z*vv.y; Oa[2][2] += pp.z*vv.z; Oa[2][3] += pp.z*vv.w;
            Oa[3][0] += pp.w*vv.x; Oa[3][1] += pp.w*vv.y; Oa[3][2] += pp.w*vv.z; Oa[3][3] += pp.w*vv.w;
        }
    }

    #pragma unroll
    for (int ii = 0; ii < 4; ++ii) {
        int t = t0 + 4*ty + ii;
        if (t >= Ntok) continue;
        float inv = 1.0f / l[ii];
        bf16* dst = O + ((size_t)b * SEQMAX + t) * EMBED + h * HD + 4 * tx;
        dst[0] = __float2bfloat16(Oa[ii][0] * inv);
        dst[1] = __float2bfloat16(Oa[ii][1] * inv);
        dst[2] = __float2bfloat16(Oa[ii][2] * inv);
        dst[3] = __float2bfloat16(Oa[ii][3] * inv);
    }
}

// ---------------------------------------------------------------------------
__global__ __launch_bounds__(256)
void patch_gather(const void* __restrict__ img, bf16* __restrict__ Ap,
                  const int* __restrict__ flag)
{
    int f = *flag;
    int idx = blockIdx.x * 256 + threadIdx.x;
    if (idx >= NB * NPATCH * EMBED) return;
    int col = idx % EMBED;
    int row = idx / EMBED;
    int t = row % NPATCH, b = row / NPATCH;
    int c = col >> 8;
    int pr = (col >> 4) & 15;
    int pc = col & 15;
    int gr = t / GRID, gc = t % GRID;
    size_t off = ((size_t)(b * 3 + c) * IMGSZ + gr * PATCH + pr) * IMGSZ + gc * PATCH + pc;
    float v = f ? ((const float*)img)[off] : b2f(((const bf16*)img)[off]);
    Ap[idx] = __float2bfloat16(v);
}

__global__ __launch_bounds__(256)
void posadd_kernel(const float* __restrict__ PEO, const float* __restrict__ sp,
                   const float* __restrict__ ip, float* __restrict__ X, int imgIdx)
{
    int idx = blockIdx.x * 256 + threadIdx.x;
    if (idx >= NB * NPATCH * EMBED) return;
    int e = idx % EMBED;
    int row = idx / EMBED;
    int t = row % NPATCH, b = row / NPATCH;
    float pos = (e < 384) ? sp[t * 384 + e] : ip[imgIdx * 384 + (e - 384)];
    X[((size_t)b * SEQMAX + imgIdx * NPATCH + t) * EMBED + e] = PEO[idx] + pos;
}

__global__ __launch_bounds__(768)
void mean_kernel(const float* __restrict__ H, float* __restrict__ Mn)
{
    int b = blockIdx.x;
    int e = threadIdx.x;
    float s = 0.f;
    for (int t = 0; t < SEQMAX; ++t) s += H[((size_t)b * SEQMAX + t) * EMBED + e];
    Mn[b * EMBED + e] = s * (1.0f / SEQMAX);
}

__global__ __launch_bounds__(256)
void bcast_kernel(const float* __restrict__ P, void* __restrict__ out,
                  const int* __restrict__ flag)
{
    int f = *flag;
    int idx = blockIdx.x * 256 + threadIdx.x;
    if (idx >= NB * IMGSZ * IMGSZ) return;
    int c = idx % IMGSZ;
    int r = (idx / IMGSZ) % IMGSZ;
    int b = idx / (IMGSZ * IMGSZ);
    float v = P[b * 256 + (r & 15) * 16 + (c & 15)];
    if (f) ((float*)out)[idx] = v;
    else   ((bf16*)out)[idx] = __float2bfloat16(v);
}

// ---------------------------------------------------------------------------
extern "C" void kernel_launch(void* const* d_in, const int* in_sizes, int n_in,
                              void* d_out, int out_size, void* d_ws, size_t ws_size,
                              hipStream_t stream)
{
    (void)n_in; (void)out_size; (void)ws_size;
    const void* img[4] = {d_in[0], d_in[1], d_in[2], d_in[3]};

    float* ws = (float*)d_ws;
    int* flag = (int*)ws;

    detect_kernel<<<1, 256, 0, stream>>>((const unsigned short*)d_in[0], flag);

    // big weight matrices -> bf16 arena; everything else -> fp32 arena
    const bool isBig[28] = {0,0,0,0, 1,0,0,0, 0,0,1,0, 1,0,0,0, 1,0,1,0, 0,0,0,0, 0,0,0,0};
    float* fArena = ws + 16;
    // first pass: fp32 params
    float* fPtr[28] = {};
    {
        float* p = fArena;
        for (int i = 4; i < 28; ++i) {
            if (isBig[i]) continue;
            fPtr[i] = p;
            int n = in_sizes[i];
            int g = (n + 255) / 256; if (g > 2048) g = 2048;
            convert_f32<<<g, 256, 0, stream>>>(d_in[i], p, n, flag);
            p += n;
        }
        fArena = p;
    }
    bf16* bPtr[28] = {};
    bf16* bArena = (bf16*)fArena;
    {
        bf16* p = bArena;
        for (int i = 4; i < 28; ++i) {
            if (!isBig[i]) continue;
            bPtr[i] = p;
            int n = in_sizes[i];
            int g = (n + 255) / 256; if (g > 4096) g = 4096;
            convert_bf16<<<g, 256, 0, stream>>>(d_in[i], p, n, flag);
            p += n;
        }
        // align up to 4 floats
        size_t off = (bf16*)p - (bf16*)ws;
        off = (off + 7) & ~(size_t)7;
        fArena = (float*)((bf16*)ws + off);
    }
    const bf16* pe_w   = bPtr[4];
    const bf16* qkv_w  = bPtr[10];
    const bf16* proj_w = bPtr[12];
    const bf16* fc1_w  = bPtr[16];
    const bf16* fc2_w  = bPtr[18];
    const float* pe_b      = fPtr[5];
    const float* sp        = fPtr[6];
    const float* ip        = fPtr[7];
    const float* ln_attn_g = fPtr[8];
    const float* ln_attn_b = fPtr[9];
    const float* qkv_b     = fPtr[11];
    const float* proj_b    = fPtr[13];
    const float* ln1_g     = fPtr[14];
    const float* ln1_b     = fPtr[15];
    const float* fc1_b     = fPtr[17];
    const float* fc2_b     = fPtr[19];
    const float* ln2_g     = fPtr[20];
    const float* ln2_b     = fPtr[21];
    const float* final_g   = fPtr[22];
    const float* final_b   = fPtr[23];
    const float* head_w1   = fPtr[24];
    const float* head_b1   = fPtr[25];
    const float* head_w2   = fPtr[26];
    const float* head_b2   = fPtr[27];

    const size_t SEQ = (size_t)NB * SEQMAX * EMBED;          // 4,816,896
    const size_t QKV_ELEMS = (size_t)NB * SEQMAX * QKVD;     // 14,450,688
    const size_t HID_ELEMS = (size_t)NB * SEQMAX * HIDDEN;   // 19,267,584
    float* X    = fArena;
    float* H    = X + SEQ;
    float* O    = H + SEQ;
    float* BIGQ = O + SEQ;               // Qh/Kh/Vh live here logically
    float* Vh   = BIGQ + QKV_ELEMS;      // tail: 4,816,896 floats
    float* Qh   = O;                     // aliases: O free during attention
    float* Kh   = H;                     // H free during attention
    // (BIGQ region itself only used for Vh tail; Q/K alias O/H)
    bf16* Hb    = (bf16*)(Vh + SEQ);
    bf16* Ob    = Hb + SEQ;
    bf16* Gb    = Ob + SEQ;
    bf16* PEb   = Gb + HID_ELEMS;
    float* PEO  = (float*)(PEb + (size_t)NB * NPATCH * EMBED);
    float* MEAN = PEO + (size_t)NB * NPATCH * EMBED;
    float* HH   = MEAN + NB * EMBED;
    float* PTCH = HH + NB * EMBED;

    const int nEmb = NB * NPATCH * EMBED;

    auto embed = [&](int i) {
        patch_gather<<<(nEmb + 255) / 256, 256, 0, stream>>>(img[i], PEb, flag);
        dim3 g(EMBED / 128, (NB * NPATCH + 127) / 128);
        mfma_gemm<<<g, 256, 0, stream>>>(PEb, pe_w + (size_t)i * EMBED * EMBED,
                                         pe_b + i * EMBED, nullptr, PEO, nullptr,
                                         nullptr, nullptr, nullptr,
                                         NB * NPATCH, EMBED, EMBED,
                                         NB * NPATCH, NB * NPATCH, 0);
        posadd_kernel<<<(nEmb + 255) / 256, 256, 0, stream>>>(PEO, sp, ip, X, i);
    };

    auto block = [&](int i, int Ntok) {
        int M = NB * Ntok;
        int gy = (M + 127) / 128;
        ln_bf16_kernel<<<M, 256, 0, stream>>>(X, Hb, ln_attn_g + i * EMBED, ln_attn_b + i * EMBED, Ntok);
        mfma_gemm<<<dim3(QKVD / 128, gy), 256, 0, stream>>>(
            Hb, qkv_w + (size_t)i * QKVD * EMBED, qkv_b + i * QKVD, nullptr,
            nullptr, nullptr, Qh, Kh, Vh, M, QKVD, EMBED, Ntok, SEQMAX, 3);
        dim3 fg(NB * HEADS, (Ntok + 63) / 64);
        flash_kernel<<<fg, 256, 0, stream>>>(Qh, Kh, Vh, Ob, Ntok);
        mfma_gemm<<<dim3(EMBED / 128, gy), 256, 0, stream>>>(
            Ob, proj_w + (size_t)i * EMBED * EMBED, proj_b + i * EMBED, X,
            X, nullptr, nullptr, nullptr, nullptr, M, EMBED, EMBED, Ntok, SEQMAX, 1);
        ln_bf16_kernel<<<M, 256, 0, stream>>>(X, Hb, ln1_g + i * EMBED, ln1_b + i * EMBED, Ntok);
        mfma_gemm<<<dim3(HIDDEN / 128, gy), 256, 0, stream>>>(
            Hb, fc1_w + (size_t)i * HIDDEN * EMBED, fc1_b + i * HIDDEN, nullptr,
            nullptr, Gb, nullptr, nullptr, nullptr, M, HIDDEN, EMBED, Ntok, SEQMAX, 2);
        mfma_gemm<<<dim3(EMBED / 128, gy), 256, 0, stream>>>(
            Gb, fc2_w + (size_t)i * EMBED * HIDDEN, fc2_b + i * EMBED, X,
            O, nullptr, nullptr, nullptr, nullptr, M, EMBED, HIDDEN, Ntok, SEQMAX, 1);
        ln_kernel<<<M, 256, 0, stream>>>(O, X, ln2_g + i * EMBED, ln2_b + i * EMBED, Ntok);
    };

    embed(0);
    embed(1);
    block(0, 392);
    embed(2);
    block(1, 588);
    embed(3);
    block(2, 784);

    ln_kernel<<<NB * SEQMAX, 256, 0, stream>>>(X, H, final_g, final_b, SEQMAX);
    mean_kernel<<<NB, 768, 0, stream>>>(H, MEAN);
    gemm_kernel<<<dim3(EMBED / 64, 1), 256, 0, stream>>>(
        MEAN, head_w1, head_b1, nullptr, HH, NB, EMBED, EMBED, NB, NB, 1);
    gemm_kernel<<<dim3(256 / 64, 1), 256, 0, stream>>>(
        HH, head_w2, head_b2, nullptr, PTCH, NB, 256, EMBED, NB, NB, 0);
    bcast_kernel<<<(NB * IMGSZ * IMGSZ + 255) / 256, 256, 0, stream>>>(PTCH, d_out, flag);
}

// Round 5
// 1841.568 us; speedup vs baseline: 5.4793x; 1.1385x over previous
//
#include <hip/hip_runtime.h>
#include <hip/hip_bf16.h>
#include <math.h>

#define EMBED 768
#define QKVD 2304
#define HEADS 12
#define HD 64
#define HIDDEN 3072
#define NPATCH 196
#define SEQMAX 784
#define NB 8
#define IMGSZ 224
#define GRID 14
#define PATCH 16
#define PSTR 68

typedef __hip_bfloat16 bf16;
typedef __attribute__((ext_vector_type(8))) short short8;
typedef __attribute__((ext_vector_type(4))) float f32x4;

__device__ __forceinline__ float b2f(bf16 v) { return __bfloat162float(v); }
__device__ __forceinline__ float geluf(float x) {
    return 0.5f * x * (1.0f + erff(x * 0.70710678118654752f));
}

// async global->LDS, 16B per lane. LDS dest is wave-uniform base + lane*16.
__device__ __forceinline__ void async16(const bf16* g, bf16* l) {
    __builtin_amdgcn_global_load_lds(
        (const __attribute__((address_space(1))) unsigned int*)g,
        (__attribute__((address_space(3))) unsigned int*)l,
        16, 0, 0);
}

// ---------------------------------------------------------------------------
// Dtype detection (bf16 vs fp32 inputs).
// ---------------------------------------------------------------------------
__global__ __launch_bounds__(256)
void detect_kernel(const unsigned short* __restrict__ raw, int* __restrict__ flag)
{
    __shared__ int bad;
    if (threadIdx.x == 0) bad = 0;
    __syncthreads();
    for (int i = threadIdx.x; i < 8192; i += 256) {
        unsigned int u = (unsigned int)raw[i] << 16;
        float v = __uint_as_float(u);
        if (!(fabsf(v) <= 1e4f)) bad = 1;
    }
    __syncthreads();
    if (threadIdx.x == 0) *flag = bad;
}

__global__ __launch_bounds__(256)
void convert_f32(const void* __restrict__ src, float* __restrict__ dst,
                 int n, const int* __restrict__ flag)
{
    int f = *flag;
    for (int i = blockIdx.x * 256 + threadIdx.x; i < n; i += gridDim.x * 256)
        dst[i] = f ? ((const float*)src)[i] : b2f(((const bf16*)src)[i]);
}

__global__ __launch_bounds__(256)
void convert_bf16(const void* __restrict__ src, bf16* __restrict__ dst,
                  int n, const int* __restrict__ flag)
{
    int f = *flag;
    for (int i = blockIdx.x * 256 + threadIdx.x; i < n; i += gridDim.x * 256)
        dst[i] = f ? __float2bfloat16(((const float*)src)[i]) : ((const bf16*)src)[i];
}

// ---------------------------------------------------------------------------
// MFMA bf16 GEMM: 128x128 tile, BK=32, 4 waves, 4x4 mfma_f32_16x16x32_bf16.
// mode: 0 = fp32 out; 1 = fp32 out + residual; 2 = bf16 out + gelu;
//       3 = qkv head-split -> bf16 Qh/Kh [bh][t][64] and bf16 VT [bh][64][t].
// ---------------------------------------------------------------------------
__global__ __launch_bounds__(256)
void mfma_gemm(const bf16* __restrict__ A, const bf16* __restrict__ W,
               const float* __restrict__ bias, const float* __restrict__ add,
               float* __restrict__ outF, bf16* __restrict__ outB,
               bf16* __restrict__ Qb, bf16* __restrict__ Kb, bf16* __restrict__ VTb,
               int M, int N, int K, int Ntok, int rowStride, int mode)
{
    __shared__ __align__(16) bf16 As[128 * 32];
    __shared__ __align__(16) bf16 Bs[128 * 32];
    int tid = threadIdx.x;
    int lane = tid & 63;
    int wave = tid >> 6;
    int wm = wave & 1, wn = wave >> 1;
    int m0 = blockIdx.y * 128, n0 = blockIdx.x * 128;

    int lr = lane >> 2;
    int lc = lane & 3;
    int ar0 = 32 * wave + lr;
    int ar1 = ar0 + 16;
    int ma0 = m0 + ar0; if (ma0 >= M) ma0 = M - 1;
    int ma1 = m0 + ar1; if (ma1 >= M) ma1 = M - 1;
    const bf16* aSrc0 = A + (size_t)((ma0 / Ntok) * rowStride + ma0 % Ntok) * K + lc * 8;
    const bf16* aSrc1 = A + (size_t)((ma1 / Ntok) * rowStride + ma1 % Ntok) * K + lc * 8;
    const bf16* bSrc0 = W + (size_t)(n0 + ar0) * K + lc * 8;
    const bf16* bSrc1 = W + (size_t)(n0 + ar1) * K + lc * 8;
    bf16* aDst0 = As + (32 * wave) * 32;
    bf16* aDst1 = As + (32 * wave + 16) * 32;
    bf16* bDst0 = Bs + (32 * wave) * 32;
    bf16* bDst1 = Bs + (32 * wave + 16) * 32;

    int fr = lane & 15;
    int fq = lane >> 4;
    const bf16* aRead = As + (wm * 64 + fr) * 32 + fq * 8;
    const bf16* bRead = Bs + (wn * 64 + fr) * 32 + fq * 8;

    f32x4 acc[4][4] = {};

    for (int kk = 0; kk < K; kk += 32) {
        __syncthreads();
        async16(aSrc0, aDst0);
        async16(aSrc1, aDst1);
        async16(bSrc0, bDst0);
        async16(bSrc1, bDst1);
        aSrc0 += 32; aSrc1 += 32; bSrc0 += 32; bSrc1 += 32;
        __builtin_amdgcn_s_waitcnt(0xF70);
        __syncthreads();
        short8 af[4], bfr[4];
        #pragma unroll
        for (int mi = 0; mi < 4; ++mi) af[mi] = *(const short8*)(aRead + mi * 16 * 32);
        #pragma unroll
        for (int ni = 0; ni < 4; ++ni) bfr[ni] = *(const short8*)(bRead + ni * 16 * 32);
        #pragma unroll
        for (int mi = 0; mi < 4; ++mi)
            #pragma unroll
            for (int ni = 0; ni < 4; ++ni)
                acc[mi][ni] = __builtin_amdgcn_mfma_f32_16x16x32_bf16(
                    af[mi], bfr[ni], acc[mi][ni], 0, 0, 0);
    }

    #pragma unroll
    for (int mi = 0; mi < 4; ++mi) {
        #pragma unroll
        for (int ni = 0; ni < 4; ++ni) {
            int n = n0 + wn * 64 + ni * 16 + fr;
            float bs = bias[n];
            #pragma unroll
            for (int r = 0; r < 4; ++r) {
                int m = m0 + wm * 64 + mi * 16 + fq * 4 + r;
                if (m >= M) continue;
                int bidx = m / Ntok, t = m - bidx * Ntok;
                size_t pr = (size_t)bidx * rowStride + t;
                float v = acc[mi][ni][r] + bs;
                if (mode == 0) {
                    outF[pr * N + n] = v;
                } else if (mode == 1) {
                    outF[pr * N + n] = v + add[pr * N + n];
                } else if (mode == 2) {
                    outB[pr * N + n] = __float2bfloat16(geluf(v));
                } else {
                    int which = n >= 1536 ? 2 : (n >= 768 ? 1 : 0);
                    int nn = n - which * 768;
                    int hh = nn >> 6, d = nn & 63;
                    bf16 bv = __float2bfloat16(v);
                    size_t bhI = (size_t)(bidx * HEADS + hh);
                    if (which == 0)      Qb[(bhI * SEQMAX + t) * HD + d] = bv;
                    else if (which == 1) Kb[(bhI * SEQMAX + t) * HD + d] = bv;
                    else                 VTb[(bhI * HD + d) * SEQMAX + t] = bv;
                }
            }
        }
    }
}

// ---------------------------------------------------------------------------
// Legacy fp32 GEMM (tiny head matmuls only).
// ---------------------------------------------------------------------------
__global__ __launch_bounds__(256)
void gemm_kernel(const float* __restrict__ A, const float* __restrict__ W,
                 const float* __restrict__ bias, const float* __restrict__ add,
                 float* __restrict__ C, int M, int N, int K,
                 int Ntok, int rowStride, int dogelu)
{
    __shared__ __align__(16) float As[16][68];
    __shared__ __align__(16) float Ws[16][68];
    int tid = threadIdx.x;
    int tx = tid & 15, ty = tid >> 4;
    int n0 = blockIdx.x * 64, m0 = blockIdx.y * 64;
    int lrow = tid >> 2;
    int lk   = (tid & 3) << 2;
    int am = m0 + lrow;
    bool aok = (am < M);
    const float* Arow = A;
    if (aok) {
        int pr = (am / Ntok) * rowStride + (am % Ntok);
        Arow = A + (size_t)pr * K;
    }
    int wn = n0 + lrow;
    const float* Wrow = (wn < N) ? (W + (size_t)wn * K) : nullptr;
    float acc[4][4] = {};
    for (int kk = 0; kk < K; kk += 16) {
        float4 av = make_float4(0.f, 0.f, 0.f, 0.f);
        if (aok) av = *(const float4*)(Arow + kk + lk);
        float4 wv = make_float4(0.f, 0.f, 0.f, 0.f);
        if (Wrow) wv = *(const float4*)(Wrow + kk + lk);
        __syncthreads();
        As[lk+0][lrow] = av.x; As[lk+1][lrow] = av.y;
        As[lk+2][lrow] = av.z; As[lk+3][lrow] = av.w;
        Ws[lk+0][lrow] = wv.x; Ws[lk+1][lrow] = wv.y;
        Ws[lk+2][lrow] = wv.z; Ws[lk+3][lrow] = wv.w;
        __syncthreads();
        #pragma unroll
        for (int k = 0; k < 16; ++k) {
            float4 a = *(const float4*)&As[k][ty << 2];
            float4 w = *(const float4*)&Ws[k][tx << 2];
            acc[0][0] += a.x*w.x; acc[0][1] += a.x*w.y; acc[0][2] += a.x*w.z; acc[0][3] += a.x*w.w;
            acc[1][0] += a.y*w.x; acc[1][1] += a.y*w.y; acc[1][2] += a.y*w.z; acc[1][3] += a.y*w.w;
            acc[2][0] += a.z*w.x; acc[2][1] += a.z*w.y; acc[2][2] += a.z*w.z; acc[2][3] += a.z*w.w;
            acc[3][0] += a.w*w.x; acc[3][1] += a.w*w.y; acc[3][2] += a.w*w.z; acc[3][3] += a.w*w.w;
        }
    }
    #pragma unroll
    for (int i = 0; i < 4; ++i) {
        int m = m0 + (ty << 2) + i;
        if (m >= M) continue;
        int pr = (m / Ntok) * rowStride + (m % Ntok);
        float* crow = C + (size_t)pr * N;
        const float* addrow = add ? (add + (size_t)pr * N) : nullptr;
        #pragma unroll
        for (int j = 0; j < 4; ++j) {
            int n = n0 + (tx << 2) + j;
            float v = acc[i][j] + bias[n];
            if (addrow) v += addrow[n];
            if (dogelu) v = geluf(v);
            crow[n] = v;
        }
    }
}

// ---------------------------------------------------------------------------
// LayerNorm fp32->bf16.
// ---------------------------------------------------------------------------
__global__ __launch_bounds__(256)
void ln_bf16_kernel(const float* __restrict__ src, bf16* __restrict__ dst,
                    const float* __restrict__ g, const float* __restrict__ bta, int Ntok)
{
    __shared__ float red[256];
    int blk = blockIdx.x;
    int t = blk % Ntok, b = blk / Ntok;
    size_t row = ((size_t)b * SEQMAX + t) * EMBED;
    int tid = threadIdx.x;
    float v0 = src[row + tid], v1 = src[row + tid + 256], v2 = src[row + tid + 512];
    red[tid] = v0 + v1 + v2;
    __syncthreads();
    for (int off = 128; off; off >>= 1) { if (tid < off) red[tid] += red[tid + off]; __syncthreads(); }
    float mu = red[0] * (1.0f / EMBED);
    __syncthreads();
    float d0 = v0 - mu, d1 = v1 - mu, d2 = v2 - mu;
    red[tid] = d0*d0 + d1*d1 + d2*d2;
    __syncthreads();
    for (int off = 128; off; off >>= 1) { if (tid < off) red[tid] += red[tid + off]; __syncthreads(); }
    float rs = rsqrtf(red[0] * (1.0f / EMBED) + 1e-5f);
    dst[row + tid]       = __float2bfloat16(d0 * rs * g[tid]       + bta[tid]);
    dst[row + tid + 256] = __float2bfloat16(d1 * rs * g[tid + 256] + bta[tid + 256]);
    dst[row + tid + 512] = __float2bfloat16(d2 * rs * g[tid + 512] + bta[tid + 512]);
}

// LayerNorm fp32->fp32.
__global__ __launch_bounds__(256)
void ln_kernel(const float* __restrict__ src, float* __restrict__ dst,
               const float* __restrict__ g, const float* __restrict__ bta, int Ntok)
{
    __shared__ float red[256];
    int blk = blockIdx.x;
    int t = blk % Ntok, b = blk / Ntok;
    size_t row = ((size_t)b * SEQMAX + t) * EMBED;
    int tid = threadIdx.x;
    float v0 = src[row + tid], v1 = src[row + tid + 256], v2 = src[row + tid + 512];
    red[tid] = v0 + v1 + v2;
    __syncthreads();
    for (int off = 128; off; off >>= 1) { if (tid < off) red[tid] += red[tid + off]; __syncthreads(); }
    float mu = red[0] * (1.0f / EMBED);
    __syncthreads();
    float d0 = v0 - mu, d1 = v1 - mu, d2 = v2 - mu;
    red[tid] = d0*d0 + d1*d1 + d2*d2;
    __syncthreads();
    for (int off = 128; off; off >>= 1) { if (tid < off) red[tid] += red[tid + off]; __syncthreads(); }
    float rs = rsqrtf(red[0] * (1.0f / EMBED) + 1e-5f);
    dst[row + tid]       = d0 * rs * g[tid]       + bta[tid];
    dst[row + tid + 256] = d1 * rs * g[tid + 256] + bta[tid + 256];
    dst[row + tid + 512] = d2 * rs * g[tid + 512] + bta[tid + 512];
}

// ---------------------------------------------------------------------------
// MFMA flash attention. Block = (bh, 64-query tile); wave w owns 16 q-rows.
// Q/K bf16 [bh][t][64], V^T bf16 [bh][64][t]. Fragments read directly from
// global; P converts C-layout -> A-layout via per-wave LDS patch (stride 68).
// ---------------------------------------------------------------------------
__global__ __launch_bounds__(256)
void flash_mfma(const bf16* __restrict__ Qh, const bf16* __restrict__ Kh,
                const bf16* __restrict__ VT, bf16* __restrict__ O, int Ntok)
{
    __shared__ __align__(16) bf16 Plds[4][16 * PSTR];
    int bh = blockIdx.x;
    int b = bh / HEADS, h = bh % HEADS;
    int t0 = blockIdx.y * 64;
    int tid = threadIdx.x;
    int lane = tid & 63, w = tid >> 6;
    int fr = lane & 15, fq = lane >> 4;

    const bf16* Qb = Qh + (size_t)bh * SEQMAX * HD;
    const bf16* Kb = Kh + (size_t)bh * SEQMAX * HD;
    const bf16* Vb = VT + (size_t)bh * HD * SEQMAX;

    int tq = t0 + w * 16 + fr; if (tq >= Ntok) tq = Ntok - 1;
    short8 aq0 = *(const short8*)(Qb + (size_t)tq * HD + fq * 8);
    short8 aq1 = *(const short8*)(Qb + (size_t)tq * HD + fq * 8 + 32);

    float mrow[4], lrow[4];
    f32x4 oacc[4];
    #pragma unroll
    for (int r = 0; r < 4; ++r) { mrow[r] = -1e30f; lrow[r] = 0.f; }
    #pragma unroll
    for (int dg = 0; dg < 4; ++dg) oacc[dg] = (f32x4){0.f, 0.f, 0.f, 0.f};

    bf16* Pw = Plds[w];

    for (int k0 = 0; k0 < Ntok; k0 += 64) {
        // S = Q K^T for this 64-key tile
        float s[4][4];
        #pragma unroll
        for (int kg = 0; kg < 4; ++kg) {
            int key = k0 + kg * 16 + fr;
            int keyc = key < Ntok ? key : Ntok - 1;
            short8 bk0 = *(const short8*)(Kb + (size_t)keyc * HD + fq * 8);
            short8 bk1 = *(const short8*)(Kb + (size_t)keyc * HD + fq * 8 + 32);
            f32x4 sa = (f32x4){0.f, 0.f, 0.f, 0.f};
            sa = __builtin_amdgcn_mfma_f32_16x16x32_bf16(aq0, bk0, sa, 0, 0, 0);
            sa = __builtin_amdgcn_mfma_f32_16x16x32_bf16(aq1, bk1, sa, 0, 0, 0);
            bool ok = key < Ntok;
            #pragma unroll
            for (int r = 0; r < 4; ++r) s[kg][r] = ok ? sa[r] * 0.125f : -1e30f;
        }

        // online softmax; per-lane rows are fq*4+r (C layout)
        #pragma unroll
        for (int r = 0; r < 4; ++r) {
            float rm = fmaxf(fmaxf(s[0][r], s[1][r]), fmaxf(s[2][r], s[3][r]));
            rm = fmaxf(rm, __shfl_xor(rm, 1));
            rm = fmaxf(rm, __shfl_xor(rm, 2));
            rm = fmaxf(rm, __shfl_xor(rm, 4));
            rm = fmaxf(rm, __shfl_xor(rm, 8));
            float mnew = fmaxf(mrow[r], rm);
            float alpha = __expf(mrow[r] - mnew);
            mrow[r] = mnew;
            float sum = 0.f;
            #pragma unroll
            for (int kg = 0; kg < 4; ++kg) {
                float p = __expf(s[kg][r] - mnew);
                s[kg][r] = p; sum += p;
            }
            sum += __shfl_xor(sum, 1); sum += __shfl_xor(sum, 2);
            sum += __shfl_xor(sum, 4); sum += __shfl_xor(sum, 8);
            lrow[r] = lrow[r] * alpha + sum;
            #pragma unroll
            for (int dg = 0; dg < 4; ++dg) oacc[dg][r] *= alpha;
        }

        // P: C-layout regs -> LDS [q_local][key] -> A-layout fragments
        __syncthreads();   // previous iteration's P reads complete
        #pragma unroll
        for (int kg = 0; kg < 4; ++kg)
            #pragma unroll
            for (int r = 0; r < 4; ++r)
                Pw[(fq * 4 + r) * PSTR + kg * 16 + fr] = __float2bfloat16(s[kg][r]);
        __syncthreads();   // P visible

        short8 ap0 = *(const short8*)(Pw + fr * PSTR + fq * 8);
        short8 ap1 = *(const short8*)(Pw + fr * PSTR + fq * 8 + 32);

        int ks = k0 + fq * 8;
        int ks1 = ks + 32;
        if (ks + 8 > SEQMAX) ks = SEQMAX - 8;      // stay in-buffer; P=0 there
        if (ks1 + 8 > SEQMAX) ks1 = SEQMAX - 8;
        #pragma unroll
        for (int dg = 0; dg < 4; ++dg) {
            int d = dg * 16 + fr;
            short8 bv0 = *(const short8*)(Vb + (size_t)d * SEQMAX + ks);
            short8 bv1 = *(const short8*)(Vb + (size_t)d * SEQMAX + ks1);
            oacc[dg] = __builtin_amdgcn_mfma_f32_16x16x32_bf16(ap0, bv0, oacc[dg], 0, 0, 0);
            oacc[dg] = __builtin_amdgcn_mfma_f32_16x16x32_bf16(ap1, bv1, oacc[dg], 0, 0, 0);
        }
    }

    #pragma unroll
    for (int r = 0; r < 4; ++r) {
        int t = t0 + w * 16 + fq * 4 + r;
        if (t >= Ntok) continue;
        float inv = 1.0f / lrow[r];
        bf16* dst = O + ((size_t)b * SEQMAX + t) * EMBED + h * HD;
        #pragma unroll
        for (int dg = 0; dg < 4; ++dg)
            dst[dg * 16 + fr] = __float2bfloat16(oacc[dg][r] * inv);
    }
}

// ---------------------------------------------------------------------------
__global__ __launch_bounds__(256)
void patch_gather(const void* __restrict__ img, bf16* __restrict__ Ap,
                  const int* __restrict__ flag)
{
    int f = *flag;
    int idx = blockIdx.x * 256 + threadIdx.x;
    if (idx >= NB * NPATCH * EMBED) return;
    int col = idx % EMBED;
    int row = idx / EMBED;
    int t = row % NPATCH, b = row / NPATCH;
    int c = col >> 8;
    int pr = (col >> 4) & 15;
    int pc = col & 15;
    int gr = t / GRID, gc = t % GRID;
    size_t off = ((size_t)(b * 3 + c) * IMGSZ + gr * PATCH + pr) * IMGSZ + gc * PATCH + pc;
    float v = f ? ((const float*)img)[off] : b2f(((const bf16*)img)[off]);
    Ap[idx] = __float2bfloat16(v);
}

__global__ __launch_bounds__(256)
void posadd_kernel(const float* __restrict__ PEO, const float* __restrict__ sp,
                   const float* __restrict__ ip, float* __restrict__ X, int imgIdx)
{
    int idx = blockIdx.x * 256 + threadIdx.x;
    if (idx >= NB * NPATCH * EMBED) return;
    int e = idx % EMBED;
    int row = idx / EMBED;
    int t = row % NPATCH, b = row / NPATCH;
    float pos = (e < 384) ? sp[t * 384 + e] : ip[imgIdx * 384 + (e - 384)];
    X[((size_t)b * SEQMAX + imgIdx * NPATCH + t) * EMBED + e] = PEO[idx] + pos;
}

__global__ __launch_bounds__(768)
void mean_kernel(const float* __restrict__ H, float* __restrict__ Mn)
{
    int b = blockIdx.x;
    int e = threadIdx.x;
    float s = 0.f;
    for (int t = 0; t < SEQMAX; ++t) s += H[((size_t)b * SEQMAX + t) * EMBED + e];
    Mn[b * EMBED + e] = s * (1.0f / SEQMAX);
}

__global__ __launch_bounds__(256)
void bcast_kernel(const float* __restrict__ P, void* __restrict__ out,
                  const int* __restrict__ flag)
{
    int f = *flag;
    int idx = blockIdx.x * 256 + threadIdx.x;
    if (idx >= NB * IMGSZ * IMGSZ) return;
    int c = idx % IMGSZ;
    int r = (idx / IMGSZ) % IMGSZ;
    int b = idx / (IMGSZ * IMGSZ);
    float v = P[b * 256 + (r & 15) * 16 + (c & 15)];
    if (f) ((float*)out)[idx] = v;
    else   ((bf16*)out)[idx] = __float2bfloat16(v);
}

// ---------------------------------------------------------------------------
extern "C" void kernel_launch(void* const* d_in, const int* in_sizes, int n_in,
                              void* d_out, int out_size, void* d_ws, size_t ws_size,
                              hipStream_t stream)
{
    (void)n_in; (void)out_size; (void)ws_size;
    const void* img[4] = {d_in[0], d_in[1], d_in[2], d_in[3]};

    float* ws = (float*)d_ws;
    int* flag = (int*)ws;

    detect_kernel<<<1, 256, 0, stream>>>((const unsigned short*)d_in[0], flag);

    const bool isBig[28] = {0,0,0,0, 1,0,0,0, 0,0,1,0, 1,0,0,0, 1,0,1,0, 0,0,0,0, 0,0,0,0};
    float* fArena = ws + 16;
    float* fPtr[28] = {};
    {
        float* p = fArena;
        for (int i = 4; i < 28; ++i) {
            if (isBig[i]) continue;
            fPtr[i] = p;
            int n = in_sizes[i];
            int g = (n + 255) / 256; if (g > 2048) g = 2048;
            convert_f32<<<g, 256, 0, stream>>>(d_in[i], p, n, flag);
            p += n;
        }
        fArena = p;
    }
    bf16* bPtr[28] = {};
    {
        bf16* p = (bf16*)fArena;
        for (int i = 4; i < 28; ++i) {
            if (!isBig[i]) continue;
            bPtr[i] = p;
            int n = in_sizes[i];
            int g = (n + 255) / 256; if (g > 4096) g = 4096;
            convert_bf16<<<g, 256, 0, stream>>>(d_in[i], p, n, flag);
            p += n;
        }
        size_t off = p - (bf16*)ws;
        off = (off + 7) & ~(size_t)7;
        fArena = (float*)((bf16*)ws + off);
    }
    const bf16* pe_w   = bPtr[4];
    const bf16* qkv_w  = bPtr[10];
    const bf16* proj_w = bPtr[12];
    const bf16* fc1_w  = bPtr[16];
    const bf16* fc2_w  = bPtr[18];
    const float* pe_b      = fPtr[5];
    const float* sp        = fPtr[6];
    const float* ip        = fPtr[7];
    const float* ln_attn_g = fPtr[8];
    const float* ln_attn_b = fPtr[9];
    const float* qkv_b     = fPtr[11];
    const float* proj_b    = fPtr[13];
    const float* ln1_g     = fPtr[14];
    const float* ln1_b     = fPtr[15];
    const float* fc1_b     = fPtr[17];
    const float* fc2_b     = fPtr[19];
    const float* ln2_g     = fPtr[20];
    const float* ln2_b     = fPtr[21];
    const float* final_g   = fPtr[22];
    const float* final_b   = fPtr[23];
    const float* head_w1   = fPtr[24];
    const float* head_b1   = fPtr[25];
    const float* head_w2   = fPtr[26];
    const float* head_b2   = fPtr[27];

    const size_t SEQ = (size_t)NB * SEQMAX * EMBED;          // 4,816,896
    const size_t HID_ELEMS = (size_t)NB * SEQMAX * HIDDEN;   // 19,267,584
    const size_t EMB_ELEMS = (size_t)NB * NPATCH * EMBED;    // 1,204,224
    float* X    = fArena;
    float* H    = X + SEQ;
    float* O    = H + SEQ;
    float* PEO  = O + SEQ;
    float* MEAN = PEO + EMB_ELEMS;
    float* HH   = MEAN + NB * EMBED;
    float* PTCH = HH + NB * EMBED;
    bf16* Hb    = (bf16*)(PTCH + NB * 256 + 16);
    bf16* Ob    = Hb + SEQ;
    bf16* Gb    = Ob + SEQ;
    bf16* PEb   = Gb + HID_ELEMS;
    bf16* Qb    = PEb + EMB_ELEMS;
    bf16* Kb    = Qb + SEQ;
    bf16* VTb   = Kb + SEQ;      // + SEQ elements (+64 slack lives after)

    const int nEmb = NB * NPATCH * EMBED;

    auto embed = [&](int i) {
        patch_gather<<<(nEmb + 255) / 256, 256, 0, stream>>>(img[i], PEb, flag);
        dim3 g(EMBED / 128, (NB * NPATCH + 127) / 128);
        mfma_gemm<<<g, 256, 0, stream>>>(PEb, pe_w + (size_t)i * EMBED * EMBED,
                                         pe_b + i * EMBED, nullptr, PEO, nullptr,
                                         nullptr, nullptr, nullptr,
                                         NB * NPATCH, EMBED, EMBED,
                                         NB * NPATCH, NB * NPATCH, 0);
        posadd_kernel<<<(nEmb + 255) / 256, 256, 0, stream>>>(PEO, sp, ip, X, i);
    };

    auto block = [&](int i, int Ntok) {
        int M = NB * Ntok;
        int gy = (M + 127) / 128;
        ln_bf16_kernel<<<M, 256, 0, stream>>>(X, Hb, ln_attn_g + i * EMBED, ln_attn_b + i * EMBED, Ntok);
        mfma_gemm<<<dim3(QKVD / 128, gy), 256, 0, stream>>>(
            Hb, qkv_w + (size_t)i * QKVD * EMBED, qkv_b + i * QKVD, nullptr,
            nullptr, nullptr, Qb, Kb, VTb, M, QKVD, EMBED, Ntok, SEQMAX, 3);
        dim3 fg(NB * HEADS, (Ntok + 63) / 64);
        flash_mfma<<<fg, 256, 0, stream>>>(Qb, Kb, VTb, Ob, Ntok);
        mfma_gemm<<<dim3(EMBED / 128, gy), 256, 0, stream>>>(
            Ob, proj_w + (size_t)i * EMBED * EMBED, proj_b + i * EMBED, X,
            X, nullptr, nullptr, nullptr, nullptr, M, EMBED, EMBED, Ntok, SEQMAX, 1);
        ln_bf16_kernel<<<M, 256, 0, stream>>>(X, Hb, ln1_g + i * EMBED, ln1_b + i * EMBED, Ntok);
        mfma_gemm<<<dim3(HIDDEN / 128, gy), 256, 0, stream>>>(
            Hb, fc1_w + (size_t)i * HIDDEN * EMBED, fc1_b + i * HIDDEN, nullptr,
            nullptr, Gb, nullptr, nullptr, nullptr, M, HIDDEN, EMBED, Ntok, SEQMAX, 2);
        mfma_gemm<<<dim3(EMBED / 128, gy), 256, 0, stream>>>(
            Gb, fc2_w + (size_t)i * EMBED * HIDDEN, fc2_b + i * EMBED, X,
            O, nullptr, nullptr, nullptr, nullptr, M, EMBED, HIDDEN, Ntok, SEQMAX, 1);
        ln_kernel<<<M, 256, 0, stream>>>(O, X, ln2_g + i * EMBED, ln2_b + i * EMBED, Ntok);
    };

    embed(0);
    embed(1);
    block(0, 392);
    embed(2);
    block(1, 588);
    embed(3);
    block(2, 784);

    ln_kernel<<<NB * SEQMAX, 256, 0, stream>>>(X, H, final_g, final_b, SEQMAX);
    mean_kernel<<<NB, 768, 0, stream>>>(H, MEAN);
    gemm_kernel<<<dim3(EMBED / 64, 1), 256, 0, stream>>>(
        MEAN, head_w1, head_b1, nullptr, HH, NB, EMBED, EMBED, NB, NB, 1);
    gemm_kernel<<<dim3(256 / 64, 1), 256, 0, stream>>>(
        HH, head_w2, head_b2, nullptr, PTCH, NB, 256, EMBED, NB, NB, 0);
    bcast_kernel<<<(NB * IMGSZ * IMGSZ + 255) / 256, 256, 0, stream>>>(PTCH, d_out, flag);
}

// Round 7
// 1736.433 us; speedup vs baseline: 5.8110x; 1.0605x over previous
//
#include <hip/hip_runtime.h>
#include <hip/hip_bf16.h>
#include <math.h>

#define EMBED 768
#define QKVD 2304
#define HEADS 12
#define HD 64
#define HIDDEN 3072
#define NPATCH 196
#define SEQMAX 784
#define NB 8
#define IMGSZ 224
#define GRID 14
#define PATCH 16
#define PSTR 72
#define VSTR 72

typedef __hip_bfloat16 bf16;
typedef __attribute__((ext_vector_type(8))) short short8;
typedef __attribute__((ext_vector_type(4))) float f32x4;

__device__ __forceinline__ float b2f(bf16 v) { return __bfloat162float(v); }
__device__ __forceinline__ float geluf(float x) {
    return 0.5f * x * (1.0f + erff(x * 0.70710678118654752f));
}

// async global->LDS, 16B per lane. LDS dest is wave-uniform base + lane*16.
__device__ __forceinline__ void async16(const bf16* g, bf16* l) {
    __builtin_amdgcn_global_load_lds(
        (const __attribute__((address_space(1))) unsigned int*)g,
        (__attribute__((address_space(3))) unsigned int*)l,
        16, 0, 0);
}

// waitcnt immediates (gfx9 encoding): vmcnt[3:0]|exp[6:4]|lgkm[11:8]|vmcnt[5:4]<<14
#define WAIT_VM0   0x0F70   // vmcnt(0), lgkm/exp free
#define WAIT_VM4   0x0F74   // vmcnt(4)
#define WAIT_LGKM0 0xC07F   // lgkmcnt(0), vm/exp free

// ---------------------------------------------------------------------------
// Dtype detection (bf16 vs fp32 inputs).
// ---------------------------------------------------------------------------
__global__ __launch_bounds__(256)
void detect_kernel(const unsigned short* __restrict__ raw, int* __restrict__ flag)
{
    __shared__ int bad;
    if (threadIdx.x == 0) bad = 0;
    __syncthreads();
    for (int i = threadIdx.x; i < 8192; i += 256) {
        unsigned int u = (unsigned int)raw[i] << 16;
        float v = __uint_as_float(u);
        if (!(fabsf(v) <= 1e4f)) bad = 1;
    }
    __syncthreads();
    if (threadIdx.x == 0) *flag = bad;
}

__global__ __launch_bounds__(256)
void convert_f32(const void* __restrict__ src, float* __restrict__ dst,
                 int n, const int* __restrict__ flag)
{
    int f = *flag;
    for (int i = blockIdx.x * 256 + threadIdx.x; i < n; i += gridDim.x * 256)
        dst[i] = f ? ((const float*)src)[i] : b2f(((const bf16*)src)[i]);
}

__global__ __launch_bounds__(256)
void convert_bf16(const void* __restrict__ src, bf16* __restrict__ dst,
                  int n, const int* __restrict__ flag)
{
    int f = *flag;
    for (int i = blockIdx.x * 256 + threadIdx.x; i < n; i += gridDim.x * 256)
        dst[i] = f ? __float2bfloat16(((const float*)src)[i]) : ((const bf16*)src)[i];
}

// ---------------------------------------------------------------------------
// MFMA bf16 GEMM: 128x128 tile, BK=32, double-buffered LDS with raw barriers
// and manual vmcnt waits so prefetch stays in flight across the barrier.
// mode: 0 = fp32 out; 1 = fp32 out + residual; 2 = bf16 out + gelu;
//       3 = qkv head-split -> bf16 Q/K/V all [bh][t][64].
// ---------------------------------------------------------------------------
__global__ __launch_bounds__(256)
void mfma_gemm(const bf16* __restrict__ A, const bf16* __restrict__ W,
               const float* __restrict__ bias, const float* __restrict__ add,
               float* __restrict__ outF, bf16* __restrict__ outB,
               bf16* __restrict__ Qb, bf16* __restrict__ Kb, bf16* __restrict__ Vb,
               int M, int N, int K, int Ntok, int rowStride, int mode)
{
    __shared__ __align__(16) bf16 As[2][128 * 32];
    __shared__ __align__(16) bf16 Bs[2][128 * 32];
    int tid = threadIdx.x;
    int lane = tid & 63;
    int wave = tid >> 6;
    int wm = wave & 1, wn = wave >> 1;
    int m0 = blockIdx.y * 128, n0 = blockIdx.x * 128;

    int lr = lane >> 2;
    int lc = lane & 3;
    int ar0 = 32 * wave + lr;
    int ar1 = ar0 + 16;
    int ma0 = m0 + ar0; if (ma0 >= M) ma0 = M - 1;
    int ma1 = m0 + ar1; if (ma1 >= M) ma1 = M - 1;
    const bf16* aSrc0 = A + (size_t)((ma0 / Ntok) * rowStride + ma0 % Ntok) * K + lc * 8;
    const bf16* aSrc1 = A + (size_t)((ma1 / Ntok) * rowStride + ma1 % Ntok) * K + lc * 8;
    const bf16* bSrc0 = W + (size_t)(n0 + ar0) * K + lc * 8;
    const bf16* bSrc1 = W + (size_t)(n0 + ar1) * K + lc * 8;

    int fr = lane & 15;
    int fq = lane >> 4;
    int aOff = (wm * 64 + fr) * 32 + fq * 8;
    int bOff = (wn * 64 + fr) * 32 + fq * 8;

    f32x4 acc[4][4] = {};

    auto stage = [&](int buf) {
        async16(aSrc0, As[buf] + (32 * wave) * 32);
        async16(aSrc1, As[buf] + (32 * wave + 16) * 32);
        async16(bSrc0, Bs[buf] + (32 * wave) * 32);
        async16(bSrc1, Bs[buf] + (32 * wave + 16) * 32);
        aSrc0 += 32; aSrc1 += 32; bSrc0 += 32; bSrc1 += 32;
    };

    int nIter = K >> 5;
    stage(0);                                  // prologue: tile 0 in flight

    for (int it = 0; it < nIter; ++it) {
        int cur = it & 1;
        __builtin_amdgcn_sched_barrier(0);
        __builtin_amdgcn_s_waitcnt(WAIT_LGKM0);   // my reads of buf[cur^1] done
        __builtin_amdgcn_s_barrier();             // everyone done reading buf[cur^1]
        bool pre = (it + 1 < nIter);
        if (pre) {
            stage(cur ^ 1);                       // prefetch stays in flight
            __builtin_amdgcn_s_waitcnt(WAIT_VM4); // buf[cur] landed (4 newest outstanding)
        } else {
            __builtin_amdgcn_s_waitcnt(WAIT_VM0); // last tile: drain all
        }
        __builtin_amdgcn_s_barrier();             // buf[cur] visible to all waves
        __builtin_amdgcn_sched_barrier(0);

        const bf16* aR = As[cur] + aOff;
        const bf16* bR = Bs[cur] + bOff;
        short8 af[4], bfr[4];
        #pragma unroll
        for (int mi = 0; mi < 4; ++mi) af[mi] = *(const short8*)(aR + mi * 16 * 32);
        #pragma unroll
        for (int ni = 0; ni < 4; ++ni) bfr[ni] = *(const short8*)(bR + ni * 16 * 32);
        #pragma unroll
        for (int mi = 0; mi < 4; ++mi)
            #pragma unroll
            for (int ni = 0; ni < 4; ++ni)
                acc[mi][ni] = __builtin_amdgcn_mfma_f32_16x16x32_bf16(
                    af[mi], bfr[ni], acc[mi][ni], 0, 0, 0);
    }

    // epilogue: C/D layout col = lane&15, row = (lane>>4)*4 + r
    #pragma unroll
    for (int mi = 0; mi < 4; ++mi) {
        #pragma unroll
        for (int ni = 0; ni < 4; ++ni) {
            int n = n0 + wn * 64 + ni * 16 + fr;
            float bs = bias[n];
            #pragma unroll
            for (int r = 0; r < 4; ++r) {
                int m = m0 + wm * 64 + mi * 16 + fq * 4 + r;
                if (m >= M) continue;
                int bidx = m / Ntok, t = m - bidx * Ntok;
                size_t pr = (size_t)bidx * rowStride + t;
                float v = acc[mi][ni][r] + bs;
                if (mode == 0) {
                    outF[pr * N + n] = v;
                } else if (mode == 1) {
                    outF[pr * N + n] = v + add[pr * N + n];
                } else if (mode == 2) {
                    outB[pr * N + n] = __float2bfloat16(geluf(v));
                } else {
                    int which = n >= 1536 ? 2 : (n >= 768 ? 1 : 0);
                    int nn = n - which * 768;
                    int hh = nn >> 6, d = nn & 63;
                    bf16 bv = __float2bfloat16(v);
                    bf16* dst = which == 0 ? Qb : which == 1 ? Kb : Vb;
                    dst[((size_t)(bidx * HEADS + hh) * SEQMAX + t) * HD + d] = bv;
                }
            }
        }
    }
}

// ---------------------------------------------------------------------------
// Legacy fp32 GEMM (tiny head matmuls only).
// ---------------------------------------------------------------------------
__global__ __launch_bounds__(256)
void gemm_kernel(const float* __restrict__ A, const float* __restrict__ W,
                 const float* __restrict__ bias, const float* __restrict__ add,
                 float* __restrict__ C, int M, int N, int K,
                 int Ntok, int rowStride, int dogelu)
{
    __shared__ __align__(16) float As[16][68];
    __shared__ __align__(16) float Ws[16][68];
    int tid = threadIdx.x;
    int tx = tid & 15, ty = tid >> 4;
    int n0 = blockIdx.x * 64, m0 = blockIdx.y * 64;
    int lrow = tid >> 2;
    int lk   = (tid & 3) << 2;
    int am = m0 + lrow;
    bool aok = (am < M);
    const float* Arow = A;
    if (aok) {
        int pr = (am / Ntok) * rowStride + (am % Ntok);
        Arow = A + (size_t)pr * K;
    }
    int wn = n0 + lrow;
    const float* Wrow = (wn < N) ? (W + (size_t)wn * K) : nullptr;
    float acc[4][4] = {};
    for (int kk = 0; kk < K; kk += 16) {
        float4 av = make_float4(0.f, 0.f, 0.f, 0.f);
        if (aok) av = *(const float4*)(Arow + kk + lk);
        float4 wv = make_float4(0.f, 0.f, 0.f, 0.f);
        if (Wrow) wv = *(const float4*)(Wrow + kk + lk);
        __syncthreads();
        As[lk+0][lrow] = av.x; As[lk+1][lrow] = av.y;
        As[lk+2][lrow] = av.z; As[lk+3][lrow] = av.w;
        Ws[lk+0][lrow] = wv.x; Ws[lk+1][lrow] = wv.y;
        Ws[lk+2][lrow] = wv.z; Ws[lk+3][lrow] = wv.w;
        __syncthreads();
        #pragma unroll
        for (int k = 0; k < 16; ++k) {
            float4 a = *(const float4*)&As[k][ty << 2];
            float4 w = *(const float4*)&Ws[k][tx << 2];
            acc[0][0] += a.x*w.x; acc[0][1] += a.x*w.y; acc[0][2] += a.x*w.z; acc[0][3] += a.x*w.w;
            acc[1][0] += a.y*w.x; acc[1][1] += a.y*w.y; acc[1][2] += a.y*w.z; acc[1][3] += a.y*w.w;
            acc[2][0] += a.z*w.x; acc[2][1] += a.z*w.y; acc[2][2] += a.z*w.z; acc[2][3] += a.z*w.w;
            acc[3][0] += a.w*w.x; acc[3][1] += a.w*w.y; acc[3][2] += a.w*w.z; acc[3][3] += a.w*w.w;
        }
    }
    #pragma unroll
    for (int i = 0; i < 4; ++i) {
        int m = m0 + (ty << 2) + i;
        if (m >= M) continue;
        int pr = (m / Ntok) * rowStride + (m % Ntok);
        float* crow = C + (size_t)pr * N;
        const float* addrow = add ? (add + (size_t)pr * N) : nullptr;
        #pragma unroll
        for (int j = 0; j < 4; ++j) {
            int n = n0 + (tx << 2) + j;
            float v = acc[i][j] + bias[n];
            if (addrow) v += addrow[n];
            if (dogelu) v = geluf(v);
            crow[n] = v;
        }
    }
}

// ---------------------------------------------------------------------------
// LayerNorm fp32->bf16.
// ---------------------------------------------------------------------------
__global__ __launch_bounds__(256)
void ln_bf16_kernel(const float* __restrict__ src, bf16* __restrict__ dst,
                    const float* __restrict__ g, const float* __restrict__ bta, int Ntok)
{
    __shared__ float red[256];
    int blk = blockIdx.x;
    int t = blk % Ntok, b = blk / Ntok;
    size_t row = ((size_t)b * SEQMAX + t) * EMBED;
    int tid = threadIdx.x;
    float v0 = src[row + tid], v1 = src[row + tid + 256], v2 = src[row + tid + 512];
    red[tid] = v0 + v1 + v2;
    __syncthreads();
    for (int off = 128; off; off >>= 1) { if (tid < off) red[tid] += red[tid + off]; __syncthreads(); }
    float mu = red[0] * (1.0f / EMBED);
    __syncthreads();
    float d0 = v0 - mu, d1 = v1 - mu, d2 = v2 - mu;
    red[tid] = d0*d0 + d1*d1 + d2*d2;
    __syncthreads();
    for (int off = 128; off; off >>= 1) { if (tid < off) red[tid] += red[tid + off]; __syncthreads(); }
    float rs = rsqrtf(red[0] * (1.0f / EMBED) + 1e-5f);
    dst[row + tid]       = __float2bfloat16(d0 * rs * g[tid]       + bta[tid]);
    dst[row + tid + 256] = __float2bfloat16(d1 * rs * g[tid + 256] + bta[tid + 256]);
    dst[row + tid + 512] = __float2bfloat16(d2 * rs * g[tid + 512] + bta[tid + 512]);
}

// LayerNorm fp32->fp32.
__global__ __launch_bounds__(256)
void ln_kernel(const float* __restrict__ src, float* __restrict__ dst,
               const float* __restrict__ g, const float* __restrict__ bta, int Ntok)
{
    __shared__ float red[256];
    int blk = blockIdx.x;
    int t = blk % Ntok, b = blk / Ntok;
    size_t row = ((size_t)b * SEQMAX + t) * EMBED;
    int tid = threadIdx.x;
    float v0 = src[row + tid], v1 = src[row + tid + 256], v2 = src[row + tid + 512];
    red[tid] = v0 + v1 + v2;
    __syncthreads();
    for (int off = 128; off; off >>= 1) { if (tid < off) red[tid] += red[tid + off]; __syncthreads(); }
    float mu = red[0] * (1.0f / EMBED);
    __syncthreads();
    float d0 = v0 - mu, d1 = v1 - mu, d2 = v2 - mu;
    red[tid] = d0*d0 + d1*d1 + d2*d2;
    __syncthreads();
    for (int off = 128; off; off >>= 1) { if (tid < off) red[tid] += red[tid + off]; __syncthreads(); }
    float rs = rsqrtf(red[0] * (1.0f / EMBED) + 1e-5f);
    dst[row + tid]       = d0 * rs * g[tid]       + bta[tid];
    dst[row + tid + 256] = d1 * rs * g[tid + 256] + bta[tid + 256];
    dst[row + tid + 512] = d2 * rs * g[tid + 512] + bta[tid + 512];
}

// ---------------------------------------------------------------------------
// MFMA flash attention. Block = (bh, 64-query tile); wave w owns 16 q-rows.
// Q/K/V bf16 [bh][t][64]. V tile transposed via LDS each k-step; P converts
// C-layout -> A-layout via per-wave LDS patch.
// ---------------------------------------------------------------------------
__global__ __launch_bounds__(256)
void flash_mfma(const bf16* __restrict__ Qh, const bf16* __restrict__ Kh,
                const bf16* __restrict__ Vh, bf16* __restrict__ O, int Ntok)
{
    __shared__ __align__(16) unsigned short Plds[4][16 * PSTR];
    __shared__ __align__(16) unsigned short VTl[64 * VSTR];
    int bh = blockIdx.x;
    int b = bh / HEADS, h = bh % HEADS;
    int t0 = blockIdx.y * 64;
    int tid = threadIdx.x;
    int lane = tid & 63, w = tid >> 6;
    int fr = lane & 15, fq = lane >> 4;

    const bf16* Qb = Qh + (size_t)bh * SEQMAX * HD;
    const bf16* Kb = Kh + (size_t)bh * SEQMAX * HD;
    const bf16* Vbm = Vh + (size_t)bh * SEQMAX * HD;

    int tq = t0 + w * 16 + fr; if (tq >= Ntok) tq = Ntok - 1;
    short8 aq0 = *(const short8*)(Qb + (size_t)tq * HD + fq * 8);
    short8 aq1 = *(const short8*)(Qb + (size_t)tq * HD + fq * 8 + 32);

    float mrow[4], lrow[4];
    f32x4 oacc[4];
    #pragma unroll
    for (int r = 0; r < 4; ++r) { mrow[r] = -1e30f; lrow[r] = 0.f; }
    #pragma unroll
    for (int dg = 0; dg < 4; ++dg) oacc[dg] = (f32x4){0.f, 0.f, 0.f, 0.f};

    unsigned short* Pw = Plds[w];

    for (int k0 = 0; k0 < Ntok; k0 += 64) {
        __syncthreads();    // prev iteration's VTl / Plds reads complete

        // stage V tile transposed: VTl[d][key_local], zero-padded
        #pragma unroll
        for (int p = tid; p < 64 * 32; p += 256) {
            int d2 = p & 31, tl = p >> 5;
            int key = k0 + tl;
            unsigned v = 0;
            if (key < Ntok) v = *(const unsigned*)(Vbm + (size_t)key * HD + d2 * 2);
            VTl[(2 * d2) * VSTR + tl]     = (unsigned short)(v & 0xFFFFu);
            VTl[(2 * d2 + 1) * VSTR + tl] = (unsigned short)(v >> 16);
        }

        // S = Q K^T for this 64-key tile
        float s[4][4];
        #pragma unroll
        for (int kg = 0; kg < 4; ++kg) {
            int key = k0 + kg * 16 + fr;
            int keyc = key < Ntok ? key : Ntok - 1;
            short8 bk0 = *(const short8*)(Kb + (size_t)keyc * HD + fq * 8);
            short8 bk1 = *(const short8*)(Kb + (size_t)keyc * HD + fq * 8 + 32);
            f32x4 sa = (f32x4){0.f, 0.f, 0.f, 0.f};
            sa = __builtin_amdgcn_mfma_f32_16x16x32_bf16(aq0, bk0, sa, 0, 0, 0);
            sa = __builtin_amdgcn_mfma_f32_16x16x32_bf16(aq1, bk1, sa, 0, 0, 0);
            bool ok = key < Ntok;
            #pragma unroll
            for (int r = 0; r < 4; ++r) s[kg][r] = ok ? sa[r] * 0.125f : -1e30f;
        }

        // online softmax; per-lane rows are fq*4+r (C layout)
        #pragma unroll
        for (int r = 0; r < 4; ++r) {
            float rm = fmaxf(fmaxf(s[0][r], s[1][r]), fmaxf(s[2][r], s[3][r]));
            rm = fmaxf(rm, __shfl_xor(rm, 1));
            rm = fmaxf(rm, __shfl_xor(rm, 2));
            rm = fmaxf(rm, __shfl_xor(rm, 4));
            rm = fmaxf(rm, __shfl_xor(rm, 8));
            float mnew = fmaxf(mrow[r], rm);
            float alpha = __expf(mrow[r] - mnew);
            mrow[r] = mnew;
            float sum = 0.f;
            #pragma unroll
            for (int kg = 0; kg < 4; ++kg) {
                float p = __expf(s[kg][r] - mnew);
                s[kg][r] = p; sum += p;
            }
            sum += __shfl_xor(sum, 1); sum += __shfl_xor(sum, 2);
            sum += __shfl_xor(sum, 4); sum += __shfl_xor(sum, 8);
            lrow[r] = lrow[r] * alpha + sum;
            #pragma unroll
            for (int dg = 0; dg < 4; ++dg) oacc[dg][r] *= alpha;
        }

        // P: C-layout regs -> LDS [q_local][key]
        #pragma unroll
        for (int kg = 0; kg < 4; ++kg)
            #pragma unroll
            for (int r = 0; r < 4; ++r) {
                bf16 pb = __float2bfloat16(s[kg][r]);
                Pw[(fq * 4 + r) * PSTR + kg * 16 + fr] = *(unsigned short*)&pb;
            }
        __syncthreads();   // VTl + Plds visible

        short8 ap0 = *(const short8*)(Pw + fr * PSTR + fq * 8);
        short8 ap1 = *(const short8*)(Pw + fr * PSTR + fq * 8 + 32);

        #pragma unroll
        for (int dg = 0; dg < 4; ++dg) {
            int d = dg * 16 + fr;
            short8 bv0 = *(const short8*)(VTl + d * VSTR + fq * 8);
            short8 bv1 = *(const short8*)(VTl + d * VSTR + fq * 8 + 32);
            oacc[dg] = __builtin_amdgcn_mfma_f32_16x16x32_bf16(ap0, bv0, oacc[dg], 0, 0, 0);
            oacc[dg] = __builtin_amdgcn_mfma_f32_16x16x32_bf16(ap1, bv1, oacc[dg], 0, 0, 0);
        }
    }

    #pragma unroll
    for (int r = 0; r < 4; ++r) {
        int t = t0 + w * 16 + fq * 4 + r;
        if (t >= Ntok) continue;
        float inv = 1.0f / lrow[r];
        bf16* dst = O + ((size_t)b * SEQMAX + t) * EMBED + h * HD;
        #pragma unroll
        for (int dg = 0; dg < 4; ++dg)
            dst[dg * 16 + fr] = __float2bfloat16(oacc[dg][r] * inv);
    }
}

// ---------------------------------------------------------------------------
__global__ __launch_bounds__(256)
void patch_gather(const void* __restrict__ img, bf16* __restrict__ Ap,
                  const int* __restrict__ flag)
{
    int f = *flag;
    int idx = blockIdx.x * 256 + threadIdx.x;
    if (idx >= NB * NPATCH * EMBED) return;
    int col = idx % EMBED;
    int row = idx / EMBED;
    int t = row % NPATCH, b = row / NPATCH;
    int c = col >> 8;
    int pr = (col >> 4) & 15;
    int pc = col & 15;
    int gr = t / GRID, gc = t % GRID;
    size_t off = ((size_t)(b * 3 + c) * IMGSZ + gr * PATCH + pr) * IMGSZ + gc * PATCH + pc;
    float v = f ? ((const float*)img)[off] : b2f(((const bf16*)img)[off]);
    Ap[idx] = __float2bfloat16(v);
}

__global__ __launch_bounds__(256)
void posadd_kernel(const float* __restrict__ PEO, const float* __restrict__ sp,
                   const float* __restrict__ ip, float* __restrict__ X, int imgIdx)
{
    int idx = blockIdx.x * 256 + threadIdx.x;
    if (idx >= NB * NPATCH * EMBED) return;
    int e = idx % EMBED;
    int row = idx / EMBED;
    int t = row % NPATCH, b = row / NPATCH;
    float pos = (e < 384) ? sp[t * 384 + e] : ip[imgIdx * 384 + (e - 384)];
    X[((size_t)b * SEQMAX + imgIdx * NPATCH + t) * EMBED + e] = PEO[idx] + pos;
}

__global__ __launch_bounds__(768)
void mean_kernel(const float* __restrict__ H, float* __restrict__ Mn)
{
    int b = blockIdx.x;
    int e = threadIdx.x;
    float s = 0.f;
    for (int t = 0; t < SEQMAX; ++t) s += H[((size_t)b * SEQMAX + t) * EMBED + e];
    Mn[b * EMBED + e] = s * (1.0f / SEQMAX);
}

__global__ __launch_bounds__(256)
void bcast_kernel(const float* __restrict__ P, void* __restrict__ out,
                  const int* __restrict__ flag)
{
    int f = *flag;
    int idx = blockIdx.x * 256 + threadIdx.x;
    if (idx >= NB * IMGSZ * IMGSZ) return;
    int c = idx % IMGSZ;
    int r = (idx / IMGSZ) % IMGSZ;
    int b = idx / (IMGSZ * IMGSZ);
    float v = P[b * 256 + (r & 15) * 16 + (c & 15)];
    if (f) ((float*)out)[idx] = v;
    else   ((bf16*)out)[idx] = __float2bfloat16(v);
}

// ---------------------------------------------------------------------------
extern "C" void kernel_launch(void* const* d_in, const int* in_sizes, int n_in,
                              void* d_out, int out_size, void* d_ws, size_t ws_size,
                              hipStream_t stream)
{
    (void)n_in; (void)out_size; (void)ws_size;
    const void* img[4] = {d_in[0], d_in[1], d_in[2], d_in[3]};

    float* ws = (float*)d_ws;
    int* flag = (int*)ws;

    detect_kernel<<<1, 256, 0, stream>>>((const unsigned short*)d_in[0], flag);

    const bool isBig[28] = {0,0,0,0, 1,0,0,0, 0,0,1,0, 1,0,0,0, 1,0,1,0, 0,0,0,0, 0,0,0,0};
    float* fArena = ws + 16;
    float* fPtr[28] = {};
    {
        float* p = fArena;
        for (int i = 4; i < 28; ++i) {
            if (isBig[i]) continue;
            fPtr[i] = p;
            int n = in_sizes[i];
            int g = (n + 255) / 256; if (g > 2048) g = 2048;
            convert_f32<<<g, 256, 0, stream>>>(d_in[i], p, n, flag);
            p += n;
        }
        fArena = p;
    }
    bf16* bPtr[28] = {};
    {
        bf16* p = (bf16*)fArena;
        for (int i = 4; i < 28; ++i) {
            if (!isBig[i]) continue;
            bPtr[i] = p;
            int n = in_sizes[i];
            int g = (n + 255) / 256; if (g > 4096) g = 4096;
            convert_bf16<<<g, 256, 0, stream>>>(d_in[i], p, n, flag);
            p += n;
        }
        size_t off = p - (bf16*)ws;
        off = (off + 7) & ~(size_t)7;
        fArena = (float*)((bf16*)ws + off);
    }
    const bf16* pe_w   = bPtr[4];
    const bf16* qkv_w  = bPtr[10];
    const bf16* proj_w = bPtr[12];
    const bf16* fc1_w  = bPtr[16];
    const bf16* fc2_w  = bPtr[18];
    const float* pe_b      = fPtr[5];
    const float* sp        = fPtr[6];
    const float* ip        = fPtr[7];
    const float* ln_attn_g = fPtr[8];
    const float* ln_attn_b = fPtr[9];
    const float* qkv_b     = fPtr[11];
    const float* proj_b    = fPtr[13];
    const float* ln1_g     = fPtr[14];
    const float* ln1_b     = fPtr[15];
    const float* fc1_b     = fPtr[17];
    const float* fc2_b     = fPtr[19];
    const float* ln2_g     = fPtr[20];
    const float* ln2_b     = fPtr[21];
    const float* final_g   = fPtr[22];
    const float* final_b   = fPtr[23];
    const float* head_w1   = fPtr[24];
    const float* head_b1   = fPtr[25];
    const float* head_w2   = fPtr[26];
    const float* head_b2   = fPtr[27];

    const size_t SEQ = (size_t)NB * SEQMAX * EMBED;          // 4,816,896
    const size_t HID_ELEMS = (size_t)NB * SEQMAX * HIDDEN;   // 19,267,584
    const size_t EMB_ELEMS = (size_t)NB * NPATCH * EMBED;    // 1,204,224
    float* X    = fArena;
    float* H    = X + SEQ;
    float* O    = H + SEQ;
    float* PEO  = O + SEQ;
    float* MEAN = PEO + EMB_ELEMS;
    float* HH   = MEAN + NB * EMBED;
    float* PTCH = HH + NB * EMBED;
    bf16* Hb    = (bf16*)(PTCH + NB * 256 + 16);
    bf16* Ob    = Hb + SEQ;
    bf16* Gb    = Ob + SEQ;
    bf16* PEb   = Gb + HID_ELEMS;
    bf16* Qb    = PEb + EMB_ELEMS;
    bf16* Kb    = Qb + SEQ;
    bf16* Vb    = Kb + SEQ;

    const int nEmb = NB * NPATCH * EMBED;

    auto embed = [&](int i) {
        patch_gather<<<(nEmb + 255) / 256, 256, 0, stream>>>(img[i], PEb, flag);
        dim3 g(EMBED / 128, (NB * NPATCH + 127) / 128);
        mfma_gemm<<<g, 256, 0, stream>>>(PEb, pe_w + (size_t)i * EMBED * EMBED,
                                         pe_b + i * EMBED, nullptr, PEO, nullptr,
                                         nullptr, nullptr, nullptr,
                                         NB * NPATCH, EMBED, EMBED,
                                         NB * NPATCH, NB * NPATCH, 0);
        posadd_kernel<<<(nEmb + 255) / 256, 256, 0, stream>>>(PEO, sp, ip, X, i);
    };

    auto block = [&](int i, int Ntok) {
        int M = NB * Ntok;
        int gy = (M + 127) / 128;
        ln_bf16_kernel<<<M, 256, 0, stream>>>(X, Hb, ln_attn_g + i * EMBED, ln_attn_b + i * EMBED, Ntok);
        mfma_gemm<<<dim3(QKVD / 128, gy), 256, 0, stream>>>(
            Hb, qkv_w + (size_t)i * QKVD * EMBED, qkv_b + i * QKVD, nullptr,
            nullptr, nullptr, Qb, Kb, Vb, M, QKVD, EMBED, Ntok, SEQMAX, 3);
        dim3 fg(NB * HEADS, (Ntok + 63) / 64);
        flash_mfma<<<fg, 256, 0, stream>>>(Qb, Kb, Vb, Ob, Ntok);
        mfma_gemm<<<dim3(EMBED / 128, gy), 256, 0, stream>>>(
            Ob, proj_w + (size_t)i * EMBED * EMBED, proj_b + i * EMBED, X,
            X, nullptr, nullptr, nullptr, nullptr, M, EMBED, EMBED, Ntok, SEQMAX, 1);
        ln_bf16_kernel<<<M, 256, 0, stream>>>(X, Hb, ln1_g + i * EMBED, ln1_b + i * EMBED, Ntok);
        mfma_gemm<<<dim3(HIDDEN / 128, gy), 256, 0, stream>>>(
            Hb, fc1_w + (size_t)i * HIDDEN * EMBED, fc1_b + i * HIDDEN, nullptr,
            nullptr, Gb, nullptr, nullptr, nullptr, M, HIDDEN, EMBED, Ntok, SEQMAX, 2);
        mfma_gemm<<<dim3(EMBED / 128, gy), 256, 0, stream>>>(
            Gb, fc2_w + (size_t)i * EMBED * HIDDEN, fc2_b + i * EMBED, X,
            O, nullptr, nullptr, nullptr, nullptr, M, EMBED, HIDDEN, Ntok, SEQMAX, 1);
        ln_kernel<<<M, 256, 0, stream>>>(O, X, ln2_g + i * EMBED, ln2_b + i * EMBED, Ntok);
    };

    embed(0);
    embed(1);
    block(0, 392);
    embed(2);
    block(1, 588);
    embed(3);
    block(2, 784);

    ln_kernel<<<NB * SEQMAX, 256, 0, stream>>>(X, H, final_g, final_b, SEQMAX);
    mean_kernel<<<NB, 768, 0, stream>>>(H, MEAN);
    gemm_kernel<<<dim3(EMBED / 64, 1), 256, 0, stream>>>(
        MEAN, head_w1, head_b1, nullptr, HH, NB, EMBED, EMBED, NB, NB, 1);
    gemm_kernel<<<dim3(256 / 64, 1), 256, 0, stream>>>(
        HH, head_w2, head_b2, nullptr, PTCH, NB, 256, EMBED, NB, NB, 0);
    bcast_kernel<<<(NB * IMGSZ * IMGSZ + 255) / 256, 256, 0, stream>>>(PTCH, d_out, flag);
}

// Round 8
// 1686.275 us; speedup vs baseline: 5.9839x; 1.0297x over previous
//
#include <hip/hip_runtime.h>
#include <hip/hip_bf16.h>
#include <math.h>

#define EMBED 768
#define QKVD 2304
#define HEADS 12
#define HD 64
#define HIDDEN 3072
#define NPATCH 196
#define SEQMAX 784
#define NB 8
#define IMGSZ 224
#define GRID 14
#define PATCH 16
#define PSTR 72
#define VROW 832

typedef __hip_bfloat16 bf16;
typedef __attribute__((ext_vector_type(8))) short short8;
typedef __attribute__((ext_vector_type(4))) float f32x4;

__device__ __forceinline__ float b2f(bf16 v) { return __bfloat162float(v); }
__device__ __forceinline__ float geluf(float x) {
    return 0.5f * x * (1.0f + erff(x * 0.70710678118654752f));
}

// async global->LDS, 16B per lane. LDS dest is wave-uniform base + lane*16.
__device__ __forceinline__ void async16(const bf16* g, bf16* l) {
    __builtin_amdgcn_global_load_lds(
        (const __attribute__((address_space(1))) unsigned int*)g,
        (__attribute__((address_space(3))) unsigned int*)l,
        16, 0, 0);
}

#define WAIT_VM0   0x0F70   // vmcnt(0)
#define WAIT_VM4   0x0F74   // vmcnt(4)
#define WAIT_LGKM0 0xC07F   // lgkmcnt(0)

// ---------------------------------------------------------------------------
// Dtype detection (bf16 vs fp32 inputs).
// ---------------------------------------------------------------------------
__global__ __launch_bounds__(256)
void detect_kernel(const unsigned short* __restrict__ raw, int* __restrict__ flag)
{
    __shared__ int bad;
    if (threadIdx.x == 0) bad = 0;
    __syncthreads();
    for (int i = threadIdx.x; i < 8192; i += 256) {
        unsigned int u = (unsigned int)raw[i] << 16;
        float v = __uint_as_float(u);
        if (!(fabsf(v) <= 1e4f)) bad = 1;
    }
    __syncthreads();
    if (threadIdx.x == 0) *flag = bad;
}

// ---------------------------------------------------------------------------
// Fused converters: one kernel per destination dtype, struct args.
// ---------------------------------------------------------------------------
struct CvtF32 {
    const void* src[19];
    int n[19];
    int dstOff[19];
    int blkOff[20];
};
__global__ __launch_bounds__(256)
void convert_f32_all(CvtF32 c, float* __restrict__ base, const int* __restrict__ flag)
{
    int f = *flag;
    int b = blockIdx.x;
    int i = 0;
    #pragma unroll
    for (int j = 0; j < 19; ++j) if (b >= c.blkOff[j + 1]) i = j + 1;
    int e = ((b - c.blkOff[i]) * 256 + threadIdx.x) * 4;
    if (e >= c.n[i]) return;
    float* dst = base + c.dstOff[i] + e;
    if (f) {
        *(float4*)dst = *(const float4*)((const float*)c.src[i] + e);
    } else {
        const bf16* s = (const bf16*)c.src[i] + e;
        dst[0] = b2f(s[0]); dst[1] = b2f(s[1]); dst[2] = b2f(s[2]); dst[3] = b2f(s[3]);
    }
}

struct CvtB16 {
    const void* src[5];
    int n[5];
    int dstOff[5];
    int blkOff[6];
};
__global__ __launch_bounds__(256)
void convert_b16_all(CvtB16 c, bf16* __restrict__ base, const int* __restrict__ flag)
{
    int f = *flag;
    int b = blockIdx.x;
    int i = 0;
    #pragma unroll
    for (int j = 0; j < 5; ++j) if (b >= c.blkOff[j + 1]) i = j + 1;
    int e = ((b - c.blkOff[i]) * 256 + threadIdx.x) * 4;
    if (e >= c.n[i]) return;
    bf16* dst = base + (size_t)c.dstOff[i] + e;
    if (f) {
        float4 v = *(const float4*)((const float*)c.src[i] + e);
        dst[0] = __float2bfloat16(v.x); dst[1] = __float2bfloat16(v.y);
        dst[2] = __float2bfloat16(v.z); dst[3] = __float2bfloat16(v.w);
    } else {
        *(uint2*)dst = *(const uint2*)((const bf16*)c.src[i] + e);
    }
}

// ---------------------------------------------------------------------------
// MFMA bf16 GEMM: 128x128 tile, BK=32, double-buffered LDS with raw barriers.
// mode: 0 = fp32 out; 1 = fp32 out + residual; 2 = bf16 out + gelu;
//       3 = qkv head-split -> bf16 Q/K/V all [bh][t][64].
// ---------------------------------------------------------------------------
__global__ __launch_bounds__(256)
void mfma_gemm(const bf16* __restrict__ A, const bf16* __restrict__ W,
               const float* __restrict__ bias, const float* __restrict__ add,
               float* __restrict__ outF, bf16* __restrict__ outB,
               bf16* __restrict__ Qb, bf16* __restrict__ Kb, bf16* __restrict__ Vb,
               int M, int N, int K, int Ntok, int rowStride, int mode)
{
    __shared__ __align__(16) bf16 As[2][128 * 32];
    __shared__ __align__(16) bf16 Bs[2][128 * 32];
    int tid = threadIdx.x;
    int lane = tid & 63;
    int wave = tid >> 6;
    int wm = wave & 1, wn = wave >> 1;
    int m0 = blockIdx.y * 128, n0 = blockIdx.x * 128;

    int lr = lane >> 2;
    int lc = lane & 3;
    int ar0 = 32 * wave + lr;
    int ar1 = ar0 + 16;
    int ma0 = m0 + ar0; if (ma0 >= M) ma0 = M - 1;
    int ma1 = m0 + ar1; if (ma1 >= M) ma1 = M - 1;
    const bf16* aSrc0 = A + (size_t)((ma0 / Ntok) * rowStride + ma0 % Ntok) * K + lc * 8;
    const bf16* aSrc1 = A + (size_t)((ma1 / Ntok) * rowStride + ma1 % Ntok) * K + lc * 8;
    const bf16* bSrc0 = W + (size_t)(n0 + ar0) * K + lc * 8;
    const bf16* bSrc1 = W + (size_t)(n0 + ar1) * K + lc * 8;

    int fr = lane & 15;
    int fq = lane >> 4;
    int aOff = (wm * 64 + fr) * 32 + fq * 8;
    int bOff = (wn * 64 + fr) * 32 + fq * 8;

    f32x4 acc[4][4] = {};

    auto stage = [&](int buf) {
        async16(aSrc0, As[buf] + (32 * wave) * 32);
        async16(aSrc1, As[buf] + (32 * wave + 16) * 32);
        async16(bSrc0, Bs[buf] + (32 * wave) * 32);
        async16(bSrc1, Bs[buf] + (32 * wave + 16) * 32);
        aSrc0 += 32; aSrc1 += 32; bSrc0 += 32; bSrc1 += 32;
    };

    int nIter = K >> 5;
    stage(0);

    for (int it = 0; it < nIter; ++it) {
        int cur = it & 1;
        __builtin_amdgcn_sched_barrier(0);
        __builtin_amdgcn_s_waitcnt(WAIT_LGKM0);
        __builtin_amdgcn_s_barrier();
        bool pre = (it + 1 < nIter);
        if (pre) {
            stage(cur ^ 1);
            __builtin_amdgcn_s_waitcnt(WAIT_VM4);
        } else {
            __builtin_amdgcn_s_waitcnt(WAIT_VM0);
        }
        __builtin_amdgcn_s_barrier();
        __builtin_amdgcn_sched_barrier(0);

        const bf16* aR = As[cur] + aOff;
        const bf16* bR = Bs[cur] + bOff;
        short8 af[4], bfr[4];
        #pragma unroll
        for (int mi = 0; mi < 4; ++mi) af[mi] = *(const short8*)(aR + mi * 16 * 32);
        #pragma unroll
        for (int ni = 0; ni < 4; ++ni) bfr[ni] = *(const short8*)(bR + ni * 16 * 32);
        #pragma unroll
        for (int mi = 0; mi < 4; ++mi)
            #pragma unroll
            for (int ni = 0; ni < 4; ++ni)
                acc[mi][ni] = __builtin_amdgcn_mfma_f32_16x16x32_bf16(
                    af[mi], bfr[ni], acc[mi][ni], 0, 0, 0);
    }

    #pragma unroll
    for (int mi = 0; mi < 4; ++mi) {
        #pragma unroll
        for (int ni = 0; ni < 4; ++ni) {
            int n = n0 + wn * 64 + ni * 16 + fr;
            float bs = bias[n];
            #pragma unroll
            for (int r = 0; r < 4; ++r) {
                int m = m0 + wm * 64 + mi * 16 + fq * 4 + r;
                if (m >= M) continue;
                int bidx = m / Ntok, t = m - bidx * Ntok;
                size_t pr = (size_t)bidx * rowStride + t;
                float v = acc[mi][ni][r] + bs;
                if (mode == 0) {
                    outF[pr * N + n] = v;
                } else if (mode == 1) {
                    outF[pr * N + n] = v + add[pr * N + n];
                } else if (mode == 2) {
                    outB[pr * N + n] = __float2bfloat16(geluf(v));
                } else {
                    int which = n >= 1536 ? 2 : (n >= 768 ? 1 : 0);
                    int nn = n - which * 768;
                    int hh = nn >> 6, d = nn & 63;
                    bf16 bv = __float2bfloat16(v);
                    bf16* dst = which == 0 ? Qb : which == 1 ? Kb : Vb;
                    dst[((size_t)(bidx * HEADS + hh) * SEQMAX + t) * HD + d] = bv;
                }
            }
        }
    }
}

// ---------------------------------------------------------------------------
// Legacy fp32 GEMM (tiny head matmuls only).
// ---------------------------------------------------------------------------
__global__ __launch_bounds__(256)
void gemm_kernel(const float* __restrict__ A, const float* __restrict__ W,
                 const float* __restrict__ bias, const float* __restrict__ add,
                 float* __restrict__ C, int M, int N, int K,
                 int Ntok, int rowStride, int dogelu)
{
    __shared__ __align__(16) float As[16][68];
    __shared__ __align__(16) float Ws[16][68];
    int tid = threadIdx.x;
    int tx = tid & 15, ty = tid >> 4;
    int n0 = blockIdx.x * 64, m0 = blockIdx.y * 64;
    int lrow = tid >> 2;
    int lk   = (tid & 3) << 2;
    int am = m0 + lrow;
    bool aok = (am < M);
    const float* Arow = A;
    if (aok) {
        int pr = (am / Ntok) * rowStride + (am % Ntok);
        Arow = A + (size_t)pr * K;
    }
    int wn = n0 + lrow;
    const float* Wrow = (wn < N) ? (W + (size_t)wn * K) : nullptr;
    float acc[4][4] = {};
    for (int kk = 0; kk < K; kk += 16) {
        float4 av = make_float4(0.f, 0.f, 0.f, 0.f);
        if (aok) av = *(const float4*)(Arow + kk + lk);
        float4 wv = make_float4(0.f, 0.f, 0.f, 0.f);
        if (Wrow) wv = *(const float4*)(Wrow + kk + lk);
        __syncthreads();
        As[lk+0][lrow] = av.x; As[lk+1][lrow] = av.y;
        As[lk+2][lrow] = av.z; As[lk+3][lrow] = av.w;
        Ws[lk+0][lrow] = wv.x; Ws[lk+1][lrow] = wv.y;
        Ws[lk+2][lrow] = wv.z; Ws[lk+3][lrow] = wv.w;
        __syncthreads();
        #pragma unroll
        for (int k = 0; k < 16; ++k) {
            float4 a = *(const float4*)&As[k][ty << 2];
            float4 w = *(const float4*)&Ws[k][tx << 2];
            acc[0][0] += a.x*w.x; acc[0][1] += a.x*w.y; acc[0][2] += a.x*w.z; acc[0][3] += a.x*w.w;
            acc[1][0] += a.y*w.x; acc[1][1] += a.y*w.y; acc[1][2] += a.y*w.z; acc[1][3] += a.y*w.w;
            acc[2][0] += a.z*w.x; acc[2][1] += a.z*w.y; acc[2][2] += a.z*w.z; acc[2][3] += a.z*w.w;
            acc[3][0] += a.w*w.x; acc[3][1] += a.w*w.y; acc[3][2] += a.w*w.z; acc[3][3] += a.w*w.w;
        }
    }
    #pragma unroll
    for (int i = 0; i < 4; ++i) {
        int m = m0 + (ty << 2) + i;
        if (m >= M) continue;
        int pr = (m / Ntok) * rowStride + (m % Ntok);
        float* crow = C + (size_t)pr * N;
        const float* addrow = add ? (add + (size_t)pr * N) : nullptr;
        #pragma unroll
        for (int j = 0; j < 4; ++j) {
            int n = n0 + (tx << 2) + j;
            float v = acc[i][j] + bias[n];
            if (addrow) v += addrow[n];
            if (dogelu) v = geluf(v);
            crow[n] = v;
        }
    }
}

// ---------------------------------------------------------------------------
// LayerNorms.
// ---------------------------------------------------------------------------
__global__ __launch_bounds__(256)
void ln_bf16_kernel(const float* __restrict__ src, bf16* __restrict__ dst,
                    const float* __restrict__ g, const float* __restrict__ bta, int Ntok)
{
    __shared__ float red[256];
    int blk = blockIdx.x;
    int t = blk % Ntok, b = blk / Ntok;
    size_t row = ((size_t)b * SEQMAX + t) * EMBED;
    int tid = threadIdx.x;
    float v0 = src[row + tid], v1 = src[row + tid + 256], v2 = src[row + tid + 512];
    red[tid] = v0 + v1 + v2;
    __syncthreads();
    for (int off = 128; off; off >>= 1) { if (tid < off) red[tid] += red[tid + off]; __syncthreads(); }
    float mu = red[0] * (1.0f / EMBED);
    __syncthreads();
    float d0 = v0 - mu, d1 = v1 - mu, d2 = v2 - mu;
    red[tid] = d0*d0 + d1*d1 + d2*d2;
    __syncthreads();
    for (int off = 128; off; off >>= 1) { if (tid < off) red[tid] += red[tid + off]; __syncthreads(); }
    float rs = rsqrtf(red[0] * (1.0f / EMBED) + 1e-5f);
    dst[row + tid]       = __float2bfloat16(d0 * rs * g[tid]       + bta[tid]);
    dst[row + tid + 256] = __float2bfloat16(d1 * rs * g[tid + 256] + bta[tid + 256]);
    dst[row + tid + 512] = __float2bfloat16(d2 * rs * g[tid + 512] + bta[tid + 512]);
}

__global__ __launch_bounds__(256)
void ln_kernel(const float* __restrict__ src, float* __restrict__ dst,
               const float* __restrict__ g, const float* __restrict__ bta, int Ntok)
{
    __shared__ float red[256];
    int blk = blockIdx.x;
    int t = blk % Ntok, b = blk / Ntok;
    size_t row = ((size_t)b * SEQMAX + t) * EMBED;
    int tid = threadIdx.x;
    float v0 = src[row + tid], v1 = src[row + tid + 256], v2 = src[row + tid + 512];
    red[tid] = v0 + v1 + v2;
    __syncthreads();
    for (int off = 128; off; off >>= 1) { if (tid < off) red[tid] += red[tid + off]; __syncthreads(); }
    float mu = red[0] * (1.0f / EMBED);
    __syncthreads();
    float d0 = v0 - mu, d1 = v1 - mu, d2 = v2 - mu;
    red[tid] = d0*d0 + d1*d1 + d2*d2;
    __syncthreads();
    for (int off = 128; off; off >>= 1) { if (tid < off) red[tid] += red[tid + off]; __syncthreads(); }
    float rs = rsqrtf(red[0] * (1.0f / EMBED) + 1e-5f);
    dst[row + tid]       = d0 * rs * g[tid]       + bta[tid];
    dst[row + tid + 256] = d1 * rs * g[tid + 256] + bta[tid + 256];
    dst[row + tid + 512] = d2 * rs * g[tid + 512] + bta[tid + 512];
}

// ---------------------------------------------------------------------------
// V transpose: V [bh][t][64] -> VT [bh*64+d][VROW], zero-padded keys>=Ntok.
// Block = (bh, 64-key tile). LDS tile [64 keys][66 shorts].
// ---------------------------------------------------------------------------
__global__ __launch_bounds__(256)
void vtrans_kernel(const bf16* __restrict__ Vh, bf16* __restrict__ VT, int Ntok)
{
    __shared__ unsigned short Lt[64 * 66];
    int bh = blockIdx.x;
    int k0 = blockIdx.y * 64;
    const bf16* Vb = Vh + (size_t)bh * SEQMAX * HD;
    int tid = threadIdx.x;
    #pragma unroll
    for (int pass = 0; pass < 8; ++pass) {
        int key_l = (tid >> 5) + pass * 8;
        int d2 = tid & 31;
        unsigned v = 0;
        if (k0 + key_l < Ntok)
            v = *(const unsigned*)(Vb + (size_t)(k0 + key_l) * HD + d2 * 2);
        *(unsigned*)&Lt[key_l * 66 + 2 * d2] = v;
    }
    __syncthreads();
    #pragma unroll
    for (int pass = 0; pass < 8; ++pass) {
        int d = (tid >> 5) + pass * 8;
        int kp = tid & 31;
        unsigned lo = Lt[(2 * kp) * 66 + d];
        unsigned hi = Lt[(2 * kp + 1) * 66 + d];
        *(unsigned*)(VT + ((size_t)bh * HD + d) * VROW + k0 + 2 * kp) = lo | (hi << 16);
    }
}

// ---------------------------------------------------------------------------
// MFMA flash attention, barrier-free. Block = (bh, 64-query tile); wave w owns
// 16 q-rows. Q/K bf16 [bh][t][64]; VT bf16 [bh*64+d][VROW]. Max-free softmax
// (scores are small; clamp at 80 guards overflow). P via per-wave LDS patch.
// ---------------------------------------------------------------------------
__global__ __launch_bounds__(256)
void flash_mfma(const bf16* __restrict__ Qh, const bf16* __restrict__ Kh,
                const bf16* __restrict__ VT, bf16* __restrict__ O, int Ntok)
{
    __shared__ __align__(16) unsigned short Plds[4][16 * PSTR];
    int bh = blockIdx.x;
    int b = bh / HEADS, h = bh % HEADS;
    int t0 = blockIdx.y * 64;
    int tid = threadIdx.x;
    int lane = tid & 63, w = tid >> 6;
    int fr = lane & 15, fq = lane >> 4;

    const bf16* Qb = Qh + (size_t)bh * SEQMAX * HD;
    const bf16* Kb = Kh + (size_t)bh * SEQMAX * HD;
    const bf16* Vt = VT + (size_t)bh * HD * VROW;

    int tq = t0 + w * 16 + fr; if (tq >= Ntok) tq = Ntok - 1;
    short8 aq0 = *(const short8*)(Qb + (size_t)tq * HD + fq * 8);
    short8 aq1 = *(const short8*)(Qb + (size_t)tq * HD + fq * 8 + 32);

    float lpart[4] = {0.f, 0.f, 0.f, 0.f};
    f32x4 oacc[4];
    #pragma unroll
    for (int dg = 0; dg < 4; ++dg) oacc[dg] = (f32x4){0.f, 0.f, 0.f, 0.f};

    unsigned short* Pw = Plds[w];

    for (int k0 = 0; k0 < Ntok; k0 += 64) {
        // S = Q K^T
        float s[4][4];
        #pragma unroll
        for (int kg = 0; kg < 4; ++kg) {
            int key = k0 + kg * 16 + fr;
            int keyc = key < Ntok ? key : Ntok - 1;
            short8 bk0 = *(const short8*)(Kb + (size_t)keyc * HD + fq * 8);
            short8 bk1 = *(const short8*)(Kb + (size_t)keyc * HD + fq * 8 + 32);
            f32x4 sa = (f32x4){0.f, 0.f, 0.f, 0.f};
            sa = __builtin_amdgcn_mfma_f32_16x16x32_bf16(aq0, bk0, sa, 0, 0, 0);
            sa = __builtin_amdgcn_mfma_f32_16x16x32_bf16(aq1, bk1, sa, 0, 0, 0);
            #pragma unroll
            for (int r = 0; r < 4; ++r) s[kg][r] = sa[r];
        }

        // max-free softmax numerator; store P to per-wave LDS (C->A layout)
        #pragma unroll
        for (int kg = 0; kg < 4; ++kg) {
            bool ok = (k0 + kg * 16 + fr) < Ntok;
            #pragma unroll
            for (int r = 0; r < 4; ++r) {
                float p = ok ? __expf(fminf(s[kg][r] * 0.125f, 80.f)) : 0.f;
                lpart[r] += p;
                bf16 pb = __float2bfloat16(p);
                Pw[(fq * 4 + r) * PSTR + kg * 16 + fr] = *(unsigned short*)&pb;
            }
        }

        short8 ap0 = *(const short8*)(Pw + fr * PSTR + fq * 8);
        short8 ap1 = *(const short8*)(Pw + fr * PSTR + fq * 8 + 32);

        #pragma unroll
        for (int dg = 0; dg < 4; ++dg) {
            int d = dg * 16 + fr;
            short8 bv0 = *(const short8*)(Vt + (size_t)d * VROW + k0 + fq * 8);
            short8 bv1 = *(const short8*)(Vt + (size_t)d * VROW + k0 + fq * 8 + 32);
            oacc[dg] = __builtin_amdgcn_mfma_f32_16x16x32_bf16(ap0, bv0, oacc[dg], 0, 0, 0);
            oacc[dg] = __builtin_amdgcn_mfma_f32_16x16x32_bf16(ap1, bv1, oacc[dg], 0, 0, 0);
        }
    }

    #pragma unroll
    for (int r = 0; r < 4; ++r) {
        float l = lpart[r];
        l += __shfl_xor(l, 1); l += __shfl_xor(l, 2);
        l += __shfl_xor(l, 4); l += __shfl_xor(l, 8);
        int t = t0 + w * 16 + fq * 4 + r;
        if (t >= Ntok) continue;
        float inv = 1.0f / l;
        bf16* dst = O + ((size_t)b * SEQMAX + t) * EMBED + h * HD;
        #pragma unroll
        for (int dg = 0; dg < 4; ++dg)
            dst[dg * 16 + fr] = __float2bfloat16(oacc[dg][r] * inv);
    }
}

// ---------------------------------------------------------------------------
__global__ __launch_bounds__(256)
void patch_gather(const void* __restrict__ img, bf16* __restrict__ Ap,
                  const int* __restrict__ flag)
{
    int f = *flag;
    int idx = blockIdx.x * 256 + threadIdx.x;
    if (idx >= NB * NPATCH * EMBED) return;
    int col = idx % EMBED;
    int row = idx / EMBED;
    int t = row % NPATCH, b = row / NPATCH;
    int c = col >> 8;
    int pr = (col >> 4) & 15;
    int pc = col & 15;
    int gr = t / GRID, gc = t % GRID;
    size_t off = ((size_t)(b * 3 + c) * IMGSZ + gr * PATCH + pr) * IMGSZ + gc * PATCH + pc;
    float v = f ? ((const float*)img)[off] : b2f(((const bf16*)img)[off]);
    Ap[idx] = __float2bfloat16(v);
}

__global__ __launch_bounds__(256)
void posadd_kernel(const float* __restrict__ PEO, const float* __restrict__ sp,
                   const float* __restrict__ ip, float* __restrict__ X, int imgIdx)
{
    int idx = blockIdx.x * 256 + threadIdx.x;
    if (idx >= NB * NPATCH * EMBED) return;
    int e = idx % EMBED;
    int row = idx / EMBED;
    int t = row % NPATCH, b = row / NPATCH;
    float pos = (e < 384) ? sp[t * 384 + e] : ip[imgIdx * 384 + (e - 384)];
    X[((size_t)b * SEQMAX + imgIdx * NPATCH + t) * EMBED + e] = PEO[idx] + pos;
}

__global__ __launch_bounds__(768)
void mean_kernel(const float* __restrict__ H, float* __restrict__ Mn)
{
    int b = blockIdx.x;
    int e = threadIdx.x;
    float s = 0.f;
    for (int t = 0; t < SEQMAX; ++t) s += H[((size_t)b * SEQMAX + t) * EMBED + e];
    Mn[b * EMBED + e] = s * (1.0f / SEQMAX);
}

__global__ __launch_bounds__(256)
void bcast_kernel(const float* __restrict__ P, void* __restrict__ out,
                  const int* __restrict__ flag)
{
    int f = *flag;
    int idx = blockIdx.x * 256 + threadIdx.x;
    if (idx >= NB * IMGSZ * IMGSZ) return;
    int c = idx % IMGSZ;
    int r = (idx / IMGSZ) % IMGSZ;
    int b = idx / (IMGSZ * IMGSZ);
    float v = P[b * 256 + (r & 15) * 16 + (c & 15)];
    if (f) ((float*)out)[idx] = v;
    else   ((bf16*)out)[idx] = __float2bfloat16(v);
}

// ---------------------------------------------------------------------------
extern "C" void kernel_launch(void* const* d_in, const int* in_sizes, int n_in,
                              void* d_out, int out_size, void* d_ws, size_t ws_size,
                              hipStream_t stream)
{
    (void)n_in; (void)out_size; (void)ws_size;
    const void* img[4] = {d_in[0], d_in[1], d_in[2], d_in[3]};

    float* ws = (float*)d_ws;
    int* flag = (int*)ws;

    detect_kernel<<<1, 256, 0, stream>>>((const unsigned short*)d_in[0], flag);

    const bool isBig[28] = {0,0,0,0, 1,0,0,0, 0,0,1,0, 1,0,0,0, 1,0,1,0, 0,0,0,0, 0,0,0,0};
    float* fBase = ws + 16;
    float* fPtr[28] = {};
    CvtF32 cf;
    int fCnt = 0, fBlk = 0;
    cf.blkOff[0] = 0;
    {
        float* p = fBase;
        for (int i = 4; i < 28; ++i) {
            if (isBig[i]) continue;
            fPtr[i] = p;
            int n = in_sizes[i];
            cf.src[fCnt] = d_in[i];
            cf.n[fCnt] = n;
            cf.dstOff[fCnt] = (int)(p - fBase);
            fBlk += (n + 1023) / 1024;
            cf.blkOff[fCnt + 1] = fBlk;
            p += n;
            ++fCnt;
        }
        fBase = ws + 16;
        // end of fp32 arena:
        fPtr[0] = p;   // sentinel: arena end
    }
    convert_f32_all<<<fBlk, 256, 0, stream>>>(cf, fBase, flag);

    bf16* bPtr[28] = {};
    bf16* bBase = (bf16*)fPtr[0];
    CvtB16 cb;
    int bCnt = 0, bBlk = 0;
    cb.blkOff[0] = 0;
    float* arenaEnd;
    {
        bf16* p = bBase;
        for (int i = 4; i < 28; ++i) {
            if (!isBig[i]) continue;
            bPtr[i] = p;
            int n = in_sizes[i];
            cb.src[bCnt] = d_in[i];
            cb.n[bCnt] = n;
            cb.dstOff[bCnt] = (int)(p - bBase);
            bBlk += (n + 1023) / 1024;
            cb.blkOff[bCnt + 1] = bBlk;
            p += n;
            ++bCnt;
        }
        size_t off = p - (bf16*)ws;
        off = (off + 7) & ~(size_t)7;
        arenaEnd = (float*)((bf16*)ws + off);
    }
    convert_b16_all<<<bBlk, 256, 0, stream>>>(cb, bBase, flag);

    const bf16* pe_w   = bPtr[4];
    const bf16* qkv_w  = bPtr[10];
    const bf16* proj_w = bPtr[12];
    const bf16* fc1_w  = bPtr[16];
    const bf16* fc2_w  = bPtr[18];
    const float* pe_b      = fPtr[5];
    const float* sp        = fPtr[6];
    const float* ip        = fPtr[7];
    const float* ln_attn_g = fPtr[8];
    const float* ln_attn_b = fPtr[9];
    const float* qkv_b     = fPtr[11];
    const float* proj_b    = fPtr[13];
    const float* ln1_g     = fPtr[14];
    const float* ln1_b     = fPtr[15];
    const float* fc1_b     = fPtr[17];
    const float* fc2_b     = fPtr[19];
    const float* ln2_g     = fPtr[20];
    const float* ln2_b     = fPtr[21];
    const float* final_g   = fPtr[22];
    const float* final_b   = fPtr[23];
    const float* head_w1   = fPtr[24];
    const float* head_b1   = fPtr[25];
    const float* head_w2   = fPtr[26];
    const float* head_b2   = fPtr[27];

    const size_t SEQ = (size_t)NB * SEQMAX * EMBED;          // 4,816,896
    const size_t HID_ELEMS = (size_t)NB * SEQMAX * HIDDEN;   // 19,267,584
    const size_t EMB_ELEMS = (size_t)NB * NPATCH * EMBED;    // 1,204,224
    const size_t VT_ELEMS = (size_t)NB * HEADS * HD * VROW;  // 5,111,808
    float* X    = arenaEnd;
    float* H    = X + SEQ;
    float* O    = H + SEQ;
    float* PEO  = O + SEQ;
    float* MEAN = PEO + EMB_ELEMS;
    float* HH   = MEAN + NB * EMBED;
    float* PTCH = HH + NB * EMBED;
    bf16* Hb    = (bf16*)(PTCH + NB * 256 + 16);
    bf16* Ob    = Hb + SEQ;
    bf16* Gb    = Ob + SEQ;
    bf16* PEb   = Gb + HID_ELEMS;
    bf16* Qb    = PEb + EMB_ELEMS;
    bf16* Kb    = Qb + SEQ;
    bf16* Vb    = Kb + SEQ;
    bf16* VTb   = Vb + SEQ;      // VT_ELEMS + slack after

    const int nEmb = NB * NPATCH * EMBED;

    auto embed = [&](int i) {
        patch_gather<<<(nEmb + 255) / 256, 256, 0, stream>>>(img[i], PEb, flag);
        dim3 g(EMBED / 128, (NB * NPATCH + 127) / 128);
        mfma_gemm<<<g, 256, 0, stream>>>(PEb, pe_w + (size_t)i * EMBED * EMBED,
                                         pe_b + i * EMBED, nullptr, PEO, nullptr,
                                         nullptr, nullptr, nullptr,
                                         NB * NPATCH, EMBED, EMBED,
                                         NB * NPATCH, NB * NPATCH, 0);
        posadd_kernel<<<(nEmb + 255) / 256, 256, 0, stream>>>(PEO, sp, ip, X, i);
    };

    auto block = [&](int i, int Ntok) {
        int M = NB * Ntok;
        int gy = (M + 127) / 128;
        int nkt = (Ntok + 63) / 64;
        ln_bf16_kernel<<<M, 256, 0, stream>>>(X, Hb, ln_attn_g + i * EMBED, ln_attn_b + i * EMBED, Ntok);
        mfma_gemm<<<dim3(QKVD / 128, gy), 256, 0, stream>>>(
            Hb, qkv_w + (size_t)i * QKVD * EMBED, qkv_b + i * QKVD, nullptr,
            nullptr, nullptr, Qb, Kb, Vb, M, QKVD, EMBED, Ntok, SEQMAX, 3);
        vtrans_kernel<<<dim3(NB * HEADS, nkt), 256, 0, stream>>>(Vb, VTb, Ntok);
        flash_mfma<<<dim3(NB * HEADS, nkt), 256, 0, stream>>>(Qb, Kb, VTb, Ob, Ntok);
        mfma_gemm<<<dim3(EMBED / 128, gy), 256, 0, stream>>>(
            Ob, proj_w + (size_t)i * EMBED * EMBED, proj_b + i * EMBED, X,
            X, nullptr, nullptr, nullptr, nullptr, M, EMBED, EMBED, Ntok, SEQMAX, 1);
        ln_bf16_kernel<<<M, 256, 0, stream>>>(X, Hb, ln1_g + i * EMBED, ln1_b + i * EMBED, Ntok);
        mfma_gemm<<<dim3(HIDDEN / 128, gy), 256, 0, stream>>>(
            Hb, fc1_w + (size_t)i * HIDDEN * EMBED, fc1_b + i * HIDDEN, nullptr,
            nullptr, Gb, nullptr, nullptr, nullptr, M, HIDDEN, EMBED, Ntok, SEQMAX, 2);
        mfma_gemm<<<dim3(EMBED / 128, gy), 256, 0, stream>>>(
            Gb, fc2_w + (size_t)i * EMBED * HIDDEN, fc2_b + i * EMBED, X,
            O, nullptr, nullptr, nullptr, nullptr, M, EMBED, HIDDEN, Ntok, SEQMAX, 1);
        ln_kernel<<<M, 256, 0, stream>>>(O, X, ln2_g + i * EMBED, ln2_b + i * EMBED, Ntok);
    };

    embed(0);
    embed(1);
    block(0, 392);
    embed(2);
    block(1, 588);
    embed(3);
    block(2, 784);

    ln_kernel<<<NB * SEQMAX, 256, 0, stream>>>(X, H, final_g, final_b, SEQMAX);
    mean_kernel<<<NB, 768, 0, stream>>>(H, MEAN);
    gemm_kernel<<<dim3(EMBED / 64, 1), 256, 0, stream>>>(
        MEAN, head_w1, head_b1, nullptr, HH, NB, EMBED, EMBED, NB, NB, 1);
    gemm_kernel<<<dim3(256 / 64, 1), 256, 0, stream>>>(
        HH, head_w2, head_b2, nullptr, PTCH, NB, 256, EMBED, NB, NB, 0);
    bcast_kernel<<<(NB * IMGSZ * IMGSZ + 255) / 256, 256, 0, stream>>>(PTCH, d_out, flag);
}

// Round 9
// 1588.106 us; speedup vs baseline: 6.3538x; 1.0618x over previous
//
#include <hip/hip_runtime.h>
#include <hip/hip_bf16.h>
#include <math.h>

#define EMBED 768
#define QKVD 2304
#define HEADS 12
#define HD 64
#define HIDDEN 3072
#define NPATCH 196
#define SEQMAX 784
#define NB 8
#define IMGSZ 224
#define GRID 14
#define PATCH 16
#define PSTR 72
#define VROW 832

typedef __hip_bfloat16 bf16;
typedef __attribute__((ext_vector_type(8))) short short8;
typedef __attribute__((ext_vector_type(4))) float f32x4;

__device__ __forceinline__ float b2f(bf16 v) { return __bfloat162float(v); }
__device__ __forceinline__ float geluf(float x) {
    return 0.5f * x * (1.0f + erff(x * 0.70710678118654752f));
}

// async global->LDS, 16B per lane. LDS dest is wave-uniform base + lane*16.
__device__ __forceinline__ void async16(const bf16* g, bf16* l) {
    __builtin_amdgcn_global_load_lds(
        (const __attribute__((address_space(1))) unsigned int*)g,
        (__attribute__((address_space(3))) unsigned int*)l,
        16, 0, 0);
}

#define WAIT_VM0   0x0F70   // vmcnt(0)
#define WAIT_VM4   0x0F74   // vmcnt(4)
#define WAIT_LGKM0 0xC07F   // lgkmcnt(0)

// ---------------------------------------------------------------------------
// Dtype detection (bf16 vs fp32 inputs).
// ---------------------------------------------------------------------------
__global__ __launch_bounds__(256)
void detect_kernel(const unsigned short* __restrict__ raw, int* __restrict__ flag)
{
    __shared__ int bad;
    if (threadIdx.x == 0) bad = 0;
    __syncthreads();
    for (int i = threadIdx.x; i < 8192; i += 256) {
        unsigned int u = (unsigned int)raw[i] << 16;
        float v = __uint_as_float(u);
        if (!(fabsf(v) <= 1e4f)) bad = 1;
    }
    __syncthreads();
    if (threadIdx.x == 0) *flag = bad;
}

// ---------------------------------------------------------------------------
// Fused converters.
// ---------------------------------------------------------------------------
struct CvtF32 {
    const void* src[19];
    int n[19];
    int dstOff[19];
    int blkOff[20];
};
__global__ __launch_bounds__(256)
void convert_f32_all(CvtF32 c, float* __restrict__ base, const int* __restrict__ flag)
{
    int f = *flag;
    int b = blockIdx.x;
    int i = 0;
    #pragma unroll
    for (int j = 0; j < 19; ++j) if (b >= c.blkOff[j + 1]) i = j + 1;
    int e = ((b - c.blkOff[i]) * 256 + threadIdx.x) * 4;
    if (e >= c.n[i]) return;
    float* dst = base + c.dstOff[i] + e;
    if (f) {
        *(float4*)dst = *(const float4*)((const float*)c.src[i] + e);
    } else {
        const bf16* s = (const bf16*)c.src[i] + e;
        dst[0] = b2f(s[0]); dst[1] = b2f(s[1]); dst[2] = b2f(s[2]); dst[3] = b2f(s[3]);
    }
}

struct CvtB16 {
    const void* src[5];
    int n[5];
    int dstOff[5];
    int blkOff[6];
};
__global__ __launch_bounds__(256)
void convert_b16_all(CvtB16 c, bf16* __restrict__ base, const int* __restrict__ flag)
{
    int f = *flag;
    int b = blockIdx.x;
    int i = 0;
    #pragma unroll
    for (int j = 0; j < 5; ++j) if (b >= c.blkOff[j + 1]) i = j + 1;
    int e = ((b - c.blkOff[i]) * 256 + threadIdx.x) * 4;
    if (e >= c.n[i]) return;
    bf16* dst = base + (size_t)c.dstOff[i] + e;
    if (f) {
        float4 v = *(const float4*)((const float*)c.src[i] + e);
        dst[0] = __float2bfloat16(v.x); dst[1] = __float2bfloat16(v.y);
        dst[2] = __float2bfloat16(v.z); dst[3] = __float2bfloat16(v.w);
    } else {
        *(uint2*)dst = *(const uint2*)((const bf16*)c.src[i] + e);
    }
}

// ---------------------------------------------------------------------------
// MFMA bf16 GEMM: 128x128 tile, BK=32, double-buffered LDS with raw barriers.
// mode: 0 = fp32 out; 1 = fp32 out + residual; 2 = bf16 out + gelu;
//       3 = qkv head-split -> bf16 Q/K/V all [bh][t][64].
// ---------------------------------------------------------------------------
__global__ __launch_bounds__(256)
void mfma_gemm(const bf16* __restrict__ A, const bf16* __restrict__ W,
               const float* __restrict__ bias, const float* __restrict__ add,
               float* __restrict__ outF, bf16* __restrict__ outB,
               bf16* __restrict__ Qb, bf16* __restrict__ Kb, bf16* __restrict__ Vb,
               int M, int N, int K, int Ntok, int rowStride, int mode)
{
    __shared__ __align__(16) bf16 As[2][128 * 32];
    __shared__ __align__(16) bf16 Bs[2][128 * 32];
    int tid = threadIdx.x;
    int lane = tid & 63;
    int wave = tid >> 6;
    int wm = wave & 1, wn = wave >> 1;
    int m0 = blockIdx.y * 128, n0 = blockIdx.x * 128;

    int lr = lane >> 2;
    int lc = lane & 3;
    int ar0 = 32 * wave + lr;
    int ar1 = ar0 + 16;
    int ma0 = m0 + ar0; if (ma0 >= M) ma0 = M - 1;
    int ma1 = m0 + ar1; if (ma1 >= M) ma1 = M - 1;
    const bf16* aSrc0 = A + (size_t)((ma0 / Ntok) * rowStride + ma0 % Ntok) * K + lc * 8;
    const bf16* aSrc1 = A + (size_t)((ma1 / Ntok) * rowStride + ma1 % Ntok) * K + lc * 8;
    const bf16* bSrc0 = W + (size_t)(n0 + ar0) * K + lc * 8;
    const bf16* bSrc1 = W + (size_t)(n0 + ar1) * K + lc * 8;

    int fr = lane & 15;
    int fq = lane >> 4;
    int aOff = (wm * 64 + fr) * 32 + fq * 8;
    int bOff = (wn * 64 + fr) * 32 + fq * 8;

    f32x4 acc[4][4] = {};

    auto stage = [&](int buf) {
        async16(aSrc0, As[buf] + (32 * wave) * 32);
        async16(aSrc1, As[buf] + (32 * wave + 16) * 32);
        async16(bSrc0, Bs[buf] + (32 * wave) * 32);
        async16(bSrc1, Bs[buf] + (32 * wave + 16) * 32);
        aSrc0 += 32; aSrc1 += 32; bSrc0 += 32; bSrc1 += 32;
    };

    int nIter = K >> 5;
    stage(0);

    for (int it = 0; it < nIter; ++it) {
        int cur = it & 1;
        __builtin_amdgcn_sched_barrier(0);
        __builtin_amdgcn_s_waitcnt(WAIT_LGKM0);
        __builtin_amdgcn_s_barrier();
        bool pre = (it + 1 < nIter);
        if (pre) {
            stage(cur ^ 1);
            __builtin_amdgcn_s_waitcnt(WAIT_VM4);
        } else {
            __builtin_amdgcn_s_waitcnt(WAIT_VM0);
        }
        __builtin_amdgcn_s_barrier();
        __builtin_amdgcn_sched_barrier(0);

        const bf16* aR = As[cur] + aOff;
        const bf16* bR = Bs[cur] + bOff;
        short8 af[4], bfr[4];
        #pragma unroll
        for (int mi = 0; mi < 4; ++mi) af[mi] = *(const short8*)(aR + mi * 16 * 32);
        #pragma unroll
        for (int ni = 0; ni < 4; ++ni) bfr[ni] = *(const short8*)(bR + ni * 16 * 32);
        #pragma unroll
        for (int mi = 0; mi < 4; ++mi)
            #pragma unroll
            for (int ni = 0; ni < 4; ++ni)
                acc[mi][ni] = __builtin_amdgcn_mfma_f32_16x16x32_bf16(
                    af[mi], bfr[ni], acc[mi][ni], 0, 0, 0);
    }

    #pragma unroll
    for (int mi = 0; mi < 4; ++mi) {
        #pragma unroll
        for (int ni = 0; ni < 4; ++ni) {
            int n = n0 + wn * 64 + ni * 16 + fr;
            float bs = bias[n];
            #pragma unroll
            for (int r = 0; r < 4; ++r) {
                int m = m0 + wm * 64 + mi * 16 + fq * 4 + r;
                if (m >= M) continue;
                int bidx = m / Ntok, t = m - bidx * Ntok;
                size_t pr = (size_t)bidx * rowStride + t;
                float v = acc[mi][ni][r] + bs;
                if (mode == 0) {
                    outF[pr * N + n] = v;
                } else if (mode == 1) {
                    outF[pr * N + n] = v + add[pr * N + n];
                } else if (mode == 2) {
                    outB[pr * N + n] = __float2bfloat16(geluf(v));
                } else {
                    int which = n >= 1536 ? 2 : (n >= 768 ? 1 : 0);
                    int nn = n - which * 768;
                    int hh = nn >> 6, d = nn & 63;
                    bf16 bv = __float2bfloat16(v);
                    bf16* dst = which == 0 ? Qb : which == 1 ? Kb : Vb;
                    dst[((size_t)(bidx * HEADS + hh) * SEQMAX + t) * HD + d] = bv;
                }
            }
        }
    }
}

// ---------------------------------------------------------------------------
// Legacy fp32 GEMM (tiny head matmuls only).
// ---------------------------------------------------------------------------
__global__ __launch_bounds__(256)
void gemm_kernel(const float* __restrict__ A, const float* __restrict__ W,
                 const float* __restrict__ bias, const float* __restrict__ add,
                 float* __restrict__ C, int M, int N, int K,
                 int Ntok, int rowStride, int dogelu)
{
    __shared__ __align__(16) float As[16][68];
    __shared__ __align__(16) float Ws[16][68];
    int tid = threadIdx.x;
    int tx = tid & 15, ty = tid >> 4;
    int n0 = blockIdx.x * 64, m0 = blockIdx.y * 64;
    int lrow = tid >> 2;
    int lk   = (tid & 3) << 2;
    int am = m0 + lrow;
    bool aok = (am < M);
    const float* Arow = A;
    if (aok) {
        int pr = (am / Ntok) * rowStride + (am % Ntok);
        Arow = A + (size_t)pr * K;
    }
    int wn = n0 + lrow;
    const float* Wrow = (wn < N) ? (W + (size_t)wn * K) : nullptr;
    float acc[4][4] = {};
    for (int kk = 0; kk < K; kk += 16) {
        float4 av = make_float4(0.f, 0.f, 0.f, 0.f);
        if (aok) av = *(const float4*)(Arow + kk + lk);
        float4 wv = make_float4(0.f, 0.f, 0.f, 0.f);
        if (Wrow) wv = *(const float4*)(Wrow + kk + lk);
        __syncthreads();
        As[lk+0][lrow] = av.x; As[lk+1][lrow] = av.y;
        As[lk+2][lrow] = av.z; As[lk+3][lrow] = av.w;
        Ws[lk+0][lrow] = wv.x; Ws[lk+1][lrow] = wv.y;
        Ws[lk+2][lrow] = wv.z; Ws[lk+3][lrow] = wv.w;
        __syncthreads();
        #pragma unroll
        for (int k = 0; k < 16; ++k) {
            float4 a = *(const float4*)&As[k][ty << 2];
            float4 w = *(const float4*)&Ws[k][tx << 2];
            acc[0][0] += a.x*w.x; acc[0][1] += a.x*w.y; acc[0][2] += a.x*w.z; acc[0][3] += a.x*w.w;
            acc[1][0] += a.y*w.x; acc[1][1] += a.y*w.y; acc[1][2] += a.y*w.z; acc[1][3] += a.y*w.w;
            acc[2][0] += a.z*w.x; acc[2][1] += a.z*w.y; acc[2][2] += a.z*w.z; acc[2][3] += a.z*w.w;
            acc[3][0] += a.w*w.x; acc[3][1] += a.w*w.y; acc[3][2] += a.w*w.z; acc[3][3] += a.w*w.w;
        }
    }
    #pragma unroll
    for (int i = 0; i < 4; ++i) {
        int m = m0 + (ty << 2) + i;
        if (m >= M) continue;
        int pr = (m / Ntok) * rowStride + (m % Ntok);
        float* crow = C + (size_t)pr * N;
        const float* addrow = add ? (add + (size_t)pr * N) : nullptr;
        #pragma unroll
        for (int j = 0; j < 4; ++j) {
            int n = n0 + (tx << 2) + j;
            float v = acc[i][j] + bias[n];
            if (addrow) v += addrow[n];
            if (dogelu) v = geluf(v);
            crow[n] = v;
        }
    }
}

// ---------------------------------------------------------------------------
// LayerNorms.
// ---------------------------------------------------------------------------
__global__ __launch_bounds__(256)
void ln_bf16_kernel(const float* __restrict__ src, bf16* __restrict__ dst,
                    const float* __restrict__ g, const float* __restrict__ bta, int Ntok)
{
    __shared__ float red[256];
    int blk = blockIdx.x;
    int t = blk % Ntok, b = blk / Ntok;
    size_t row = ((size_t)b * SEQMAX + t) * EMBED;
    int tid = threadIdx.x;
    float v0 = src[row + tid], v1 = src[row + tid + 256], v2 = src[row + tid + 512];
    red[tid] = v0 + v1 + v2;
    __syncthreads();
    for (int off = 128; off; off >>= 1) { if (tid < off) red[tid] += red[tid + off]; __syncthreads(); }
    float mu = red[0] * (1.0f / EMBED);
    __syncthreads();
    float d0 = v0 - mu, d1 = v1 - mu, d2 = v2 - mu;
    red[tid] = d0*d0 + d1*d1 + d2*d2;
    __syncthreads();
    for (int off = 128; off; off >>= 1) { if (tid < off) red[tid] += red[tid + off]; __syncthreads(); }
    float rs = rsqrtf(red[0] * (1.0f / EMBED) + 1e-5f);
    dst[row + tid]       = __float2bfloat16(d0 * rs * g[tid]       + bta[tid]);
    dst[row + tid + 256] = __float2bfloat16(d1 * rs * g[tid + 256] + bta[tid + 256]);
    dst[row + tid + 512] = __float2bfloat16(d2 * rs * g[tid + 512] + bta[tid + 512]);
}

__global__ __launch_bounds__(256)
void ln_kernel(const float* __restrict__ src, float* __restrict__ dst,
               const float* __restrict__ g, const float* __restrict__ bta, int Ntok)
{
    __shared__ float red[256];
    int blk = blockIdx.x;
    int t = blk % Ntok, b = blk / Ntok;
    size_t row = ((size_t)b * SEQMAX + t) * EMBED;
    int tid = threadIdx.x;
    float v0 = src[row + tid], v1 = src[row + tid + 256], v2 = src[row + tid + 512];
    red[tid] = v0 + v1 + v2;
    __syncthreads();
    for (int off = 128; off; off >>= 1) { if (tid < off) red[tid] += red[tid + off]; __syncthreads(); }
    float mu = red[0] * (1.0f / EMBED);
    __syncthreads();
    float d0 = v0 - mu, d1 = v1 - mu, d2 = v2 - mu;
    red[tid] = d0*d0 + d1*d1 + d2*d2;
    __syncthreads();
    for (int off = 128; off; off >>= 1) { if (tid < off) red[tid] += red[tid + off]; __syncthreads(); }
    float rs = rsqrtf(red[0] * (1.0f / EMBED) + 1e-5f);
    dst[row + tid]       = d0 * rs * g[tid]       + bta[tid];
    dst[row + tid + 256] = d1 * rs * g[tid + 256] + bta[tid + 256];
    dst[row + tid + 512] = d2 * rs * g[tid + 512] + bta[tid + 512];
}

// ---------------------------------------------------------------------------
// V transpose: V [bh][t][64] -> VT [bh*64+d][VROW], zero-padded keys>=Ntok.
// ---------------------------------------------------------------------------
__global__ __launch_bounds__(256)
void vtrans_kernel(const bf16* __restrict__ Vh, bf16* __restrict__ VT, int Ntok)
{
    __shared__ unsigned short Lt[64 * 66];
    int bh = blockIdx.x;
    int k0 = blockIdx.y * 64;
    const bf16* Vb = Vh + (size_t)bh * SEQMAX * HD;
    int tid = threadIdx.x;
    #pragma unroll
    for (int pass = 0; pass < 8; ++pass) {
        int key_l = (tid >> 5) + pass * 8;
        int d2 = tid & 31;
        unsigned v = 0;
        if (k0 + key_l < Ntok)
            v = *(const unsigned*)(Vb + (size_t)(k0 + key_l) * HD + d2 * 2);
        *(unsigned*)&Lt[key_l * 66 + 2 * d2] = v;
    }
    __syncthreads();
    #pragma unroll
    for (int pass = 0; pass < 8; ++pass) {
        int d = (tid >> 5) + pass * 8;
        int kp = tid & 31;
        unsigned lo = Lt[(2 * kp) * 66 + d];
        unsigned hi = Lt[(2 * kp + 1) * 66 + d];
        *(unsigned*)(VT + ((size_t)bh * HD + d) * VROW + k0 + 2 * kp) = lo | (hi << 16);
    }
}

// ---------------------------------------------------------------------------
// MFMA flash attention v3. Block = (bh, 128-query tile); wave w owns 32 q-rows
// (two 16-row A-fragments). K loads then VT loads issued at top of each
// k-iteration so VT latency is hidden behind S + softmax + P roundtrip.
// Max-free softmax (small scores; clamp 80). P via per-wave LDS patch.
// ---------------------------------------------------------------------------
__global__ __launch_bounds__(256)
void flash_mfma(const bf16* __restrict__ Qh, const bf16* __restrict__ Kh,
                const bf16* __restrict__ VT, bf16* __restrict__ O, int Ntok)
{
    __shared__ __align__(16) unsigned short Plds[4][32 * PSTR];
    int bh = blockIdx.x;
    int b = bh / HEADS, h = bh % HEADS;
    int t0 = blockIdx.y * 128;
    int tid = threadIdx.x;
    int lane = tid & 63, w = tid >> 6;
    int fr = lane & 15, fq = lane >> 4;

    const bf16* Qb = Qh + (size_t)bh * SEQMAX * HD;
    const bf16* Kb = Kh + (size_t)bh * SEQMAX * HD;
    const bf16* Vt = VT + (size_t)bh * HD * VROW;

    short8 aq[2][2];
    #pragma unroll
    for (int qi = 0; qi < 2; ++qi) {
        int tq = t0 + w * 32 + qi * 16 + fr; if (tq >= Ntok) tq = Ntok - 1;
        aq[qi][0] = *(const short8*)(Qb + (size_t)tq * HD + fq * 8);
        aq[qi][1] = *(const short8*)(Qb + (size_t)tq * HD + fq * 8 + 32);
    }

    float lpart[2][4] = {};
    f32x4 oacc[2][4];
    #pragma unroll
    for (int qi = 0; qi < 2; ++qi)
        #pragma unroll
        for (int dg = 0; dg < 4; ++dg) oacc[qi][dg] = (f32x4){0.f, 0.f, 0.f, 0.f};

    unsigned short* Pw = Plds[w];

    for (int k0 = 0; k0 < Ntok; k0 += 64) {
        // K fragment loads first...
        short8 bk[4][2];
        #pragma unroll
        for (int kg = 0; kg < 4; ++kg) {
            int key = k0 + kg * 16 + fr;
            int keyc = key < Ntok ? key : Ntok - 1;
            bk[kg][0] = *(const short8*)(Kb + (size_t)keyc * HD + fq * 8);
            bk[kg][1] = *(const short8*)(Kb + (size_t)keyc * HD + fq * 8 + 32);
        }
        // ...then VT loads: stay in flight through S + softmax (vmcnt(8) for S)
        short8 bv[4][2];
        #pragma unroll
        for (int dg = 0; dg < 4; ++dg) {
            int d = dg * 16 + fr;
            bv[dg][0] = *(const short8*)(Vt + (size_t)d * VROW + k0 + fq * 8);
            bv[dg][1] = *(const short8*)(Vt + (size_t)d * VROW + k0 + fq * 8 + 32);
        }

        // S = Q K^T (2 q-frags x 4 k-frags)
        float s[2][4][4];
        #pragma unroll
        for (int qi = 0; qi < 2; ++qi)
            #pragma unroll
            for (int kg = 0; kg < 4; ++kg) {
                f32x4 sa = (f32x4){0.f, 0.f, 0.f, 0.f};
                sa = __builtin_amdgcn_mfma_f32_16x16x32_bf16(aq[qi][0], bk[kg][0], sa, 0, 0, 0);
                sa = __builtin_amdgcn_mfma_f32_16x16x32_bf16(aq[qi][1], bk[kg][1], sa, 0, 0, 0);
                #pragma unroll
                for (int r = 0; r < 4; ++r) s[qi][kg][r] = sa[r];
            }

        // max-free softmax numerators; store P to per-wave LDS (C->A layout)
        #pragma unroll
        for (int qi = 0; qi < 2; ++qi)
            #pragma unroll
            for (int kg = 0; kg < 4; ++kg) {
                bool ok = (k0 + kg * 16 + fr) < Ntok;
                #pragma unroll
                for (int r = 0; r < 4; ++r) {
                    float p = ok ? __expf(fminf(s[qi][kg][r] * 0.125f, 80.f)) : 0.f;
                    lpart[qi][r] += p;
                    bf16 pb = __float2bfloat16(p);
                    Pw[(qi * 16 + fq * 4 + r) * PSTR + kg * 16 + fr] = *(unsigned short*)&pb;
                }
            }

        short8 ap[2][2];
        #pragma unroll
        for (int qi = 0; qi < 2; ++qi) {
            ap[qi][0] = *(const short8*)(Pw + (qi * 16 + fr) * PSTR + fq * 8);
            ap[qi][1] = *(const short8*)(Pw + (qi * 16 + fr) * PSTR + fq * 8 + 32);
        }

        #pragma unroll
        for (int qi = 0; qi < 2; ++qi)
            #pragma unroll
            for (int dg = 0; dg < 4; ++dg) {
                oacc[qi][dg] = __builtin_amdgcn_mfma_f32_16x16x32_bf16(
                    ap[qi][0], bv[dg][0], oacc[qi][dg], 0, 0, 0);
                oacc[qi][dg] = __builtin_amdgcn_mfma_f32_16x16x32_bf16(
                    ap[qi][1], bv[dg][1], oacc[qi][dg], 0, 0, 0);
            }
    }

    #pragma unroll
    for (int qi = 0; qi < 2; ++qi)
        #pragma unroll
        for (int r = 0; r < 4; ++r) {
            float l = lpart[qi][r];
            l += __shfl_xor(l, 1); l += __shfl_xor(l, 2);
            l += __shfl_xor(l, 4); l += __shfl_xor(l, 8);
            int t = t0 + w * 32 + qi * 16 + fq * 4 + r;
            if (t >= Ntok) continue;
            float inv = 1.0f / l;
            bf16* dst = O + ((size_t)b * SEQMAX + t) * EMBED + h * HD;
            #pragma unroll
            for (int dg = 0; dg < 4; ++dg)
                dst[dg * 16 + fr] = __float2bfloat16(oacc[qi][dg][r] * inv);
        }
}

// ---------------------------------------------------------------------------
__global__ __launch_bounds__(256)
void patch_gather(const void* __restrict__ img, bf16* __restrict__ Ap,
                  const int* __restrict__ flag)
{
    int f = *flag;
    int idx = blockIdx.x * 256 + threadIdx.x;
    if (idx >= NB * NPATCH * EMBED) return;
    int col = idx % EMBED;
    int row = idx / EMBED;
    int t = row % NPATCH, b = row / NPATCH;
    int c = col >> 8;
    int pr = (col >> 4) & 15;
    int pc = col & 15;
    int gr = t / GRID, gc = t % GRID;
    size_t off = ((size_t)(b * 3 + c) * IMGSZ + gr * PATCH + pr) * IMGSZ + gc * PATCH + pc;
    float v = f ? ((const float*)img)[off] : b2f(((const bf16*)img)[off]);
    Ap[idx] = __float2bfloat16(v);
}

__global__ __launch_bounds__(256)
void posadd_kernel(const float* __restrict__ PEO, const float* __restrict__ sp,
                   const float* __restrict__ ip, float* __restrict__ X, int imgIdx)
{
    int idx = blockIdx.x * 256 + threadIdx.x;
    if (idx >= NB * NPATCH * EMBED) return;
    int e = idx % EMBED;
    int row = idx / EMBED;
    int t = row % NPATCH, b = row / NPATCH;
    float pos = (e < 384) ? sp[t * 384 + e] : ip[imgIdx * 384 + (e - 384)];
    X[((size_t)b * SEQMAX + imgIdx * NPATCH + t) * EMBED + e] = PEO[idx] + pos;
}

__global__ __launch_bounds__(768)
void mean_kernel(const float* __restrict__ H, float* __restrict__ Mn)
{
    int b = blockIdx.x;
    int e = threadIdx.x;
    float s = 0.f;
    for (int t = 0; t < SEQMAX; ++t) s += H[((size_t)b * SEQMAX + t) * EMBED + e];
    Mn[b * EMBED + e] = s * (1.0f / SEQMAX);
}

__global__ __launch_bounds__(256)
void bcast_kernel(const float* __restrict__ P, void* __restrict__ out,
                  const int* __restrict__ flag)
{
    int f = *flag;
    int idx = blockIdx.x * 256 + threadIdx.x;
    if (idx >= NB * IMGSZ * IMGSZ) return;
    int c = idx % IMGSZ;
    int r = (idx / IMGSZ) % IMGSZ;
    int b = idx / (IMGSZ * IMGSZ);
    float v = P[b * 256 + (r & 15) * 16 + (c & 15)];
    if (f) ((float*)out)[idx] = v;
    else   ((bf16*)out)[idx] = __float2bfloat16(v);
}

// ---------------------------------------------------------------------------
extern "C" void kernel_launch(void* const* d_in, const int* in_sizes, int n_in,
                              void* d_out, int out_size, void* d_ws, size_t ws_size,
                              hipStream_t stream)
{
    (void)n_in; (void)out_size; (void)ws_size;
    const void* img[4] = {d_in[0], d_in[1], d_in[2], d_in[3]};

    float* ws = (float*)d_ws;
    int* flag = (int*)ws;

    detect_kernel<<<1, 256, 0, stream>>>((const unsigned short*)d_in[0], flag);

    const bool isBig[28] = {0,0,0,0, 1,0,0,0, 0,0,1,0, 1,0,0,0, 1,0,1,0, 0,0,0,0, 0,0,0,0};
    float* fBase = ws + 16;
    float* fPtr[28] = {};
    CvtF32 cf;
    int fCnt = 0, fBlk = 0;
    cf.blkOff[0] = 0;
    {
        float* p = fBase;
        for (int i = 4; i < 28; ++i) {
            if (isBig[i]) continue;
            fPtr[i] = p;
            int n = in_sizes[i];
            cf.src[fCnt] = d_in[i];
            cf.n[fCnt] = n;
            cf.dstOff[fCnt] = (int)(p - fBase);
            fBlk += (n + 1023) / 1024;
            cf.blkOff[fCnt + 1] = fBlk;
            p += n;
            ++fCnt;
        }
        fBase = ws + 16;
        fPtr[0] = p;   // sentinel: arena end
    }
    convert_f32_all<<<fBlk, 256, 0, stream>>>(cf, fBase, flag);

    bf16* bPtr[28] = {};
    bf16* bBase = (bf16*)fPtr[0];
    CvtB16 cb;
    int bCnt = 0, bBlk = 0;
    cb.blkOff[0] = 0;
    float* arenaEnd;
    {
        bf16* p = bBase;
        for (int i = 4; i < 28; ++i) {
            if (!isBig[i]) continue;
            bPtr[i] = p;
            int n = in_sizes[i];
            cb.src[bCnt] = d_in[i];
            cb.n[bCnt] = n;
            cb.dstOff[bCnt] = (int)(p - bBase);
            bBlk += (n + 1023) / 1024;
            cb.blkOff[bCnt + 1] = bBlk;
            p += n;
            ++bCnt;
        }
        size_t off = p - (bf16*)ws;
        off = (off + 7) & ~(size_t)7;
        arenaEnd = (float*)((bf16*)ws + off);
    }
    convert_b16_all<<<bBlk, 256, 0, stream>>>(cb, bBase, flag);

    const bf16* pe_w   = bPtr[4];
    const bf16* qkv_w  = bPtr[10];
    const bf16* proj_w = bPtr[12];
    const bf16* fc1_w  = bPtr[16];
    const bf16* fc2_w  = bPtr[18];
    const float* pe_b      = fPtr[5];
    const float* sp        = fPtr[6];
    const float* ip        = fPtr[7];
    const float* ln_attn_g = fPtr[8];
    const float* ln_attn_b = fPtr[9];
    const float* qkv_b     = fPtr[11];
    const float* proj_b    = fPtr[13];
    const float* ln1_g     = fPtr[14];
    const float* ln1_b     = fPtr[15];
    const float* fc1_b     = fPtr[17];
    const float* fc2_b     = fPtr[19];
    const float* ln2_g     = fPtr[20];
    const float* ln2_b     = fPtr[21];
    const float* final_g   = fPtr[22];
    const float* final_b   = fPtr[23];
    const float* head_w1   = fPtr[24];
    const float* head_b1   = fPtr[25];
    const float* head_w2   = fPtr[26];
    const float* head_b2   = fPtr[27];

    const size_t SEQ = (size_t)NB * SEQMAX * EMBED;          // 4,816,896
    const size_t HID_ELEMS = (size_t)NB * SEQMAX * HIDDEN;   // 19,267,584
    const size_t EMB_ELEMS = (size_t)NB * NPATCH * EMBED;    // 1,204,224
    float* X    = arenaEnd;
    float* H    = X + SEQ;
    float* O    = H + SEQ;
    float* PEO  = O + SEQ;
    float* MEAN = PEO + EMB_ELEMS;
    float* HH   = MEAN + NB * EMBED;
    float* PTCH = HH + NB * EMBED;
    bf16* Hb    = (bf16*)(PTCH + NB * 256 + 16);
    bf16* Ob    = Hb + SEQ;
    bf16* Gb    = Ob + SEQ;
    bf16* PEb   = Gb + HID_ELEMS;
    bf16* Qb    = PEb + EMB_ELEMS;
    bf16* Kb    = Qb + SEQ;
    bf16* Vb    = Kb + SEQ;
    bf16* VTb   = Vb + SEQ;

    const int nEmb = NB * NPATCH * EMBED;

    auto embed = [&](int i) {
        patch_gather<<<(nEmb + 255) / 256, 256, 0, stream>>>(img[i], PEb, flag);
        dim3 g(EMBED / 128, (NB * NPATCH + 127) / 128);
        mfma_gemm<<<g, 256, 0, stream>>>(PEb, pe_w + (size_t)i * EMBED * EMBED,
                                         pe_b + i * EMBED, nullptr, PEO, nullptr,
                                         nullptr, nullptr, nullptr,
                                         NB * NPATCH, EMBED, EMBED,
                                         NB * NPATCH, NB * NPATCH, 0);
        posadd_kernel<<<(nEmb + 255) / 256, 256, 0, stream>>>(PEO, sp, ip, X, i);
    };

    auto block = [&](int i, int Ntok) {
        int M = NB * Ntok;
        int gy = (M + 127) / 128;
        int nkt = (Ntok + 63) / 64;
        int nqt = (Ntok + 127) / 128;
        ln_bf16_kernel<<<M, 256, 0, stream>>>(X, Hb, ln_attn_g + i * EMBED, ln_attn_b + i * EMBED, Ntok);
        mfma_gemm<<<dim3(QKVD / 128, gy), 256, 0, stream>>>(
            Hb, qkv_w + (size_t)i * QKVD * EMBED, qkv_b + i * QKVD, nullptr,
            nullptr, nullptr, Qb, Kb, Vb, M, QKVD, EMBED, Ntok, SEQMAX, 3);
        vtrans_kernel<<<dim3(NB * HEADS, nkt), 256, 0, stream>>>(Vb, VTb, Ntok);
        flash_mfma<<<dim3(NB * HEADS, nqt), 256, 0, stream>>>(Qb, Kb, VTb, Ob, Ntok);
        mfma_gemm<<<dim3(EMBED / 128, gy), 256, 0, stream>>>(
            Ob, proj_w + (size_t)i * EMBED * EMBED, proj_b + i * EMBED, X,
            X, nullptr, nullptr, nullptr, nullptr, M, EMBED, EMBED, Ntok, SEQMAX, 1);
        ln_bf16_kernel<<<M, 256, 0, stream>>>(X, Hb, ln1_g + i * EMBED, ln1_b + i * EMBED, Ntok);
        mfma_gemm<<<dim3(HIDDEN / 128, gy), 256, 0, stream>>>(
            Hb, fc1_w + (size_t)i * HIDDEN * EMBED, fc1_b + i * HIDDEN, nullptr,
            nullptr, Gb, nullptr, nullptr, nullptr, M, HIDDEN, EMBED, Ntok, SEQMAX, 2);
        mfma_gemm<<<dim3(EMBED / 128, gy), 256, 0, stream>>>(
            Gb, fc2_w + (size_t)i * EMBED * HIDDEN, fc2_b + i * EMBED, X,
            O, nullptr, nullptr, nullptr, nullptr, M, EMBED, HIDDEN, Ntok, SEQMAX, 1);
        ln_kernel<<<M, 256, 0, stream>>>(O, X, ln2_g + i * EMBED, ln2_b + i * EMBED, Ntok);
    };

    embed(0);
    embed(1);
    block(0, 392);
    embed(2);
    block(1, 588);
    embed(3);
    block(2, 784);

    ln_kernel<<<NB * SEQMAX, 256, 0, stream>>>(X, H, final_g, final_b, SEQMAX);
    mean_kernel<<<NB, 768, 0, stream>>>(H, MEAN);
    gemm_kernel<<<dim3(EMBED / 64, 1), 256, 0, stream>>>(
        MEAN, head_w1, head_b1, nullptr, HH, NB, EMBED, EMBED, NB, NB, 1);
    gemm_kernel<<<dim3(256 / 64, 1), 256, 0, stream>>>(
        HH, head_w2, head_b2, nullptr, PTCH, NB, 256, EMBED, NB, NB, 0);
    bcast_kernel<<<(NB * IMGSZ * IMGSZ + 255) / 256, 256, 0, stream>>>(PTCH, d_out, flag);
}

// Round 10
// 1443.100 us; speedup vs baseline: 6.9922x; 1.1005x over previous
//
#include <hip/hip_runtime.h>
#include <hip/hip_bf16.h>
#include <math.h>

#define EMBED 768
#define QKVD 2304
#define HEADS 12
#define HD 64
#define HIDDEN 3072
#define NPATCH 196
#define SEQMAX 784
#define NB 8
#define IMGSZ 224
#define GRID 14
#define PATCH 16
#define PSTR 72
#define VROW 832

typedef __hip_bfloat16 bf16;
typedef __attribute__((ext_vector_type(8))) short short8;
typedef __attribute__((ext_vector_type(4))) float f32x4;

__device__ __forceinline__ float b2f(bf16 v) { return __bfloat162float(v); }
__device__ __forceinline__ float geluf(float x) {
    return 0.5f * x * (1.0f + erff(x * 0.70710678118654752f));
}

// async global->LDS, 16B per lane. LDS dest is wave-uniform base + lane*16.
__device__ __forceinline__ void async16(const bf16* g, bf16* l) {
    __builtin_amdgcn_global_load_lds(
        (const __attribute__((address_space(1))) unsigned int*)g,
        (__attribute__((address_space(3))) unsigned int*)l,
        16, 0, 0);
}

#define WAIT_VM0   0x0F70   // vmcnt(0)
#define WAIT_VM3   0x0F73   // vmcnt(3)
#define WAIT_VM4   0x0F74   // vmcnt(4)
#define WAIT_LGKM0 0xC07F   // lgkmcnt(0)

// ---------------------------------------------------------------------------
// Dtype detection (bf16 vs fp32 inputs).
// ---------------------------------------------------------------------------
__global__ __launch_bounds__(256)
void detect_kernel(const unsigned short* __restrict__ raw, int* __restrict__ flag)
{
    __shared__ int bad;
    if (threadIdx.x == 0) bad = 0;
    __syncthreads();
    for (int i = threadIdx.x; i < 8192; i += 256) {
        unsigned int u = (unsigned int)raw[i] << 16;
        float v = __uint_as_float(u);
        if (!(fabsf(v) <= 1e4f)) bad = 1;
    }
    __syncthreads();
    if (threadIdx.x == 0) *flag = bad;
}

// ---------------------------------------------------------------------------
// Fused converters.
// ---------------------------------------------------------------------------
struct CvtF32 {
    const void* src[19];
    int n[19];
    int dstOff[19];
    int blkOff[20];
};
__global__ __launch_bounds__(256)
void convert_f32_all(CvtF32 c, float* __restrict__ base, const int* __restrict__ flag)
{
    int f = *flag;
    int b = blockIdx.x;
    int i = 0;
    #pragma unroll
    for (int j = 0; j < 19; ++j) if (b >= c.blkOff[j + 1]) i = j + 1;
    int e = ((b - c.blkOff[i]) * 256 + threadIdx.x) * 4;
    if (e >= c.n[i]) return;
    float* dst = base + c.dstOff[i] + e;
    if (f) {
        *(float4*)dst = *(const float4*)((const float*)c.src[i] + e);
    } else {
        const bf16* s = (const bf16*)c.src[i] + e;
        dst[0] = b2f(s[0]); dst[1] = b2f(s[1]); dst[2] = b2f(s[2]); dst[3] = b2f(s[3]);
    }
}

struct CvtB16 {
    const void* src[5];
    int n[5];
    int dstOff[5];
    int blkOff[6];
};
__global__ __launch_bounds__(256)
void convert_b16_all(CvtB16 c, bf16* __restrict__ base, const int* __restrict__ flag)
{
    int f = *flag;
    int b = blockIdx.x;
    int i = 0;
    #pragma unroll
    for (int j = 0; j < 5; ++j) if (b >= c.blkOff[j + 1]) i = j + 1;
    int e = ((b - c.blkOff[i]) * 256 + threadIdx.x) * 4;
    if (e >= c.n[i]) return;
    bf16* dst = base + (size_t)c.dstOff[i] + e;
    if (f) {
        float4 v = *(const float4*)((const float*)c.src[i] + e);
        dst[0] = __float2bfloat16(v.x); dst[1] = __float2bfloat16(v.y);
        dst[2] = __float2bfloat16(v.z); dst[3] = __float2bfloat16(v.w);
    } else {
        *(uint2*)dst = *(const uint2*)((const bf16*)c.src[i] + e);
    }
}

// ---------------------------------------------------------------------------
// MFMA bf16 GEMM, templated M-tile (MT x 128), BK=32, double-buffered LDS.
// MT=128: 4 waves x 64x64 (4x4 frags, 4 loads/wave/iter).
// MT=64 : 4 waves x 32x64 (2x4 frags, 3 loads/wave/iter) — for narrow-N GEMMs
//         (more blocks -> occupancy; grid was the binding constraint).
// mode: 0 = fp32 out; 1 = fp32 out + residual; 2 = bf16 out + gelu;
//       3 = qkv head-split -> bf16 Q/K/V all [bh][t][64].
// ---------------------------------------------------------------------------
template<int MT>
__global__ __launch_bounds__(256)
void mfma_gemm(const bf16* __restrict__ A, const bf16* __restrict__ W,
               const float* __restrict__ bias, const float* __restrict__ add,
               float* __restrict__ outF, bf16* __restrict__ outB,
               bf16* __restrict__ Qb, bf16* __restrict__ Kb, bf16* __restrict__ Vb,
               int M, int N, int K, int Ntok, int rowStride, int mode)
{
    constexpr int MI = MT / 32;            // m-frags per wave (4 or 2)
    __shared__ __align__(16) bf16 As[2][MT * 32];
    __shared__ __align__(16) bf16 Bs[2][128 * 32];
    int tid = threadIdx.x;
    int lane = tid & 63;
    int wave = tid >> 6;
    int wm = wave & 1, wn = wave >> 1;
    int m0 = blockIdx.y * MT, n0 = blockIdx.x * 128;

    int lr = lane >> 2;
    int lc = lane & 3;
    // A staging: wave stages rows [(MT/4)*wave, +MT/4)
    int ar0 = (MT / 4) * wave + lr;
    int ma0 = m0 + ar0; if (ma0 >= M) ma0 = M - 1;
    const bf16* aSrc0 = A + (size_t)((ma0 / Ntok) * rowStride + ma0 % Ntok) * K + lc * 8;
    const bf16* aSrc1 = nullptr;
    if constexpr (MT == 128) {
        int ma1 = m0 + ar0 + 16; if (ma1 >= M) ma1 = M - 1;
        aSrc1 = A + (size_t)((ma1 / Ntok) * rowStride + ma1 % Ntok) * K + lc * 8;
    }
    // B staging: wave stages 32 rows
    const bf16* bSrc0 = W + (size_t)(n0 + 32 * wave + lr) * K + lc * 8;
    const bf16* bSrc1 = W + (size_t)(n0 + 32 * wave + 16 + lr) * K + lc * 8;

    int fr = lane & 15;
    int fq = lane >> 4;
    int aOff = (wm * (MT / 2) + fr) * 32 + fq * 8;
    int bOff = (wn * 64 + fr) * 32 + fq * 8;

    f32x4 acc[MI][4] = {};

    auto stage = [&](int buf) {
        async16(aSrc0, As[buf] + ((MT / 4) * wave) * 32);
        if constexpr (MT == 128) {
            async16(aSrc1, As[buf] + ((MT / 4) * wave + 16) * 32);
        }
        async16(bSrc0, Bs[buf] + (32 * wave) * 32);
        async16(bSrc1, Bs[buf] + (32 * wave + 16) * 32);
        aSrc0 += 32; bSrc0 += 32; bSrc1 += 32;
        if constexpr (MT == 128) aSrc1 += 32;
    };

    int nIter = K >> 5;
    stage(0);

    for (int it = 0; it < nIter; ++it) {
        int cur = it & 1;
        __builtin_amdgcn_sched_barrier(0);
        __builtin_amdgcn_s_waitcnt(WAIT_LGKM0);
        __builtin_amdgcn_s_barrier();
        bool pre = (it + 1 < nIter);
        if (pre) {
            stage(cur ^ 1);
            if constexpr (MT == 128) __builtin_amdgcn_s_waitcnt(WAIT_VM4);
            else                     __builtin_amdgcn_s_waitcnt(WAIT_VM3);
        } else {
            __builtin_amdgcn_s_waitcnt(WAIT_VM0);
        }
        __builtin_amdgcn_s_barrier();
        __builtin_amdgcn_sched_barrier(0);

        const bf16* aR = As[cur] + aOff;
        const bf16* bR = Bs[cur] + bOff;
        short8 af[MI], bfr[4];
        #pragma unroll
        for (int mi = 0; mi < MI; ++mi) af[mi] = *(const short8*)(aR + mi * 16 * 32);
        #pragma unroll
        for (int ni = 0; ni < 4; ++ni) bfr[ni] = *(const short8*)(bR + ni * 16 * 32);
        #pragma unroll
        for (int mi = 0; mi < MI; ++mi)
            #pragma unroll
            for (int ni = 0; ni < 4; ++ni)
                acc[mi][ni] = __builtin_amdgcn_mfma_f32_16x16x32_bf16(
                    af[mi], bfr[ni], acc[mi][ni], 0, 0, 0);
    }

    #pragma unroll
    for (int mi = 0; mi < MI; ++mi) {
        #pragma unroll
        for (int ni = 0; ni < 4; ++ni) {
            int n = n0 + wn * 64 + ni * 16 + fr;
            float bs = bias[n];
            #pragma unroll
            for (int r = 0; r < 4; ++r) {
                int m = m0 + wm * (MT / 2) + mi * 16 + fq * 4 + r;
                if (m >= M) continue;
                int bidx = m / Ntok, t = m - bidx * Ntok;
                size_t pr = (size_t)bidx * rowStride + t;
                float v = acc[mi][ni][r] + bs;
                if (mode == 0) {
                    outF[pr * N + n] = v;
                } else if (mode == 1) {
                    outF[pr * N + n] = v + add[pr * N + n];
                } else if (mode == 2) {
                    outB[pr * N + n] = __float2bfloat16(geluf(v));
                } else {
                    int which = n >= 1536 ? 2 : (n >= 768 ? 1 : 0);
                    int nn = n - which * 768;
                    int hh = nn >> 6, d = nn & 63;
                    bf16 bv = __float2bfloat16(v);
                    bf16* dst = which == 0 ? Qb : which == 1 ? Kb : Vb;
                    dst[((size_t)(bidx * HEADS + hh) * SEQMAX + t) * HD + d] = bv;
                }
            }
        }
    }
}

// ---------------------------------------------------------------------------
// Legacy fp32 GEMM (tiny head matmuls only).
// ---------------------------------------------------------------------------
__global__ __launch_bounds__(256)
void gemm_kernel(const float* __restrict__ A, const float* __restrict__ W,
                 const float* __restrict__ bias, const float* __restrict__ add,
                 float* __restrict__ C, int M, int N, int K,
                 int Ntok, int rowStride, int dogelu)
{
    __shared__ __align__(16) float As[16][68];
    __shared__ __align__(16) float Ws[16][68];
    int tid = threadIdx.x;
    int tx = tid & 15, ty = tid >> 4;
    int n0 = blockIdx.x * 64, m0 = blockIdx.y * 64;
    int lrow = tid >> 2;
    int lk   = (tid & 3) << 2;
    int am = m0 + lrow;
    bool aok = (am < M);
    const float* Arow = A;
    if (aok) {
        int pr = (am / Ntok) * rowStride + (am % Ntok);
        Arow = A + (size_t)pr * K;
    }
    int wn = n0 + lrow;
    const float* Wrow = (wn < N) ? (W + (size_t)wn * K) : nullptr;
    float acc[4][4] = {};
    for (int kk = 0; kk < K; kk += 16) {
        float4 av = make_float4(0.f, 0.f, 0.f, 0.f);
        if (aok) av = *(const float4*)(Arow + kk + lk);
        float4 wv = make_float4(0.f, 0.f, 0.f, 0.f);
        if (Wrow) wv = *(const float4*)(Wrow + kk + lk);
        __syncthreads();
        As[lk+0][lrow] = av.x; As[lk+1][lrow] = av.y;
        As[lk+2][lrow] = av.z; As[lk+3][lrow] = av.w;
        Ws[lk+0][lrow] = wv.x; Ws[lk+1][lrow] = wv.y;
        Ws[lk+2][lrow] = wv.z; Ws[lk+3][lrow] = wv.w;
        __syncthreads();
        #pragma unroll
        for (int k = 0; k < 16; ++k) {
            float4 a = *(const float4*)&As[k][ty << 2];
            float4 w = *(const float4*)&Ws[k][tx << 2];
            acc[0][0] += a.x*w.x; acc[0][1] += a.x*w.y; acc[0][2] += a.x*w.z; acc[0][3] += a.x*w.w;
            acc[1][0] += a.y*w.x; acc[1][1] += a.y*w.y; acc[1][2] += a.y*w.z; acc[1][3] += a.y*w.w;
            acc[2][0] += a.z*w.x; acc[2][1] += a.z*w.y; acc[2][2] += a.z*w.z; acc[2][3] += a.z*w.w;
            acc[3][0] += a.w*w.x; acc[3][1] += a.w*w.y; acc[3][2] += a.w*w.z; acc[3][3] += a.w*w.w;
        }
    }
    #pragma unroll
    for (int i = 0; i < 4; ++i) {
        int m = m0 + (ty << 2) + i;
        if (m >= M) continue;
        int pr = (m / Ntok) * rowStride + (m % Ntok);
        float* crow = C + (size_t)pr * N;
        const float* addrow = add ? (add + (size_t)pr * N) : nullptr;
        #pragma unroll
        for (int j = 0; j < 4; ++j) {
            int n = n0 + (tx << 2) + j;
            float v = acc[i][j] + bias[n];
            if (addrow) v += addrow[n];
            if (dogelu) v = geluf(v);
            crow[n] = v;
        }
    }
}

// ---------------------------------------------------------------------------
// LayerNorms.
// ---------------------------------------------------------------------------
__global__ __launch_bounds__(256)
void ln_bf16_kernel(const float* __restrict__ src, bf16* __restrict__ dst,
                    const float* __restrict__ g, const float* __restrict__ bta, int Ntok)
{
    __shared__ float red[256];
    int blk = blockIdx.x;
    int t = blk % Ntok, b = blk / Ntok;
    size_t row = ((size_t)b * SEQMAX + t) * EMBED;
    int tid = threadIdx.x;
    float v0 = src[row + tid], v1 = src[row + tid + 256], v2 = src[row + tid + 512];
    red[tid] = v0 + v1 + v2;
    __syncthreads();
    for (int off = 128; off; off >>= 1) { if (tid < off) red[tid] += red[tid + off]; __syncthreads(); }
    float mu = red[0] * (1.0f / EMBED);
    __syncthreads();
    float d0 = v0 - mu, d1 = v1 - mu, d2 = v2 - mu;
    red[tid] = d0*d0 + d1*d1 + d2*d2;
    __syncthreads();
    for (int off = 128; off; off >>= 1) { if (tid < off) red[tid] += red[tid + off]; __syncthreads(); }
    float rs = rsqrtf(red[0] * (1.0f / EMBED) + 1e-5f);
    dst[row + tid]       = __float2bfloat16(d0 * rs * g[tid]       + bta[tid]);
    dst[row + tid + 256] = __float2bfloat16(d1 * rs * g[tid + 256] + bta[tid + 256]);
    dst[row + tid + 512] = __float2bfloat16(d2 * rs * g[tid + 512] + bta[tid + 512]);
}

__global__ __launch_bounds__(256)
void ln_kernel(const float* __restrict__ src, float* __restrict__ dst,
               const float* __restrict__ g, const float* __restrict__ bta, int Ntok)
{
    __shared__ float red[256];
    int blk = blockIdx.x;
    int t = blk % Ntok, b = blk / Ntok;
    size_t row = ((size_t)b * SEQMAX + t) * EMBED;
    int tid = threadIdx.x;
    float v0 = src[row + tid], v1 = src[row + tid + 256], v2 = src[row + tid + 512];
    red[tid] = v0 + v1 + v2;
    __syncthreads();
    for (int off = 128; off; off >>= 1) { if (tid < off) red[tid] += red[tid + off]; __syncthreads(); }
    float mu = red[0] * (1.0f / EMBED);
    __syncthreads();
    float d0 = v0 - mu, d1 = v1 - mu, d2 = v2 - mu;
    red[tid] = d0*d0 + d1*d1 + d2*d2;
    __syncthreads();
    for (int off = 128; off; off >>= 1) { if (tid < off) red[tid] += red[tid + off]; __syncthreads(); }
    float rs = rsqrtf(red[0] * (1.0f / EMBED) + 1e-5f);
    dst[row + tid]       = d0 * rs * g[tid]       + bta[tid];
    dst[row + tid + 256] = d1 * rs * g[tid + 256] + bta[tid + 256];
    dst[row + tid + 512] = d2 * rs * g[tid + 512] + bta[tid + 512];
}

// ---------------------------------------------------------------------------
// V transpose: V [bh][t][64] -> VT [bh*64+d][VROW], zero-padded keys>=Ntok.
// ---------------------------------------------------------------------------
__global__ __launch_bounds__(256)
void vtrans_kernel(const bf16* __restrict__ Vh, bf16* __restrict__ VT, int Ntok)
{
    __shared__ unsigned short Lt[64 * 66];
    int bh = blockIdx.x;
    int k0 = blockIdx.y * 64;
    const bf16* Vb = Vh + (size_t)bh * SEQMAX * HD;
    int tid = threadIdx.x;
    #pragma unroll
    for (int pass = 0; pass < 8; ++pass) {
        int key_l = (tid >> 5) + pass * 8;
        int d2 = tid & 31;
        unsigned v = 0;
        if (k0 + key_l < Ntok)
            v = *(const unsigned*)(Vb + (size_t)(k0 + key_l) * HD + d2 * 2);
        *(unsigned*)&Lt[key_l * 66 + 2 * d2] = v;
    }
    __syncthreads();
    #pragma unroll
    for (int pass = 0; pass < 8; ++pass) {
        int d = (tid >> 5) + pass * 8;
        int kp = tid & 31;
        unsigned lo = Lt[(2 * kp) * 66 + d];
        unsigned hi = Lt[(2 * kp + 1) * 66 + d];
        *(unsigned*)(VT + ((size_t)bh * HD + d) * VROW + k0 + 2 * kp) = lo | (hi << 16);
    }
}

// ---------------------------------------------------------------------------
// MFMA flash attention v3. Block = (bh, 128-query tile); wave w owns 32 q-rows
// (two 16-row A-fragments). K loads then VT loads issued at top of each
// k-iteration so VT latency is hidden behind S + softmax + P roundtrip.
// Max-free softmax (small scores; clamp 80). P via per-wave LDS patch.
// ---------------------------------------------------------------------------
__global__ __launch_bounds__(256)
void flash_mfma(const bf16* __restrict__ Qh, const bf16* __restrict__ Kh,
                const bf16* __restrict__ VT, bf16* __restrict__ O, int Ntok)
{
    __shared__ __align__(16) unsigned short Plds[4][32 * PSTR];
    int bh = blockIdx.x;
    int b = bh / HEADS, h = bh % HEADS;
    int t0 = blockIdx.y * 128;
    int tid = threadIdx.x;
    int lane = tid & 63, w = tid >> 6;
    int fr = lane & 15, fq = lane >> 4;

    const bf16* Qb = Qh + (size_t)bh * SEQMAX * HD;
    const bf16* Kb = Kh + (size_t)bh * SEQMAX * HD;
    const bf16* Vt = VT + (size_t)bh * HD * VROW;

    short8 aq[2][2];
    #pragma unroll
    for (int qi = 0; qi < 2; ++qi) {
        int tq = t0 + w * 32 + qi * 16 + fr; if (tq >= Ntok) tq = Ntok - 1;
        aq[qi][0] = *(const short8*)(Qb + (size_t)tq * HD + fq * 8);
        aq[qi][1] = *(const short8*)(Qb + (size_t)tq * HD + fq * 8 + 32);
    }

    float lpart[2][4] = {};
    f32x4 oacc[2][4];
    #pragma unroll
    for (int qi = 0; qi < 2; ++qi)
        #pragma unroll
        for (int dg = 0; dg < 4; ++dg) oacc[qi][dg] = (f32x4){0.f, 0.f, 0.f, 0.f};

    unsigned short* Pw = Plds[w];

    for (int k0 = 0; k0 < Ntok; k0 += 64) {
        short8 bk[4][2];
        #pragma unroll
        for (int kg = 0; kg < 4; ++kg) {
            int key = k0 + kg * 16 + fr;
            int keyc = key < Ntok ? key : Ntok - 1;
            bk[kg][0] = *(const short8*)(Kb + (size_t)keyc * HD + fq * 8);
            bk[kg][1] = *(const short8*)(Kb + (size_t)keyc * HD + fq * 8 + 32);
        }
        short8 bv[4][2];
        #pragma unroll
        for (int dg = 0; dg < 4; ++dg) {
            int d = dg * 16 + fr;
            bv[dg][0] = *(const short8*)(Vt + (size_t)d * VROW + k0 + fq * 8);
            bv[dg][1] = *(const short8*)(Vt + (size_t)d * VROW + k0 + fq * 8 + 32);
        }

        float s[2][4][4];
        #pragma unroll
        for (int qi = 0; qi < 2; ++qi)
            #pragma unroll
            for (int kg = 0; kg < 4; ++kg) {
                f32x4 sa = (f32x4){0.f, 0.f, 0.f, 0.f};
                sa = __builtin_amdgcn_mfma_f32_16x16x32_bf16(aq[qi][0], bk[kg][0], sa, 0, 0, 0);
                sa = __builtin_amdgcn_mfma_f32_16x16x32_bf16(aq[qi][1], bk[kg][1], sa, 0, 0, 0);
                #pragma unroll
                for (int r = 0; r < 4; ++r) s[qi][kg][r] = sa[r];
            }

        #pragma unroll
        for (int qi = 0; qi < 2; ++qi)
            #pragma unroll
            for (int kg = 0; kg < 4; ++kg) {
                bool ok = (k0 + kg * 16 + fr) < Ntok;
                #pragma unroll
                for (int r = 0; r < 4; ++r) {
                    float p = ok ? __expf(fminf(s[qi][kg][r] * 0.125f, 80.f)) : 0.f;
                    lpart[qi][r] += p;
                    bf16 pb = __float2bfloat16(p);
                    Pw[(qi * 16 + fq * 4 + r) * PSTR + kg * 16 + fr] = *(unsigned short*)&pb;
                }
            }

        short8 ap[2][2];
        #pragma unroll
        for (int qi = 0; qi < 2; ++qi) {
            ap[qi][0] = *(const short8*)(Pw + (qi * 16 + fr) * PSTR + fq * 8);
            ap[qi][1] = *(const short8*)(Pw + (qi * 16 + fr) * PSTR + fq * 8 + 32);
        }

        #pragma unroll
        for (int qi = 0; qi < 2; ++qi)
            #pragma unroll
            for (int dg = 0; dg < 4; ++dg) {
                oacc[qi][dg] = __builtin_amdgcn_mfma_f32_16x16x32_bf16(
                    ap[qi][0], bv[dg][0], oacc[qi][dg], 0, 0, 0);
                oacc[qi][dg] = __builtin_amdgcn_mfma_f32_16x16x32_bf16(
                    ap[qi][1], bv[dg][1], oacc[qi][dg], 0, 0, 0);
            }
    }

    #pragma unroll
    for (int qi = 0; qi < 2; ++qi)
        #pragma unroll
        for (int r = 0; r < 4; ++r) {
            float l = lpart[qi][r];
            l += __shfl_xor(l, 1); l += __shfl_xor(l, 2);
            l += __shfl_xor(l, 4); l += __shfl_xor(l, 8);
            int t = t0 + w * 32 + qi * 16 + fq * 4 + r;
            if (t >= Ntok) continue;
            float inv = 1.0f / l;
            bf16* dst = O + ((size_t)b * SEQMAX + t) * EMBED + h * HD;
            #pragma unroll
            for (int dg = 0; dg < 4; ++dg)
                dst[dg * 16 + fr] = __float2bfloat16(oacc[qi][dg][r] * inv);
        }
}

// ---------------------------------------------------------------------------
__global__ __launch_bounds__(256)
void patch_gather(const void* __restrict__ img, bf16* __restrict__ Ap,
                  const int* __restrict__ flag)
{
    int f = *flag;
    int idx = blockIdx.x * 256 + threadIdx.x;
    if (idx >= NB * NPATCH * EMBED) return;
    int col = idx % EMBED;
    int row = idx / EMBED;
    int t = row % NPATCH, b = row / NPATCH;
    int c = col >> 8;
    int pr = (col >> 4) & 15;
    int pc = col & 15;
    int gr = t / GRID, gc = t % GRID;
    size_t off = ((size_t)(b * 3 + c) * IMGSZ + gr * PATCH + pr) * IMGSZ + gc * PATCH + pc;
    float v = f ? ((const float*)img)[off] : b2f(((const bf16*)img)[off]);
    Ap[idx] = __float2bfloat16(v);
}

__global__ __launch_bounds__(256)
void posadd_kernel(const float* __restrict__ PEO, const float* __restrict__ sp,
                   const float* __restrict__ ip, float* __restrict__ X, int imgIdx)
{
    int idx = blockIdx.x * 256 + threadIdx.x;
    if (idx >= NB * NPATCH * EMBED) return;
    int e = idx % EMBED;
    int row = idx / EMBED;
    int t = row % NPATCH, b = row / NPATCH;
    float pos = (e < 384) ? sp[t * 384 + e] : ip[imgIdx * 384 + (e - 384)];
    X[((size_t)b * SEQMAX + imgIdx * NPATCH + t) * EMBED + e] = PEO[idx] + pos;
}

__global__ __launch_bounds__(768)
void mean_kernel(const float* __restrict__ H, float* __restrict__ Mn)
{
    int b = blockIdx.x;
    int e = threadIdx.x;
    float s = 0.f;
    for (int t = 0; t < SEQMAX; ++t) s += H[((size_t)b * SEQMAX + t) * EMBED + e];
    Mn[b * EMBED + e] = s * (1.0f / SEQMAX);
}

__global__ __launch_bounds__(256)
void bcast_kernel(const float* __restrict__ P, void* __restrict__ out,
                  const int* __restrict__ flag)
{
    int f = *flag;
    int idx = blockIdx.x * 256 + threadIdx.x;
    if (idx >= NB * IMGSZ * IMGSZ) return;
    int c = idx % IMGSZ;
    int r = (idx / IMGSZ) % IMGSZ;
    int b = idx / (IMGSZ * IMGSZ);
    float v = P[b * 256 + (r & 15) * 16 + (c & 15)];
    if (f) ((float*)out)[idx] = v;
    else   ((bf16*)out)[idx] = __float2bfloat16(v);
}

// ---------------------------------------------------------------------------
extern "C" void kernel_launch(void* const* d_in, const int* in_sizes, int n_in,
                              void* d_out, int out_size, void* d_ws, size_t ws_size,
                              hipStream_t stream)
{
    (void)n_in; (void)out_size; (void)ws_size;
    const void* img[4] = {d_in[0], d_in[1], d_in[2], d_in[3]};

    float* ws = (float*)d_ws;
    int* flag = (int*)ws;

    detect_kernel<<<1, 256, 0, stream>>>((const unsigned short*)d_in[0], flag);

    const bool isBig[28] = {0,0,0,0, 1,0,0,0, 0,0,1,0, 1,0,0,0, 1,0,1,0, 0,0,0,0, 0,0,0,0};
    float* fBase = ws + 16;
    float* fPtr[28] = {};
    CvtF32 cf;
    int fCnt = 0, fBlk = 0;
    cf.blkOff[0] = 0;
    {
        float* p = fBase;
        for (int i = 4; i < 28; ++i) {
            if (isBig[i]) continue;
            fPtr[i] = p;
            int n = in_sizes[i];
            cf.src[fCnt] = d_in[i];
            cf.n[fCnt] = n;
            cf.dstOff[fCnt] = (int)(p - fBase);
            fBlk += (n + 1023) / 1024;
            cf.blkOff[fCnt + 1] = fBlk;
            p += n;
            ++fCnt;
        }
        fBase = ws + 16;
        fPtr[0] = p;   // sentinel: arena end
    }
    convert_f32_all<<<fBlk, 256, 0, stream>>>(cf, fBase, flag);

    bf16* bPtr[28] = {};
    bf16* bBase = (bf16*)fPtr[0];
    CvtB16 cb;
    int bCnt = 0, bBlk = 0;
    cb.blkOff[0] = 0;
    float* arenaEnd;
    {
        bf16* p = bBase;
        for (int i = 4; i < 28; ++i) {
            if (!isBig[i]) continue;
            bPtr[i] = p;
            int n = in_sizes[i];
            cb.src[bCnt] = d_in[i];
            cb.n[bCnt] = n;
            cb.dstOff[bCnt] = (int)(p - bBase);
            bBlk += (n + 1023) / 1024;
            cb.blkOff[bCnt + 1] = bBlk;
            p += n;
            ++bCnt;
        }
        size_t off = p - (bf16*)ws;
        off = (off + 7) & ~(size_t)7;
        arenaEnd = (float*)((bf16*)ws + off);
    }
    convert_b16_all<<<bBlk, 256, 0, stream>>>(cb, bBase, flag);

    const bf16* pe_w   = bPtr[4];
    const bf16* qkv_w  = bPtr[10];
    const bf16* proj_w = bPtr[12];
    const bf16* fc1_w  = bPtr[16];
    const bf16* fc2_w  = bPtr[18];
    const float* pe_b      = fPtr[5];
    const float* sp        = fPtr[6];
    const float* ip        = fPtr[7];
    const float* ln_attn_g = fPtr[8];
    const float* ln_attn_b = fPtr[9];
    const float* qkv_b     = fPtr[11];
    const float* proj_b    = fPtr[13];
    const float* ln1_g     = fPtr[14];
    const float* ln1_b     = fPtr[15];
    const float* fc1_b     = fPtr[17];
    const float* fc2_b     = fPtr[19];
    const float* ln2_g     = fPtr[20];
    const float* ln2_b     = fPtr[21];
    const float* final_g   = fPtr[22];
    const float* final_b   = fPtr[23];
    const float* head_w1   = fPtr[24];
    const float* head_b1   = fPtr[25];
    const float* head_w2   = fPtr[26];
    const float* head_b2   = fPtr[27];

    const size_t SEQ = (size_t)NB * SEQMAX * EMBED;          // 4,816,896
    const size_t HID_ELEMS = (size_t)NB * SEQMAX * HIDDEN;   // 19,267,584
    const size_t EMB_ELEMS = (size_t)NB * NPATCH * EMBED;    // 1,204,224
    float* X    = arenaEnd;
    float* H    = X + SEQ;
    float* O    = H + SEQ;
    float* PEO  = O + SEQ;
    float* MEAN = PEO + EMB_ELEMS;
    float* HH   = MEAN + NB * EMBED;
    float* PTCH = HH + NB * EMBED;
    bf16* Hb    = (bf16*)(PTCH + NB * 256 + 16);
    bf16* Ob    = Hb + SEQ;
    bf16* Gb    = Ob + SEQ;
    bf16* PEb   = Gb + HID_ELEMS;
    bf16* Qb    = PEb + EMB_ELEMS;
    bf16* Kb    = Qb + SEQ;
    bf16* Vb    = Kb + SEQ;
    bf16* VTb   = Vb + SEQ;

    const int nEmb = NB * NPATCH * EMBED;

    auto embed = [&](int i) {
        patch_gather<<<(nEmb + 255) / 256, 256, 0, stream>>>(img[i], PEb, flag);
        dim3 g(EMBED / 128, (NB * NPATCH + 63) / 64);
        mfma_gemm<64><<<g, 256, 0, stream>>>(PEb, pe_w + (size_t)i * EMBED * EMBED,
                                             pe_b + i * EMBED, nullptr, PEO, nullptr,
                                             nullptr, nullptr, nullptr,
                                             NB * NPATCH, EMBED, EMBED,
                                             NB * NPATCH, NB * NPATCH, 0);
        posadd_kernel<<<(nEmb + 255) / 256, 256, 0, stream>>>(PEO, sp, ip, X, i);
    };

    auto block = [&](int i, int Ntok) {
        int M = NB * Ntok;
        int gy128 = (M + 127) / 128;
        int gy64  = (M + 63) / 64;
        int nkt = (Ntok + 63) / 64;
        int nqt = (Ntok + 127) / 128;
        ln_bf16_kernel<<<M, 256, 0, stream>>>(X, Hb, ln_attn_g + i * EMBED, ln_attn_b + i * EMBED, Ntok);
        mfma_gemm<128><<<dim3(QKVD / 128, gy128), 256, 0, stream>>>(
            Hb, qkv_w + (size_t)i * QKVD * EMBED, qkv_b + i * QKVD, nullptr,
            nullptr, nullptr, Qb, Kb, Vb, M, QKVD, EMBED, Ntok, SEQMAX, 3);
        vtrans_kernel<<<dim3(NB * HEADS, nkt), 256, 0, stream>>>(Vb, VTb, Ntok);
        flash_mfma<<<dim3(NB * HEADS, nqt), 256, 0, stream>>>(Qb, Kb, VTb, Ob, Ntok);
        mfma_gemm<64><<<dim3(EMBED / 128, gy64), 256, 0, stream>>>(
            Ob, proj_w + (size_t)i * EMBED * EMBED, proj_b + i * EMBED, X,
            X, nullptr, nullptr, nullptr, nullptr, M, EMBED, EMBED, Ntok, SEQMAX, 1);
        ln_bf16_kernel<<<M, 256, 0, stream>>>(X, Hb, ln1_g + i * EMBED, ln1_b + i * EMBED, Ntok);
        mfma_gemm<128><<<dim3(HIDDEN / 128, gy128), 256, 0, stream>>>(
            Hb, fc1_w + (size_t)i * HIDDEN * EMBED, fc1_b + i * HIDDEN, nullptr,
            nullptr, Gb, nullptr, nullptr, nullptr, M, HIDDEN, EMBED, Ntok, SEQMAX, 2);
        mfma_gemm<64><<<dim3(EMBED / 128, gy64), 256, 0, stream>>>(
            Gb, fc2_w + (size_t)i * EMBED * HIDDEN, fc2_b + i * EMBED, X,
            O, nullptr, nullptr, nullptr, nullptr, M, EMBED, HIDDEN, Ntok, SEQMAX, 1);
        ln_kernel<<<M, 256, 0, stream>>>(O, X, ln2_g + i * EMBED, ln2_b + i * EMBED, Ntok);
    };

    embed(0);
    embed(1);
    block(0, 392);
    embed(2);
    block(1, 588);
    embed(3);
    block(2, 784);

    ln_kernel<<<NB * SEQMAX, 256, 0, stream>>>(X, H, final_g, final_b, SEQMAX);
    mean_kernel<<<NB, 768, 0, stream>>>(H, MEAN);
    gemm_kernel<<<dim3(EMBED / 64, 1), 256, 0, stream>>>(
        MEAN, head_w1, head_b1, nullptr, HH, NB, EMBED, EMBED, NB, NB, 1);
    gemm_kernel<<<dim3(256 / 64, 1), 256, 0, stream>>>(
        HH, head_w2, head_b2, nullptr, PTCH, NB, 256, EMBED, NB, NB, 0);
    bcast_kernel<<<(NB * IMGSZ * IMGSZ + 255) / 256, 256, 0, stream>>>(PTCH, d_out, flag);
}

// Round 11
// 1441.622 us; speedup vs baseline: 6.9994x; 1.0010x over previous
//
#include <hip/hip_runtime.h>
#include <hip/hip_bf16.h>
#include <math.h>

#define EMBED 768
#define QKVD 2304
#define HEADS 12
#define HD 64
#define HIDDEN 3072
#define NPATCH 196
#define SEQMAX 784
#define NB 8
#define IMGSZ 224
#define GRID 14
#define PATCH 16
#define PSTR 72
#define VROW 832

typedef __hip_bfloat16 bf16;
typedef __attribute__((ext_vector_type(8))) short short8;
typedef __attribute__((ext_vector_type(4))) float f32x4;

__device__ __forceinline__ float b2f(bf16 v) { return __bfloat162float(v); }
__device__ __forceinline__ float geluf(float x) {
    return 0.5f * x * (1.0f + erff(x * 0.70710678118654752f));
}

// async global->LDS, 16B per lane. LDS dest is wave-uniform base + lane*16.
__device__ __forceinline__ void async16(const bf16* g, bf16* l) {
    __builtin_amdgcn_global_load_lds(
        (const __attribute__((address_space(1))) unsigned int*)g,
        (__attribute__((address_space(3))) unsigned int*)l,
        16, 0, 0);
}

#define WAIT_VM0   0x0F70   // vmcnt(0)
#define WAIT_VM3   0x0F73   // vmcnt(3)
#define WAIT_VM4   0x0F74   // vmcnt(4)
#define WAIT_VM6   0x0F76   // vmcnt(6)
#define WAIT_VM8   0x0F78   // vmcnt(8)
#define WAIT_LGKM0 0xC07F   // lgkmcnt(0)

// ---------------------------------------------------------------------------
// Dtype detection (bf16 vs fp32 inputs).
// ---------------------------------------------------------------------------
__global__ __launch_bounds__(256)
void detect_kernel(const unsigned short* __restrict__ raw, int* __restrict__ flag)
{
    __shared__ int bad;
    if (threadIdx.x == 0) bad = 0;
    __syncthreads();
    for (int i = threadIdx.x; i < 8192; i += 256) {
        unsigned int u = (unsigned int)raw[i] << 16;
        float v = __uint_as_float(u);
        if (!(fabsf(v) <= 1e4f)) bad = 1;
    }
    __syncthreads();
    if (threadIdx.x == 0) *flag = bad;
}

// ---------------------------------------------------------------------------
// Fused converters.
// ---------------------------------------------------------------------------
struct CvtF32 {
    const void* src[19];
    int n[19];
    int dstOff[19];
    int blkOff[20];
};
__global__ __launch_bounds__(256)
void convert_f32_all(CvtF32 c, float* __restrict__ base, const int* __restrict__ flag)
{
    int f = *flag;
    int b = blockIdx.x;
    int i = 0;
    #pragma unroll
    for (int j = 0; j < 19; ++j) if (b >= c.blkOff[j + 1]) i = j + 1;
    int e = ((b - c.blkOff[i]) * 256 + threadIdx.x) * 4;
    if (e >= c.n[i]) return;
    float* dst = base + c.dstOff[i] + e;
    if (f) {
        *(float4*)dst = *(const float4*)((const float*)c.src[i] + e);
    } else {
        const bf16* s = (const bf16*)c.src[i] + e;
        dst[0] = b2f(s[0]); dst[1] = b2f(s[1]); dst[2] = b2f(s[2]); dst[3] = b2f(s[3]);
    }
}

struct CvtB16 {
    const void* src[5];
    int n[5];
    int dstOff[5];
    int blkOff[6];
};
__global__ __launch_bounds__(256)
void convert_b16_all(CvtB16 c, bf16* __restrict__ base, const int* __restrict__ flag)
{
    int f = *flag;
    int b = blockIdx.x;
    int i = 0;
    #pragma unroll
    for (int j = 0; j < 5; ++j) if (b >= c.blkOff[j + 1]) i = j + 1;
    int e = ((b - c.blkOff[i]) * 256 + threadIdx.x) * 4;
    if (e >= c.n[i]) return;
    bf16* dst = base + (size_t)c.dstOff[i] + e;
    if (f) {
        float4 v = *(const float4*)((const float*)c.src[i] + e);
        dst[0] = __float2bfloat16(v.x); dst[1] = __float2bfloat16(v.y);
        dst[2] = __float2bfloat16(v.z); dst[3] = __float2bfloat16(v.w);
    } else {
        *(uint2*)dst = *(const uint2*)((const bf16*)c.src[i] + e);
    }
}

// ---------------------------------------------------------------------------
// MFMA bf16 GEMM, templated M-tile (MT x 128), BK=32, 3-stage LDS ring with
// prefetch distance 2: the vmcnt wait for the current tile only requires the
// group issued TWO iterations ago, so loads get ~2 iterations to land.
// mode: 0 = fp32 out; 1 = fp32 out + residual; 2 = bf16 out + gelu;
//       3 = qkv head-split -> bf16 Q/K/V all [bh][t][64].
// ---------------------------------------------------------------------------
template<int MT>
__global__ __launch_bounds__(256)
void mfma_gemm(const bf16* __restrict__ A, const bf16* __restrict__ W,
               const float* __restrict__ bias, const float* __restrict__ add,
               float* __restrict__ outF, bf16* __restrict__ outB,
               bf16* __restrict__ Qb, bf16* __restrict__ Kb, bf16* __restrict__ Vb,
               int M, int N, int K, int Ntok, int rowStride, int mode)
{
    constexpr int MI = MT / 32;            // m-frags per wave (4 or 2)
    __shared__ __align__(16) bf16 As[3][MT * 32];
    __shared__ __align__(16) bf16 Bs[3][128 * 32];
    int tid = threadIdx.x;
    int lane = tid & 63;
    int wave = tid >> 6;
    int wm = wave & 1, wn = wave >> 1;
    int m0 = blockIdx.y * MT, n0 = blockIdx.x * 128;

    int lr = lane >> 2;
    int lc = lane & 3;
    int ar0 = (MT / 4) * wave + lr;
    int ma0 = m0 + ar0; if (ma0 >= M) ma0 = M - 1;
    const bf16* aSrc0 = A + (size_t)((ma0 / Ntok) * rowStride + ma0 % Ntok) * K + lc * 8;
    const bf16* aSrc1 = nullptr;
    if constexpr (MT == 128) {
        int ma1 = m0 + ar0 + 16; if (ma1 >= M) ma1 = M - 1;
        aSrc1 = A + (size_t)((ma1 / Ntok) * rowStride + ma1 % Ntok) * K + lc * 8;
    }
    const bf16* bSrc0 = W + (size_t)(n0 + 32 * wave + lr) * K + lc * 8;
    const bf16* bSrc1 = W + (size_t)(n0 + 32 * wave + 16 + lr) * K + lc * 8;

    int fr = lane & 15;
    int fq = lane >> 4;
    int aOff = (wm * (MT / 2) + fr) * 32 + fq * 8;
    int bOff = (wn * 64 + fr) * 32 + fq * 8;

    f32x4 acc[MI][4] = {};

    auto stage = [&](int buf) {
        async16(aSrc0, As[buf] + ((MT / 4) * wave) * 32);
        if constexpr (MT == 128) {
            async16(aSrc1, As[buf] + ((MT / 4) * wave + 16) * 32);
        }
        async16(bSrc0, Bs[buf] + (32 * wave) * 32);
        async16(bSrc1, Bs[buf] + (32 * wave + 16) * 32);
        aSrc0 += 32; bSrc0 += 32; bSrc1 += 32;
        if constexpr (MT == 128) aSrc1 += 32;
    };

    int nIter = K >> 5;                 // >= 24 at all call sites
    stage(0);
    stage(1);

    int cur = 0;
    for (int it = 0; it < nIter; ++it) {
        __builtin_amdgcn_sched_barrier(0);
        __builtin_amdgcn_s_waitcnt(WAIT_LGKM0);   // my reads of ring[cur] (prev use) done
        __builtin_amdgcn_s_barrier();             // all waves done reading buffer being overwritten
        if (it + 2 < nIter) {
            int nxt = cur + 2; if (nxt >= 3) nxt -= 3;
            stage(nxt);                           // prefetch distance 2
            if constexpr (MT == 128) __builtin_amdgcn_s_waitcnt(WAIT_VM8);
            else                     __builtin_amdgcn_s_waitcnt(WAIT_VM6);
        } else if (it + 1 < nIter) {
            if constexpr (MT == 128) __builtin_amdgcn_s_waitcnt(WAIT_VM4);
            else                     __builtin_amdgcn_s_waitcnt(WAIT_VM3);
        } else {
            __builtin_amdgcn_s_waitcnt(WAIT_VM0);
        }
        __builtin_amdgcn_s_barrier();             // ring[cur] visible to all waves
        __builtin_amdgcn_sched_barrier(0);

        const bf16* aR = As[cur] + aOff;
        const bf16* bR = Bs[cur] + bOff;
        short8 af[MI], bfr[4];
        #pragma unroll
        for (int mi = 0; mi < MI; ++mi) af[mi] = *(const short8*)(aR + mi * 16 * 32);
        #pragma unroll
        for (int ni = 0; ni < 4; ++ni) bfr[ni] = *(const short8*)(bR + ni * 16 * 32);
        #pragma unroll
        for (int mi = 0; mi < MI; ++mi)
            #pragma unroll
            for (int ni = 0; ni < 4; ++ni)
                acc[mi][ni] = __builtin_amdgcn_mfma_f32_16x16x32_bf16(
                    af[mi], bfr[ni], acc[mi][ni], 0, 0, 0);
        if (++cur >= 3) cur = 0;
    }

    #pragma unroll
    for (int mi = 0; mi < MI; ++mi) {
        #pragma unroll
        for (int ni = 0; ni < 4; ++ni) {
            int n = n0 + wn * 64 + ni * 16 + fr;
            float bs = bias[n];
            #pragma unroll
            for (int r = 0; r < 4; ++r) {
                int m = m0 + wm * (MT / 2) + mi * 16 + fq * 4 + r;
                if (m >= M) continue;
                int bidx = m / Ntok, t = m - bidx * Ntok;
                size_t pr = (size_t)bidx * rowStride + t;
                float v = acc[mi][ni][r] + bs;
                if (mode == 0) {
                    outF[pr * N + n] = v;
                } else if (mode == 1) {
                    outF[pr * N + n] = v + add[pr * N + n];
                } else if (mode == 2) {
                    outB[pr * N + n] = __float2bfloat16(geluf(v));
                } else {
                    int which = n >= 1536 ? 2 : (n >= 768 ? 1 : 0);
                    int nn = n - which * 768;
                    int hh = nn >> 6, d = nn & 63;
                    bf16 bv = __float2bfloat16(v);
                    bf16* dst = which == 0 ? Qb : which == 1 ? Kb : Vb;
                    dst[((size_t)(bidx * HEADS + hh) * SEQMAX + t) * HD + d] = bv;
                }
            }
        }
    }
}

// ---------------------------------------------------------------------------
// Legacy fp32 GEMM (tiny head matmuls only).
// ---------------------------------------------------------------------------
__global__ __launch_bounds__(256)
void gemm_kernel(const float* __restrict__ A, const float* __restrict__ W,
                 const float* __restrict__ bias, const float* __restrict__ add,
                 float* __restrict__ C, int M, int N, int K,
                 int Ntok, int rowStride, int dogelu)
{
    __shared__ __align__(16) float As[16][68];
    __shared__ __align__(16) float Ws[16][68];
    int tid = threadIdx.x;
    int tx = tid & 15, ty = tid >> 4;
    int n0 = blockIdx.x * 64, m0 = blockIdx.y * 64;
    int lrow = tid >> 2;
    int lk   = (tid & 3) << 2;
    int am = m0 + lrow;
    bool aok = (am < M);
    const float* Arow = A;
    if (aok) {
        int pr = (am / Ntok) * rowStride + (am % Ntok);
        Arow = A + (size_t)pr * K;
    }
    int wn = n0 + lrow;
    const float* Wrow = (wn < N) ? (W + (size_t)wn * K) : nullptr;
    float acc[4][4] = {};
    for (int kk = 0; kk < K; kk += 16) {
        float4 av = make_float4(0.f, 0.f, 0.f, 0.f);
        if (aok) av = *(const float4*)(Arow + kk + lk);
        float4 wv = make_float4(0.f, 0.f, 0.f, 0.f);
        if (Wrow) wv = *(const float4*)(Wrow + kk + lk);
        __syncthreads();
        As[lk+0][lrow] = av.x; As[lk+1][lrow] = av.y;
        As[lk+2][lrow] = av.z; As[lk+3][lrow] = av.w;
        Ws[lk+0][lrow] = wv.x; Ws[lk+1][lrow] = wv.y;
        Ws[lk+2][lrow] = wv.z; Ws[lk+3][lrow] = wv.w;
        __syncthreads();
        #pragma unroll
        for (int k = 0; k < 16; ++k) {
            float4 a = *(const float4*)&As[k][ty << 2];
            float4 w = *(const float4*)&Ws[k][tx << 2];
            acc[0][0] += a.x*w.x; acc[0][1] += a.x*w.y; acc[0][2] += a.x*w.z; acc[0][3] += a.x*w.w;
            acc[1][0] += a.y*w.x; acc[1][1] += a.y*w.y; acc[1][2] += a.y*w.z; acc[1][3] += a.y*w.w;
            acc[2][0] += a.z*w.x; acc[2][1] += a.z*w.y; acc[2][2] += a.z*w.z; acc[2][3] += a.z*w.w;
            acc[3][0] += a.w*w.x; acc[3][1] += a.w*w.y; acc[3][2] += a.w*w.z; acc[3][3] += a.w*w.w;
        }
    }
    #pragma unroll
    for (int i = 0; i < 4; ++i) {
        int m = m0 + (ty << 2) + i;
        if (m >= M) continue;
        int pr = (m / Ntok) * rowStride + (m % Ntok);
        float* crow = C + (size_t)pr * N;
        const float* addrow = add ? (add + (size_t)pr * N) : nullptr;
        #pragma unroll
        for (int j = 0; j < 4; ++j) {
            int n = n0 + (tx << 2) + j;
            float v = acc[i][j] + bias[n];
            if (addrow) v += addrow[n];
            if (dogelu) v = geluf(v);
            crow[n] = v;
        }
    }
}

// ---------------------------------------------------------------------------
// LayerNorms.
// ---------------------------------------------------------------------------
__global__ __launch_bounds__(256)
void ln_bf16_kernel(const float* __restrict__ src, bf16* __restrict__ dst,
                    const float* __restrict__ g, const float* __restrict__ bta, int Ntok)
{
    __shared__ float red[256];
    int blk = blockIdx.x;
    int t = blk % Ntok, b = blk / Ntok;
    size_t row = ((size_t)b * SEQMAX + t) * EMBED;
    int tid = threadIdx.x;
    float v0 = src[row + tid], v1 = src[row + tid + 256], v2 = src[row + tid + 512];
    red[tid] = v0 + v1 + v2;
    __syncthreads();
    for (int off = 128; off; off >>= 1) { if (tid < off) red[tid] += red[tid + off]; __syncthreads(); }
    float mu = red[0] * (1.0f / EMBED);
    __syncthreads();
    float d0 = v0 - mu, d1 = v1 - mu, d2 = v2 - mu;
    red[tid] = d0*d0 + d1*d1 + d2*d2;
    __syncthreads();
    for (int off = 128; off; off >>= 1) { if (tid < off) red[tid] += red[tid + off]; __syncthreads(); }
    float rs = rsqrtf(red[0] * (1.0f / EMBED) + 1e-5f);
    dst[row + tid]       = __float2bfloat16(d0 * rs * g[tid]       + bta[tid]);
    dst[row + tid + 256] = __float2bfloat16(d1 * rs * g[tid + 256] + bta[tid + 256]);
    dst[row + tid + 512] = __float2bfloat16(d2 * rs * g[tid + 512] + bta[tid + 512]);
}

__global__ __launch_bounds__(256)
void ln_kernel(const float* __restrict__ src, float* __restrict__ dst,
               const float* __restrict__ g, const float* __restrict__ bta, int Ntok)
{
    __shared__ float red[256];
    int blk = blockIdx.x;
    int t = blk % Ntok, b = blk / Ntok;
    size_t row = ((size_t)b * SEQMAX + t) * EMBED;
    int tid = threadIdx.x;
    float v0 = src[row + tid], v1 = src[row + tid + 256], v2 = src[row + tid + 512];
    red[tid] = v0 + v1 + v2;
    __syncthreads();
    for (int off = 128; off; off >>= 1) { if (tid < off) red[tid] += red[tid + off]; __syncthreads(); }
    float mu = red[0] * (1.0f / EMBED);
    __syncthreads();
    float d0 = v0 - mu, d1 = v1 - mu, d2 = v2 - mu;
    red[tid] = d0*d0 + d1*d1 + d2*d2;
    __syncthreads();
    for (int off = 128; off; off >>= 1) { if (tid < off) red[tid] += red[tid + off]; __syncthreads(); }
    float rs = rsqrtf(red[0] * (1.0f / EMBED) + 1e-5f);
    dst[row + tid]       = d0 * rs * g[tid]       + bta[tid];
    dst[row + tid + 256] = d1 * rs * g[tid + 256] + bta[tid + 256];
    dst[row + tid + 512] = d2 * rs * g[tid + 512] + bta[tid + 512];
}

// ---------------------------------------------------------------------------
// V transpose: V [bh][t][64] -> VT [bh*64+d][VROW], zero-padded keys>=Ntok.
// ---------------------------------------------------------------------------
__global__ __launch_bounds__(256)
void vtrans_kernel(const bf16* __restrict__ Vh, bf16* __restrict__ VT, int Ntok)
{
    __shared__ unsigned short Lt[64 * 66];
    int bh = blockIdx.x;
    int k0 = blockIdx.y * 64;
    const bf16* Vb = Vh + (size_t)bh * SEQMAX * HD;
    int tid = threadIdx.x;
    #pragma unroll
    for (int pass = 0; pass < 8; ++pass) {
        int key_l = (tid >> 5) + pass * 8;
        int d2 = tid & 31;
        unsigned v = 0;
        if (k0 + key_l < Ntok)
            v = *(const unsigned*)(Vb + (size_t)(k0 + key_l) * HD + d2 * 2);
        *(unsigned*)&Lt[key_l * 66 + 2 * d2] = v;
    }
    __syncthreads();
    #pragma unroll
    for (int pass = 0; pass < 8; ++pass) {
        int d = (tid >> 5) + pass * 8;
        int kp = tid & 31;
        unsigned lo = Lt[(2 * kp) * 66 + d];
        unsigned hi = Lt[(2 * kp + 1) * 66 + d];
        *(unsigned*)(VT + ((size_t)bh * HD + d) * VROW + k0 + 2 * kp) = lo | (hi << 16);
    }
}

// ---------------------------------------------------------------------------
// MFMA flash attention v3. Block = (bh, 128-query tile); wave w owns 32 q-rows
// (two 16-row A-fragments). K loads then VT loads issued at top of each
// k-iteration so VT latency is hidden behind S + softmax + P roundtrip.
// Max-free softmax (small scores; clamp 80). P via per-wave LDS patch.
// ---------------------------------------------------------------------------
__global__ __launch_bounds__(256)
void flash_mfma(const bf16* __restrict__ Qh, const bf16* __restrict__ Kh,
                const bf16* __restrict__ VT, bf16* __restrict__ O, int Ntok)
{
    __shared__ __align__(16) unsigned short Plds[4][32 * PSTR];
    int bh = blockIdx.x;
    int b = bh / HEADS, h = bh % HEADS;
    int t0 = blockIdx.y * 128;
    int tid = threadIdx.x;
    int lane = tid & 63, w = tid >> 6;
    int fr = lane & 15, fq = lane >> 4;

    const bf16* Qb = Qh + (size_t)bh * SEQMAX * HD;
    const bf16* Kb = Kh + (size_t)bh * SEQMAX * HD;
    const bf16* Vt = VT + (size_t)bh * HD * VROW;

    short8 aq[2][2];
    #pragma unroll
    for (int qi = 0; qi < 2; ++qi) {
        int tq = t0 + w * 32 + qi * 16 + fr; if (tq >= Ntok) tq = Ntok - 1;
        aq[qi][0] = *(const short8*)(Qb + (size_t)tq * HD + fq * 8);
        aq[qi][1] = *(const short8*)(Qb + (size_t)tq * HD + fq * 8 + 32);
    }

    float lpart[2][4] = {};
    f32x4 oacc[2][4];
    #pragma unroll
    for (int qi = 0; qi < 2; ++qi)
        #pragma unroll
        for (int dg = 0; dg < 4; ++dg) oacc[qi][dg] = (f32x4){0.f, 0.f, 0.f, 0.f};

    unsigned short* Pw = Plds[w];

    for (int k0 = 0; k0 < Ntok; k0 += 64) {
        short8 bk[4][2];
        #pragma unroll
        for (int kg = 0; kg < 4; ++kg) {
            int key = k0 + kg * 16 + fr;
            int keyc = key < Ntok ? key : Ntok - 1;
            bk[kg][0] = *(const short8*)(Kb + (size_t)keyc * HD + fq * 8);
            bk[kg][1] = *(const short8*)(Kb + (size_t)keyc * HD + fq * 8 + 32);
        }
        short8 bv[4][2];
        #pragma unroll
        for (int dg = 0; dg < 4; ++dg) {
            int d = dg * 16 + fr;
            bv[dg][0] = *(const short8*)(Vt + (size_t)d * VROW + k0 + fq * 8);
            bv[dg][1] = *(const short8*)(Vt + (size_t)d * VROW + k0 + fq * 8 + 32);
        }

        float s[2][4][4];
        #pragma unroll
        for (int qi = 0; qi < 2; ++qi)
            #pragma unroll
            for (int kg = 0; kg < 4; ++kg) {
                f32x4 sa = (f32x4){0.f, 0.f, 0.f, 0.f};
                sa = __builtin_amdgcn_mfma_f32_16x16x32_bf16(aq[qi][0], bk[kg][0], sa, 0, 0, 0);
                sa = __builtin_amdgcn_mfma_f32_16x16x32_bf16(aq[qi][1], bk[kg][1], sa, 0, 0, 0);
                #pragma unroll
                for (int r = 0; r < 4; ++r) s[qi][kg][r] = sa[r];
            }

        #pragma unroll
        for (int qi = 0; qi < 2; ++qi)
            #pragma unroll
            for (int kg = 0; kg < 4; ++kg) {
                bool ok = (k0 + kg * 16 + fr) < Ntok;
                #pragma unroll
                for (int r = 0; r < 4; ++r) {
                    float p = ok ? __expf(fminf(s[qi][kg][r] * 0.125f, 80.f)) : 0.f;
                    lpart[qi][r] += p;
                    bf16 pb = __float2bfloat16(p);
                    Pw[(qi * 16 + fq * 4 + r) * PSTR + kg * 16 + fr] = *(unsigned short*)&pb;
                }
            }

        short8 ap[2][2];
        #pragma unroll
        for (int qi = 0; qi < 2; ++qi) {
            ap[qi][0] = *(const short8*)(Pw + (qi * 16 + fr) * PSTR + fq * 8);
            ap[qi][1] = *(const short8*)(Pw + (qi * 16 + fr) * PSTR + fq * 8 + 32);
        }

        #pragma unroll
        for (int qi = 0; qi < 2; ++qi)
            #pragma unroll
            for (int dg = 0; dg < 4; ++dg) {
                oacc[qi][dg] = __builtin_amdgcn_mfma_f32_16x16x32_bf16(
                    ap[qi][0], bv[dg][0], oacc[qi][dg], 0, 0, 0);
                oacc[qi][dg] = __builtin_amdgcn_mfma_f32_16x16x32_bf16(
                    ap[qi][1], bv[dg][1], oacc[qi][dg], 0, 0, 0);
            }
    }

    #pragma unroll
    for (int qi = 0; qi < 2; ++qi)
        #pragma unroll
        for (int r = 0; r < 4; ++r) {
            float l = lpart[qi][r];
            l += __shfl_xor(l, 1); l += __shfl_xor(l, 2);
            l += __shfl_xor(l, 4); l += __shfl_xor(l, 8);
            int t = t0 + w * 32 + qi * 16 + fq * 4 + r;
            if (t >= Ntok) continue;
            float inv = 1.0f / l;
            bf16* dst = O + ((size_t)b * SEQMAX + t) * EMBED + h * HD;
            #pragma unroll
            for (int dg = 0; dg < 4; ++dg)
                dst[dg * 16 + fr] = __float2bfloat16(oacc[qi][dg][r] * inv);
        }
}

// ---------------------------------------------------------------------------
__global__ __launch_bounds__(256)
void patch_gather(const void* __restrict__ img, bf16* __restrict__ Ap,
                  const int* __restrict__ flag)
{
    int f = *flag;
    int idx = blockIdx.x * 256 + threadIdx.x;
    if (idx >= NB * NPATCH * EMBED) return;
    int col = idx % EMBED;
    int row = idx / EMBED;
    int t = row % NPATCH, b = row / NPATCH;
    int c = col >> 8;
    int pr = (col >> 4) & 15;
    int pc = col & 15;
    int gr = t / GRID, gc = t % GRID;
    size_t off = ((size_t)(b * 3 + c) * IMGSZ + gr * PATCH + pr) * IMGSZ + gc * PATCH + pc;
    float v = f ? ((const float*)img)[off] : b2f(((const bf16*)img)[off]);
    Ap[idx] = __float2bfloat16(v);
}

__global__ __launch_bounds__(256)
void posadd_kernel(const float* __restrict__ PEO, const float* __restrict__ sp,
                   const float* __restrict__ ip, float* __restrict__ X, int imgIdx)
{
    int idx = blockIdx.x * 256 + threadIdx.x;
    if (idx >= NB * NPATCH * EMBED) return;
    int e = idx % EMBED;
    int row = idx / EMBED;
    int t = row % NPATCH, b = row / NPATCH;
    float pos = (e < 384) ? sp[t * 384 + e] : ip[imgIdx * 384 + (e - 384)];
    X[((size_t)b * SEQMAX + imgIdx * NPATCH + t) * EMBED + e] = PEO[idx] + pos;
}

__global__ __launch_bounds__(768)
void mean_kernel(const float* __restrict__ H, float* __restrict__ Mn)
{
    int b = blockIdx.x;
    int e = threadIdx.x;
    float s = 0.f;
    for (int t = 0; t < SEQMAX; ++t) s += H[((size_t)b * SEQMAX + t) * EMBED + e];
    Mn[b * EMBED + e] = s * (1.0f / SEQMAX);
}

__global__ __launch_bounds__(256)
void bcast_kernel(const float* __restrict__ P, void* __restrict__ out,
                  const int* __restrict__ flag)
{
    int f = *flag;
    int idx = blockIdx.x * 256 + threadIdx.x;
    if (idx >= NB * IMGSZ * IMGSZ) return;
    int c = idx % IMGSZ;
    int r = (idx / IMGSZ) % IMGSZ;
    int b = idx / (IMGSZ * IMGSZ);
    float v = P[b * 256 + (r & 15) * 16 + (c & 15)];
    if (f) ((float*)out)[idx] = v;
    else   ((bf16*)out)[idx] = __float2bfloat16(v);
}

// ---------------------------------------------------------------------------
extern "C" void kernel_launch(void* const* d_in, const int* in_sizes, int n_in,
                              void* d_out, int out_size, void* d_ws, size_t ws_size,
                              hipStream_t stream)
{
    (void)n_in; (void)out_size; (void)ws_size;
    const void* img[4] = {d_in[0], d_in[1], d_in[2], d_in[3]};

    float* ws = (float*)d_ws;
    int* flag = (int*)ws;

    detect_kernel<<<1, 256, 0, stream>>>((const unsigned short*)d_in[0], flag);

    const bool isBig[28] = {0,0,0,0, 1,0,0,0, 0,0,1,0, 1,0,0,0, 1,0,1,0, 0,0,0,0, 0,0,0,0};
    float* fBase = ws + 16;
    float* fPtr[28] = {};
    CvtF32 cf;
    int fCnt = 0, fBlk = 0;
    cf.blkOff[0] = 0;
    {
        float* p = fBase;
        for (int i = 4; i < 28; ++i) {
            if (isBig[i]) continue;
            fPtr[i] = p;
            int n = in_sizes[i];
            cf.src[fCnt] = d_in[i];
            cf.n[fCnt] = n;
            cf.dstOff[fCnt] = (int)(p - fBase);
            fBlk += (n + 1023) / 1024;
            cf.blkOff[fCnt + 1] = fBlk;
            p += n;
            ++fCnt;
        }
        fBase = ws + 16;
        fPtr[0] = p;   // sentinel: arena end
    }
    convert_f32_all<<<fBlk, 256, 0, stream>>>(cf, fBase, flag);

    bf16* bPtr[28] = {};
    bf16* bBase = (bf16*)fPtr[0];
    CvtB16 cb;
    int bCnt = 0, bBlk = 0;
    cb.blkOff[0] = 0;
    float* arenaEnd;
    {
        bf16* p = bBase;
        for (int i = 4; i < 28; ++i) {
            if (!isBig[i]) continue;
            bPtr[i] = p;
            int n = in_sizes[i];
            cb.src[bCnt] = d_in[i];
            cb.n[bCnt] = n;
            cb.dstOff[bCnt] = (int)(p - bBase);
            bBlk += (n + 1023) / 1024;
            cb.blkOff[bCnt + 1] = bBlk;
            p += n;
            ++bCnt;
        }
        size_t off = p - (bf16*)ws;
        off = (off + 7) & ~(size_t)7;
        arenaEnd = (float*)((bf16*)ws + off);
    }
    convert_b16_all<<<bBlk, 256, 0, stream>>>(cb, bBase, flag);

    const bf16* pe_w   = bPtr[4];
    const bf16* qkv_w  = bPtr[10];
    const bf16* proj_w = bPtr[12];
    const bf16* fc1_w  = bPtr[16];
    const bf16* fc2_w  = bPtr[18];
    const float* pe_b      = fPtr[5];
    const float* sp        = fPtr[6];
    const float* ip        = fPtr[7];
    const float* ln_attn_g = fPtr[8];
    const float* ln_attn_b = fPtr[9];
    const float* qkv_b     = fPtr[11];
    const float* proj_b    = fPtr[13];
    const float* ln1_g     = fPtr[14];
    const float* ln1_b     = fPtr[15];
    const float* fc1_b     = fPtr[17];
    const float* fc2_b     = fPtr[19];
    const float* ln2_g     = fPtr[20];
    const float* ln2_b     = fPtr[21];
    const float* final_g   = fPtr[22];
    const float* final_b   = fPtr[23];
    const float* head_w1   = fPtr[24];
    const float* head_b1   = fPtr[25];
    const float* head_w2   = fPtr[26];
    const float* head_b2   = fPtr[27];

    const size_t SEQ = (size_t)NB * SEQMAX * EMBED;          // 4,816,896
    const size_t HID_ELEMS = (size_t)NB * SEQMAX * HIDDEN;   // 19,267,584
    const size_t EMB_ELEMS = (size_t)NB * NPATCH * EMBED;    // 1,204,224
    float* X    = arenaEnd;
    float* H    = X + SEQ;
    float* O    = H + SEQ;
    float* PEO  = O + SEQ;
    float* MEAN = PEO + EMB_ELEMS;
    float* HH   = MEAN + NB * EMBED;
    float* PTCH = HH + NB * EMBED;
    bf16* Hb    = (bf16*)(PTCH + NB * 256 + 16);
    bf16* Ob    = Hb + SEQ;
    bf16* Gb    = Ob + SEQ;
    bf16* PEb   = Gb + HID_ELEMS;
    bf16* Qb    = PEb + EMB_ELEMS;
    bf16* Kb    = Qb + SEQ;
    bf16* Vb    = Kb + SEQ;
    bf16* VTb   = Vb + SEQ;

    const int nEmb = NB * NPATCH * EMBED;

    auto embed = [&](int i) {
        patch_gather<<<(nEmb + 255) / 256, 256, 0, stream>>>(img[i], PEb, flag);
        dim3 g(EMBED / 128, (NB * NPATCH + 63) / 64);
        mfma_gemm<64><<<g, 256, 0, stream>>>(PEb, pe_w + (size_t)i * EMBED * EMBED,
                                             pe_b + i * EMBED, nullptr, PEO, nullptr,
                                             nullptr, nullptr, nullptr,
                                             NB * NPATCH, EMBED, EMBED,
                                             NB * NPATCH, NB * NPATCH, 0);
        posadd_kernel<<<(nEmb + 255) / 256, 256, 0, stream>>>(PEO, sp, ip, X, i);
    };

    auto block = [&](int i, int Ntok) {
        int M = NB * Ntok;
        int gy128 = (M + 127) / 128;
        int gy64  = (M + 63) / 64;
        int nkt = (Ntok + 63) / 64;
        int nqt = (Ntok + 127) / 128;
        ln_bf16_kernel<<<M, 256, 0, stream>>>(X, Hb, ln_attn_g + i * EMBED, ln_attn_b + i * EMBED, Ntok);
        mfma_gemm<128><<<dim3(QKVD / 128, gy128), 256, 0, stream>>>(
            Hb, qkv_w + (size_t)i * QKVD * EMBED, qkv_b + i * QKVD, nullptr,
            nullptr, nullptr, Qb, Kb, Vb, M, QKVD, EMBED, Ntok, SEQMAX, 3);
        vtrans_kernel<<<dim3(NB * HEADS, nkt), 256, 0, stream>>>(Vb, VTb, Ntok);
        flash_mfma<<<dim3(NB * HEADS, nqt), 256, 0, stream>>>(Qb, Kb, VTb, Ob, Ntok);
        mfma_gemm<64><<<dim3(EMBED / 128, gy64), 256, 0, stream>>>(
            Ob, proj_w + (size_t)i * EMBED * EMBED, proj_b + i * EMBED, X,
            X, nullptr, nullptr, nullptr, nullptr, M, EMBED, EMBED, Ntok, SEQMAX, 1);
        ln_bf16_kernel<<<M, 256, 0, stream>>>(X, Hb, ln1_g + i * EMBED, ln1_b + i * EMBED, Ntok);
        mfma_gemm<128><<<dim3(HIDDEN / 128, gy128), 256, 0, stream>>>(
            Hb, fc1_w + (size_t)i * HIDDEN * EMBED, fc1_b + i * HIDDEN, nullptr,
            nullptr, Gb, nullptr, nullptr, nullptr, M, HIDDEN, EMBED, Ntok, SEQMAX, 2);
        mfma_gemm<64><<<dim3(EMBED / 128, gy64), 256, 0, stream>>>(
            Gb, fc2_w + (size_t)i * EMBED * HIDDEN, fc2_b + i * EMBED, X,
            O, nullptr, nullptr, nullptr, nullptr, M, EMBED, HIDDEN, Ntok, SEQMAX, 1);
        ln_kernel<<<M, 256, 0, stream>>>(O, X, ln2_g + i * EMBED, ln2_b + i * EMBED, Ntok);
    };

    embed(0);
    embed(1);
    block(0, 392);
    embed(2);
    block(1, 588);
    embed(3);
    block(2, 784);

    ln_kernel<<<NB * SEQMAX, 256, 0, stream>>>(X, H, final_g, final_b, SEQMAX);
    mean_kernel<<<NB, 768, 0, stream>>>(H, MEAN);
    gemm_kernel<<<dim3(EMBED / 64, 1), 256, 0, stream>>>(
        MEAN, head_w1, head_b1, nullptr, HH, NB, EMBED, EMBED, NB, NB, 1);
    gemm_kernel<<<dim3(256 / 64, 1), 256, 0, stream>>>(
        HH, head_w2, head_b2, nullptr, PTCH, NB, 256, EMBED, NB, NB, 0);
    bcast_kernel<<<(NB * IMGSZ * IMGSZ + 255) / 256, 256, 0, stream>>>(PTCH, d_out, flag);
}

// Round 12
// 1413.880 us; speedup vs baseline: 7.1367x; 1.0196x over previous
//
#include <hip/hip_runtime.h>
#include <hip/hip_bf16.h>
#include <math.h>

#define EMBED 768
#define QKVD 2304
#define HEADS 12
#define HD 64
#define HIDDEN 3072
#define NPATCH 196
#define SEQMAX 784
#define NB 8
#define IMGSZ 224
#define GRID 14
#define PATCH 16
#define PSTR 72
#define VROW 832

typedef __hip_bfloat16 bf16;
typedef __attribute__((ext_vector_type(8))) short short8;
typedef __attribute__((ext_vector_type(4))) float f32x4;

__device__ __forceinline__ float b2f(bf16 v) { return __bfloat162float(v); }
__device__ __forceinline__ float geluf(float x) {
    return 0.5f * x * (1.0f + erff(x * 0.70710678118654752f));
}

// async global->LDS, 16B per lane. LDS dest is wave-uniform base + lane*16.
__device__ __forceinline__ void async16(const bf16* g, bf16* l) {
    __builtin_amdgcn_global_load_lds(
        (const __attribute__((address_space(1))) unsigned int*)g,
        (__attribute__((address_space(3))) unsigned int*)l,
        16, 0, 0);
}

#define WAIT_VM0   0x0F70   // vmcnt(0)
#define WAIT_VM3   0x0F73   // vmcnt(3)
#define WAIT_VM4   0x0F74   // vmcnt(4)
#define WAIT_VM6   0x0F76   // vmcnt(6)
#define WAIT_VM8   0x0F78   // vmcnt(8)
#define WAIT_LGKM0 0xC07F   // lgkmcnt(0)

// ---------------------------------------------------------------------------
// Dtype detection (bf16 vs fp32 inputs).
// ---------------------------------------------------------------------------
__global__ __launch_bounds__(256)
void detect_kernel(const unsigned short* __restrict__ raw, int* __restrict__ flag)
{
    __shared__ int bad;
    if (threadIdx.x == 0) bad = 0;
    __syncthreads();
    for (int i = threadIdx.x; i < 8192; i += 256) {
        unsigned int u = (unsigned int)raw[i] << 16;
        float v = __uint_as_float(u);
        if (!(fabsf(v) <= 1e4f)) bad = 1;
    }
    __syncthreads();
    if (threadIdx.x == 0) *flag = bad;
}

// ---------------------------------------------------------------------------
// Fused converters.
// ---------------------------------------------------------------------------
struct CvtF32 {
    const void* src[19];
    int n[19];
    int dstOff[19];
    int blkOff[20];
};
__global__ __launch_bounds__(256)
void convert_f32_all(CvtF32 c, float* __restrict__ base, const int* __restrict__ flag)
{
    int f = *flag;
    int b = blockIdx.x;
    int i = 0;
    #pragma unroll
    for (int j = 0; j < 19; ++j) if (b >= c.blkOff[j + 1]) i = j + 1;
    int e = ((b - c.blkOff[i]) * 256 + threadIdx.x) * 4;
    if (e >= c.n[i]) return;
    float* dst = base + c.dstOff[i] + e;
    if (f) {
        *(float4*)dst = *(const float4*)((const float*)c.src[i] + e);
    } else {
        const bf16* s = (const bf16*)c.src[i] + e;
        dst[0] = b2f(s[0]); dst[1] = b2f(s[1]); dst[2] = b2f(s[2]); dst[3] = b2f(s[3]);
    }
}

struct CvtB16 {
    const void* src[5];
    int n[5];
    int dstOff[5];
    int blkOff[6];
};
__global__ __launch_bounds__(256)
void convert_b16_all(CvtB16 c, bf16* __restrict__ base, const int* __restrict__ flag)
{
    int f = *flag;
    int b = blockIdx.x;
    int i = 0;
    #pragma unroll
    for (int j = 0; j < 5; ++j) if (b >= c.blkOff[j + 1]) i = j + 1;
    int e = ((b - c.blkOff[i]) * 256 + threadIdx.x) * 4;
    if (e >= c.n[i]) return;
    bf16* dst = base + (size_t)c.dstOff[i] + e;
    if (f) {
        float4 v = *(const float4*)((const float*)c.src[i] + e);
        dst[0] = __float2bfloat16(v.x); dst[1] = __float2bfloat16(v.y);
        dst[2] = __float2bfloat16(v.z); dst[3] = __float2bfloat16(v.w);
    } else {
        *(uint2*)dst = *(const uint2*)((const bf16*)c.src[i] + e);
    }
}

// ---------------------------------------------------------------------------
// MFMA bf16 GEMM, templated M-tile (MT x 128), BK=32, 3-stage LDS ring with
// prefetch distance 2. MT=64 everywhere now: ~70 VGPR + 36 KB LDS -> ~4
// blocks/CU (16 waves) vs MT=128's 2 blocks — TLP was the binding constraint
// (round-10/11 evidence: fc2 at MT=64 outruns fc1 at MT=128 at equal FLOPs).
// mode: 0 = fp32 out; 1 = fp32 out + residual; 2 = bf16 out + gelu;
//       3 = qkv head-split -> bf16 Q/K/V all [bh][t][64].
// ---------------------------------------------------------------------------
template<int MT>
__global__ __launch_bounds__(256)
void mfma_gemm(const bf16* __restrict__ A, const bf16* __restrict__ W,
               const float* __restrict__ bias, const float* __restrict__ add,
               float* __restrict__ outF, bf16* __restrict__ outB,
               bf16* __restrict__ Qb, bf16* __restrict__ Kb, bf16* __restrict__ Vb,
               int M, int N, int K, int Ntok, int rowStride, int mode)
{
    constexpr int MI = MT / 32;            // m-frags per wave (4 or 2)
    __shared__ __align__(16) bf16 As[3][MT * 32];
    __shared__ __align__(16) bf16 Bs[3][128 * 32];
    int tid = threadIdx.x;
    int lane = tid & 63;
    int wave = tid >> 6;
    int wm = wave & 1, wn = wave >> 1;
    int m0 = blockIdx.y * MT, n0 = blockIdx.x * 128;

    int lr = lane >> 2;
    int lc = lane & 3;
    int ar0 = (MT / 4) * wave + lr;
    int ma0 = m0 + ar0; if (ma0 >= M) ma0 = M - 1;
    const bf16* aSrc0 = A + (size_t)((ma0 / Ntok) * rowStride + ma0 % Ntok) * K + lc * 8;
    const bf16* aSrc1 = nullptr;
    if constexpr (MT == 128) {
        int ma1 = m0 + ar0 + 16; if (ma1 >= M) ma1 = M - 1;
        aSrc1 = A + (size_t)((ma1 / Ntok) * rowStride + ma1 % Ntok) * K + lc * 8;
    }
    const bf16* bSrc0 = W + (size_t)(n0 + 32 * wave + lr) * K + lc * 8;
    const bf16* bSrc1 = W + (size_t)(n0 + 32 * wave + 16 + lr) * K + lc * 8;

    int fr = lane & 15;
    int fq = lane >> 4;
    int aOff = (wm * (MT / 2) + fr) * 32 + fq * 8;
    int bOff = (wn * 64 + fr) * 32 + fq * 8;

    f32x4 acc[MI][4] = {};

    auto stage = [&](int buf) {
        async16(aSrc0, As[buf] + ((MT / 4) * wave) * 32);
        if constexpr (MT == 128) {
            async16(aSrc1, As[buf] + ((MT / 4) * wave + 16) * 32);
        }
        async16(bSrc0, Bs[buf] + (32 * wave) * 32);
        async16(bSrc1, Bs[buf] + (32 * wave + 16) * 32);
        aSrc0 += 32; bSrc0 += 32; bSrc1 += 32;
        if constexpr (MT == 128) aSrc1 += 32;
    };

    int nIter = K >> 5;                 // >= 24 at all call sites
    stage(0);
    stage(1);

    int cur = 0;
    for (int it = 0; it < nIter; ++it) {
        __builtin_amdgcn_sched_barrier(0);
        __builtin_amdgcn_s_waitcnt(WAIT_LGKM0);   // my reads of ring[cur] (prev use) done
        __builtin_amdgcn_s_barrier();             // all waves done reading buffer being overwritten
        if (it + 2 < nIter) {
            int nxt = cur + 2; if (nxt >= 3) nxt -= 3;
            stage(nxt);                           // prefetch distance 2
            if constexpr (MT == 128) __builtin_amdgcn_s_waitcnt(WAIT_VM8);
            else                     __builtin_amdgcn_s_waitcnt(WAIT_VM6);
        } else if (it + 1 < nIter) {
            if constexpr (MT == 128) __builtin_amdgcn_s_waitcnt(WAIT_VM4);
            else                     __builtin_amdgcn_s_waitcnt(WAIT_VM3);
        } else {
            __builtin_amdgcn_s_waitcnt(WAIT_VM0);
        }
        __builtin_amdgcn_s_barrier();             // ring[cur] visible to all waves
        __builtin_amdgcn_sched_barrier(0);

        const bf16* aR = As[cur] + aOff;
        const bf16* bR = Bs[cur] + bOff;
        short8 af[MI], bfr[4];
        #pragma unroll
        for (int mi = 0; mi < MI; ++mi) af[mi] = *(const short8*)(aR + mi * 16 * 32);
        #pragma unroll
        for (int ni = 0; ni < 4; ++ni) bfr[ni] = *(const short8*)(bR + ni * 16 * 32);
        #pragma unroll
        for (int mi = 0; mi < MI; ++mi)
            #pragma unroll
            for (int ni = 0; ni < 4; ++ni)
                acc[mi][ni] = __builtin_amdgcn_mfma_f32_16x16x32_bf16(
                    af[mi], bfr[ni], acc[mi][ni], 0, 0, 0);
        if (++cur >= 3) cur = 0;
    }

    #pragma unroll
    for (int mi = 0; mi < MI; ++mi) {
        #pragma unroll
        for (int ni = 0; ni < 4; ++ni) {
            int n = n0 + wn * 64 + ni * 16 + fr;
            float bs = bias[n];
            #pragma unroll
            for (int r = 0; r < 4; ++r) {
                int m = m0 + wm * (MT / 2) + mi * 16 + fq * 4 + r;
                if (m >= M) continue;
                int bidx = m / Ntok, t = m - bidx * Ntok;
                size_t pr = (size_t)bidx * rowStride + t;
                float v = acc[mi][ni][r] + bs;
                if (mode == 0) {
                    outF[pr * N + n] = v;
                } else if (mode == 1) {
                    outF[pr * N + n] = v + add[pr * N + n];
                } else if (mode == 2) {
                    outB[pr * N + n] = __float2bfloat16(geluf(v));
                } else {
                    int which = n >= 1536 ? 2 : (n >= 768 ? 1 : 0);
                    int nn = n - which * 768;
                    int hh = nn >> 6, d = nn & 63;
                    bf16 bv = __float2bfloat16(v);
                    bf16* dst = which == 0 ? Qb : which == 1 ? Kb : Vb;
                    dst[((size_t)(bidx * HEADS + hh) * SEQMAX + t) * HD + d] = bv;
                }
            }
        }
    }
}

// ---------------------------------------------------------------------------
// Legacy fp32 GEMM (tiny head matmuls only).
// ---------------------------------------------------------------------------
__global__ __launch_bounds__(256)
void gemm_kernel(const float* __restrict__ A, const float* __restrict__ W,
                 const float* __restrict__ bias, const float* __restrict__ add,
                 float* __restrict__ C, int M, int N, int K,
                 int Ntok, int rowStride, int dogelu)
{
    __shared__ __align__(16) float As[16][68];
    __shared__ __align__(16) float Ws[16][68];
    int tid = threadIdx.x;
    int tx = tid & 15, ty = tid >> 4;
    int n0 = blockIdx.x * 64, m0 = blockIdx.y * 64;
    int lrow = tid >> 2;
    int lk   = (tid & 3) << 2;
    int am = m0 + lrow;
    bool aok = (am < M);
    const float* Arow = A;
    if (aok) {
        int pr = (am / Ntok) * rowStride + (am % Ntok);
        Arow = A + (size_t)pr * K;
    }
    int wn = n0 + lrow;
    const float* Wrow = (wn < N) ? (W + (size_t)wn * K) : nullptr;
    float acc[4][4] = {};
    for (int kk = 0; kk < K; kk += 16) {
        float4 av = make_float4(0.f, 0.f, 0.f, 0.f);
        if (aok) av = *(const float4*)(Arow + kk + lk);
        float4 wv = make_float4(0.f, 0.f, 0.f, 0.f);
        if (Wrow) wv = *(const float4*)(Wrow + kk + lk);
        __syncthreads();
        As[lk+0][lrow] = av.x; As[lk+1][lrow] = av.y;
        As[lk+2][lrow] = av.z; As[lk+3][lrow] = av.w;
        Ws[lk+0][lrow] = wv.x; Ws[lk+1][lrow] = wv.y;
        Ws[lk+2][lrow] = wv.z; Ws[lk+3][lrow] = wv.w;
        __syncthreads();
        #pragma unroll
        for (int k = 0; k < 16; ++k) {
            float4 a = *(const float4*)&As[k][ty << 2];
            float4 w = *(const float4*)&Ws[k][tx << 2];
            acc[0][0] += a.x*w.x; acc[0][1] += a.x*w.y; acc[0][2] += a.x*w.z; acc[0][3] += a.x*w.w;
            acc[1][0] += a.y*w.x; acc[1][1] += a.y*w.y; acc[1][2] += a.y*w.z; acc[1][3] += a.y*w.w;
            acc[2][0] += a.z*w.x; acc[2][1] += a.z*w.y; acc[2][2] += a.z*w.z; acc[2][3] += a.z*w.w;
            acc[3][0] += a.w*w.x; acc[3][1] += a.w*w.y; acc[3][2] += a.w*w.z; acc[3][3] += a.w*w.w;
        }
    }
    #pragma unroll
    for (int i = 0; i < 4; ++i) {
        int m = m0 + (ty << 2) + i;
        if (m >= M) continue;
        int pr = (m / Ntok) * rowStride + (m % Ntok);
        float* crow = C + (size_t)pr * N;
        const float* addrow = add ? (add + (size_t)pr * N) : nullptr;
        #pragma unroll
        for (int j = 0; j < 4; ++j) {
            int n = n0 + (tx << 2) + j;
            float v = acc[i][j] + bias[n];
            if (addrow) v += addrow[n];
            if (dogelu) v = geluf(v);
            crow[n] = v;
        }
    }
}

// ---------------------------------------------------------------------------
// LayerNorms.
// ---------------------------------------------------------------------------
__global__ __launch_bounds__(256)
void ln_bf16_kernel(const float* __restrict__ src, bf16* __restrict__ dst,
                    const float* __restrict__ g, const float* __restrict__ bta, int Ntok)
{
    __shared__ float red[256];
    int blk = blockIdx.x;
    int t = blk % Ntok, b = blk / Ntok;
    size_t row = ((size_t)b * SEQMAX + t) * EMBED;
    int tid = threadIdx.x;
    float v0 = src[row + tid], v1 = src[row + tid + 256], v2 = src[row + tid + 512];
    red[tid] = v0 + v1 + v2;
    __syncthreads();
    for (int off = 128; off; off >>= 1) { if (tid < off) red[tid] += red[tid + off]; __syncthreads(); }
    float mu = red[0] * (1.0f / EMBED);
    __syncthreads();
    float d0 = v0 - mu, d1 = v1 - mu, d2 = v2 - mu;
    red[tid] = d0*d0 + d1*d1 + d2*d2;
    __syncthreads();
    for (int off = 128; off; off >>= 1) { if (tid < off) red[tid] += red[tid + off]; __syncthreads(); }
    float rs = rsqrtf(red[0] * (1.0f / EMBED) + 1e-5f);
    dst[row + tid]       = __float2bfloat16(d0 * rs * g[tid]       + bta[tid]);
    dst[row + tid + 256] = __float2bfloat16(d1 * rs * g[tid + 256] + bta[tid + 256]);
    dst[row + tid + 512] = __float2bfloat16(d2 * rs * g[tid + 512] + bta[tid + 512]);
}

__global__ __launch_bounds__(256)
void ln_kernel(const float* __restrict__ src, float* __restrict__ dst,
               const float* __restrict__ g, const float* __restrict__ bta, int Ntok)
{
    __shared__ float red[256];
    int blk = blockIdx.x;
    int t = blk % Ntok, b = blk / Ntok;
    size_t row = ((size_t)b * SEQMAX + t) * EMBED;
    int tid = threadIdx.x;
    float v0 = src[row + tid], v1 = src[row + tid + 256], v2 = src[row + tid + 512];
    red[tid] = v0 + v1 + v2;
    __syncthreads();
    for (int off = 128; off; off >>= 1) { if (tid < off) red[tid] += red[tid + off]; __syncthreads(); }
    float mu = red[0] * (1.0f / EMBED);
    __syncthreads();
    float d0 = v0 - mu, d1 = v1 - mu, d2 = v2 - mu;
    red[tid] = d0*d0 + d1*d1 + d2*d2;
    __syncthreads();
    for (int off = 128; off; off >>= 1) { if (tid < off) red[tid] += red[tid + off]; __syncthreads(); }
    float rs = rsqrtf(red[0] * (1.0f / EMBED) + 1e-5f);
    dst[row + tid]       = d0 * rs * g[tid]       + bta[tid];
    dst[row + tid + 256] = d1 * rs * g[tid + 256] + bta[tid + 256];
    dst[row + tid + 512] = d2 * rs * g[tid + 512] + bta[tid + 512];
}

// ---------------------------------------------------------------------------
// V transpose: V [bh][t][64] -> VT [bh*64+d][VROW], zero-padded keys>=Ntok.
// ---------------------------------------------------------------------------
__global__ __launch_bounds__(256)
void vtrans_kernel(const bf16* __restrict__ Vh, bf16* __restrict__ VT, int Ntok)
{
    __shared__ unsigned short Lt[64 * 66];
    int bh = blockIdx.x;
    int k0 = blockIdx.y * 64;
    const bf16* Vb = Vh + (size_t)bh * SEQMAX * HD;
    int tid = threadIdx.x;
    #pragma unroll
    for (int pass = 0; pass < 8; ++pass) {
        int key_l = (tid >> 5) + pass * 8;
        int d2 = tid & 31;
        unsigned v = 0;
        if (k0 + key_l < Ntok)
            v = *(const unsigned*)(Vb + (size_t)(k0 + key_l) * HD + d2 * 2);
        *(unsigned*)&Lt[key_l * 66 + 2 * d2] = v;
    }
    __syncthreads();
    #pragma unroll
    for (int pass = 0; pass < 8; ++pass) {
        int d = (tid >> 5) + pass * 8;
        int kp = tid & 31;
        unsigned lo = Lt[(2 * kp) * 66 + d];
        unsigned hi = Lt[(2 * kp + 1) * 66 + d];
        *(unsigned*)(VT + ((size_t)bh * HD + d) * VROW + k0 + 2 * kp) = lo | (hi << 16);
    }
}

// ---------------------------------------------------------------------------
// MFMA flash attention v3. Block = (bh, 128-query tile); wave w owns 32 q-rows
// (two 16-row A-fragments). K loads then VT loads issued at top of each
// k-iteration so VT latency is hidden behind S + softmax + P roundtrip.
// Max-free softmax (small scores; clamp 80). P via per-wave LDS patch.
// ---------------------------------------------------------------------------
__global__ __launch_bounds__(256)
void flash_mfma(const bf16* __restrict__ Qh, const bf16* __restrict__ Kh,
                const bf16* __restrict__ VT, bf16* __restrict__ O, int Ntok)
{
    __shared__ __align__(16) unsigned short Plds[4][32 * PSTR];
    int bh = blockIdx.x;
    int b = bh / HEADS, h = bh % HEADS;
    int t0 = blockIdx.y * 128;
    int tid = threadIdx.x;
    int lane = tid & 63, w = tid >> 6;
    int fr = lane & 15, fq = lane >> 4;

    const bf16* Qb = Qh + (size_t)bh * SEQMAX * HD;
    const bf16* Kb = Kh + (size_t)bh * SEQMAX * HD;
    const bf16* Vt = VT + (size_t)bh * HD * VROW;

    short8 aq[2][2];
    #pragma unroll
    for (int qi = 0; qi < 2; ++qi) {
        int tq = t0 + w * 32 + qi * 16 + fr; if (tq >= Ntok) tq = Ntok - 1;
        aq[qi][0] = *(const short8*)(Qb + (size_t)tq * HD + fq * 8);
        aq[qi][1] = *(const short8*)(Qb + (size_t)tq * HD + fq * 8 + 32);
    }

    float lpart[2][4] = {};
    f32x4 oacc[2][4];
    #pragma unroll
    for (int qi = 0; qi < 2; ++qi)
        #pragma unroll
        for (int dg = 0; dg < 4; ++dg) oacc[qi][dg] = (f32x4){0.f, 0.f, 0.f, 0.f};

    unsigned short* Pw = Plds[w];

    for (int k0 = 0; k0 < Ntok; k0 += 64) {
        short8 bk[4][2];
        #pragma unroll
        for (int kg = 0; kg < 4; ++kg) {
            int key = k0 + kg * 16 + fr;
            int keyc = key < Ntok ? key : Ntok - 1;
            bk[kg][0] = *(const short8*)(Kb + (size_t)keyc * HD + fq * 8);
            bk[kg][1] = *(const short8*)(Kb + (size_t)keyc * HD + fq * 8 + 32);
        }
        short8 bv[4][2];
        #pragma unroll
        for (int dg = 0; dg < 4; ++dg) {
            int d = dg * 16 + fr;
            bv[dg][0] = *(const short8*)(Vt + (size_t)d * VROW + k0 + fq * 8);
            bv[dg][1] = *(const short8*)(Vt + (size_t)d * VROW + k0 + fq * 8 + 32);
        }

        float s[2][4][4];
        #pragma unroll
        for (int qi = 0; qi < 2; ++qi)
            #pragma unroll
            for (int kg = 0; kg < 4; ++kg) {
                f32x4 sa = (f32x4){0.f, 0.f, 0.f, 0.f};
                sa = __builtin_amdgcn_mfma_f32_16x16x32_bf16(aq[qi][0], bk[kg][0], sa, 0, 0, 0);
                sa = __builtin_amdgcn_mfma_f32_16x16x32_bf16(aq[qi][1], bk[kg][1], sa, 0, 0, 0);
                #pragma unroll
                for (int r = 0; r < 4; ++r) s[qi][kg][r] = sa[r];
            }

        #pragma unroll
        for (int qi = 0; qi < 2; ++qi)
            #pragma unroll
            for (int kg = 0; kg < 4; ++kg) {
                bool ok = (k0 + kg * 16 + fr) < Ntok;
                #pragma unroll
                for (int r = 0; r < 4; ++r) {
                    float p = ok ? __expf(fminf(s[qi][kg][r] * 0.125f, 80.f)) : 0.f;
                    lpart[qi][r] += p;
                    bf16 pb = __float2bfloat16(p);
                    Pw[(qi * 16 + fq * 4 + r) * PSTR + kg * 16 + fr] = *(unsigned short*)&pb;
                }
            }

        short8 ap[2][2];
        #pragma unroll
        for (int qi = 0; qi < 2; ++qi) {
            ap[qi][0] = *(const short8*)(Pw + (qi * 16 + fr) * PSTR + fq * 8);
            ap[qi][1] = *(const short8*)(Pw + (qi * 16 + fr) * PSTR + fq * 8 + 32);
        }

        #pragma unroll
        for (int qi = 0; qi < 2; ++qi)
            #pragma unroll
            for (int dg = 0; dg < 4; ++dg) {
                oacc[qi][dg] = __builtin_amdgcn_mfma_f32_16x16x32_bf16(
                    ap[qi][0], bv[dg][0], oacc[qi][dg], 0, 0, 0);
                oacc[qi][dg] = __builtin_amdgcn_mfma_f32_16x16x32_bf16(
                    ap[qi][1], bv[dg][1], oacc[qi][dg], 0, 0, 0);
            }
    }

    #pragma unroll
    for (int qi = 0; qi < 2; ++qi)
        #pragma unroll
        for (int r = 0; r < 4; ++r) {
            float l = lpart[qi][r];
            l += __shfl_xor(l, 1); l += __shfl_xor(l, 2);
            l += __shfl_xor(l, 4); l += __shfl_xor(l, 8);
            int t = t0 + w * 32 + qi * 16 + fq * 4 + r;
            if (t >= Ntok) continue;
            float inv = 1.0f / l;
            bf16* dst = O + ((size_t)b * SEQMAX + t) * EMBED + h * HD;
            #pragma unroll
            for (int dg = 0; dg < 4; ++dg)
                dst[dg * 16 + fr] = __float2bfloat16(oacc[qi][dg][r] * inv);
        }
}

// ---------------------------------------------------------------------------
__global__ __launch_bounds__(256)
void patch_gather(const void* __restrict__ img, bf16* __restrict__ Ap,
                  const int* __restrict__ flag)
{
    int f = *flag;
    int idx = blockIdx.x * 256 + threadIdx.x;
    if (idx >= NB * NPATCH * EMBED) return;
    int col = idx % EMBED;
    int row = idx / EMBED;
    int t = row % NPATCH, b = row / NPATCH;
    int c = col >> 8;
    int pr = (col >> 4) & 15;
    int pc = col & 15;
    int gr = t / GRID, gc = t % GRID;
    size_t off = ((size_t)(b * 3 + c) * IMGSZ + gr * PATCH + pr) * IMGSZ + gc * PATCH + pc;
    float v = f ? ((const float*)img)[off] : b2f(((const bf16*)img)[off]);
    Ap[idx] = __float2bfloat16(v);
}

__global__ __launch_bounds__(256)
void posadd_kernel(const float* __restrict__ PEO, const float* __restrict__ sp,
                   const float* __restrict__ ip, float* __restrict__ X, int imgIdx)
{
    int idx = blockIdx.x * 256 + threadIdx.x;
    if (idx >= NB * NPATCH * EMBED) return;
    int e = idx % EMBED;
    int row = idx / EMBED;
    int t = row % NPATCH, b = row / NPATCH;
    float pos = (e < 384) ? sp[t * 384 + e] : ip[imgIdx * 384 + (e - 384)];
    X[((size_t)b * SEQMAX + imgIdx * NPATCH + t) * EMBED + e] = PEO[idx] + pos;
}

__global__ __launch_bounds__(768)
void mean_kernel(const float* __restrict__ H, float* __restrict__ Mn)
{
    int b = blockIdx.x;
    int e = threadIdx.x;
    float s = 0.f;
    for (int t = 0; t < SEQMAX; ++t) s += H[((size_t)b * SEQMAX + t) * EMBED + e];
    Mn[b * EMBED + e] = s * (1.0f / SEQMAX);
}

__global__ __launch_bounds__(256)
void bcast_kernel(const float* __restrict__ P, void* __restrict__ out,
                  const int* __restrict__ flag)
{
    int f = *flag;
    int idx = blockIdx.x * 256 + threadIdx.x;
    if (idx >= NB * IMGSZ * IMGSZ) return;
    int c = idx % IMGSZ;
    int r = (idx / IMGSZ) % IMGSZ;
    int b = idx / (IMGSZ * IMGSZ);
    float v = P[b * 256 + (r & 15) * 16 + (c & 15)];
    if (f) ((float*)out)[idx] = v;
    else   ((bf16*)out)[idx] = __float2bfloat16(v);
}

// ---------------------------------------------------------------------------
extern "C" void kernel_launch(void* const* d_in, const int* in_sizes, int n_in,
                              void* d_out, int out_size, void* d_ws, size_t ws_size,
                              hipStream_t stream)
{
    (void)n_in; (void)out_size; (void)ws_size;
    const void* img[4] = {d_in[0], d_in[1], d_in[2], d_in[3]};

    float* ws = (float*)d_ws;
    int* flag = (int*)ws;

    detect_kernel<<<1, 256, 0, stream>>>((const unsigned short*)d_in[0], flag);

    const bool isBig[28] = {0,0,0,0, 1,0,0,0, 0,0,1,0, 1,0,0,0, 1,0,1,0, 0,0,0,0, 0,0,0,0};
    float* fBase = ws + 16;
    float* fPtr[28] = {};
    CvtF32 cf;
    int fCnt = 0, fBlk = 0;
    cf.blkOff[0] = 0;
    {
        float* p = fBase;
        for (int i = 4; i < 28; ++i) {
            if (isBig[i]) continue;
            fPtr[i] = p;
            int n = in_sizes[i];
            cf.src[fCnt] = d_in[i];
            cf.n[fCnt] = n;
            cf.dstOff[fCnt] = (int)(p - fBase);
            fBlk += (n + 1023) / 1024;
            cf.blkOff[fCnt + 1] = fBlk;
            p += n;
            ++fCnt;
        }
        fBase = ws + 16;
        fPtr[0] = p;   // sentinel: arena end
    }
    convert_f32_all<<<fBlk, 256, 0, stream>>>(cf, fBase, flag);

    bf16* bPtr[28] = {};
    bf16* bBase = (bf16*)fPtr[0];
    CvtB16 cb;
    int bCnt = 0, bBlk = 0;
    cb.blkOff[0] = 0;
    float* arenaEnd;
    {
        bf16* p = bBase;
        for (int i = 4; i < 28; ++i) {
            if (!isBig[i]) continue;
            bPtr[i] = p;
            int n = in_sizes[i];
            cb.src[bCnt] = d_in[i];
            cb.n[bCnt] = n;
            cb.dstOff[bCnt] = (int)(p - bBase);
            bBlk += (n + 1023) / 1024;
            cb.blkOff[bCnt + 1] = bBlk;
            p += n;
            ++bCnt;
        }
        size_t off = p - (bf16*)ws;
        off = (off + 7) & ~(size_t)7;
        arenaEnd = (float*)((bf16*)ws + off);
    }
    convert_b16_all<<<bBlk, 256, 0, stream>>>(cb, bBase, flag);

    const bf16* pe_w   = bPtr[4];
    const bf16* qkv_w  = bPtr[10];
    const bf16* proj_w = bPtr[12];
    const bf16* fc1_w  = bPtr[16];
    const bf16* fc2_w  = bPtr[18];
    const float* pe_b      = fPtr[5];
    const float* sp        = fPtr[6];
    const float* ip        = fPtr[7];
    const float* ln_attn_g = fPtr[8];
    const float* ln_attn_b = fPtr[9];
    const float* qkv_b     = fPtr[11];
    const float* proj_b    = fPtr[13];
    const float* ln1_g     = fPtr[14];
    const float* ln1_b     = fPtr[15];
    const float* fc1_b     = fPtr[17];
    const float* fc2_b     = fPtr[19];
    const float* ln2_g     = fPtr[20];
    const float* ln2_b     = fPtr[21];
    const float* final_g   = fPtr[22];
    const float* final_b   = fPtr[23];
    const float* head_w1   = fPtr[24];
    const float* head_b1   = fPtr[25];
    const float* head_w2   = fPtr[26];
    const float* head_b2   = fPtr[27];

    const size_t SEQ = (size_t)NB * SEQMAX * EMBED;          // 4,816,896
    const size_t HID_ELEMS = (size_t)NB * SEQMAX * HIDDEN;   // 19,267,584
    const size_t EMB_ELEMS = (size_t)NB * NPATCH * EMBED;    // 1,204,224
    float* X    = arenaEnd;
    float* H    = X + SEQ;
    float* O    = H + SEQ;
    float* PEO  = O + SEQ;
    float* MEAN = PEO + EMB_ELEMS;
    float* HH   = MEAN + NB * EMBED;
    float* PTCH = HH + NB * EMBED;
    bf16* Hb    = (bf16*)(PTCH + NB * 256 + 16);
    bf16* Ob    = Hb + SEQ;
    bf16* Gb    = Ob + SEQ;
    bf16* PEb   = Gb + HID_ELEMS;
    bf16* Qb    = PEb + EMB_ELEMS;
    bf16* Kb    = Qb + SEQ;
    bf16* Vb    = Kb + SEQ;
    bf16* VTb   = Vb + SEQ;

    const int nEmb = NB * NPATCH * EMBED;

    auto embed = [&](int i) {
        patch_gather<<<(nEmb + 255) / 256, 256, 0, stream>>>(img[i], PEb, flag);
        dim3 g(EMBED / 128, (NB * NPATCH + 63) / 64);
        mfma_gemm<64><<<g, 256, 0, stream>>>(PEb, pe_w + (size_t)i * EMBED * EMBED,
                                             pe_b + i * EMBED, nullptr, PEO, nullptr,
                                             nullptr, nullptr, nullptr,
                                             NB * NPATCH, EMBED, EMBED,
                                             NB * NPATCH, NB * NPATCH, 0);
        posadd_kernel<<<(nEmb + 255) / 256, 256, 0, stream>>>(PEO, sp, ip, X, i);
    };

    auto block = [&](int i, int Ntok) {
        int M = NB * Ntok;
        int gy64  = (M + 63) / 64;
        int nkt = (Ntok + 63) / 64;
        int nqt = (Ntok + 127) / 128;
        ln_bf16_kernel<<<M, 256, 0, stream>>>(X, Hb, ln_attn_g + i * EMBED, ln_attn_b + i * EMBED, Ntok);
        mfma_gemm<64><<<dim3(QKVD / 128, gy64), 256, 0, stream>>>(
            Hb, qkv_w + (size_t)i * QKVD * EMBED, qkv_b + i * QKVD, nullptr,
            nullptr, nullptr, Qb, Kb, Vb, M, QKVD, EMBED, Ntok, SEQMAX, 3);
        vtrans_kernel<<<dim3(NB * HEADS, nkt), 256, 0, stream>>>(Vb, VTb, Ntok);
        flash_mfma<<<dim3(NB * HEADS, nqt), 256, 0, stream>>>(Qb, Kb, VTb, Ob, Ntok);
        mfma_gemm<64><<<dim3(EMBED / 128, gy64), 256, 0, stream>>>(
            Ob, proj_w + (size_t)i * EMBED * EMBED, proj_b + i * EMBED, X,
            X, nullptr, nullptr, nullptr, nullptr, M, EMBED, EMBED, Ntok, SEQMAX, 1);
        ln_bf16_kernel<<<M, 256, 0, stream>>>(X, Hb, ln1_g + i * EMBED, ln1_b + i * EMBED, Ntok);
        mfma_gemm<64><<<dim3(HIDDEN / 128, gy64), 256, 0, stream>>>(
            Hb, fc1_w + (size_t)i * HIDDEN * EMBED, fc1_b + i * HIDDEN, nullptr,
            nullptr, Gb, nullptr, nullptr, nullptr, M, HIDDEN, EMBED, Ntok, SEQMAX, 2);
        mfma_gemm<64><<<dim3(EMBED / 128, gy64), 256, 0, stream>>>(
            Gb, fc2_w + (size_t)i * EMBED * HIDDEN, fc2_b + i * EMBED, X,
            O, nullptr, nullptr, nullptr, nullptr, M, EMBED, HIDDEN, Ntok, SEQMAX, 1);
        ln_kernel<<<M, 256, 0, stream>>>(O, X, ln2_g + i * EMBED, ln2_b + i * EMBED, Ntok);
    };

    embed(0);
    embed(1);
    block(0, 392);
    embed(2);
    block(1, 588);
    embed(3);
    block(2, 784);

    ln_kernel<<<NB * SEQMAX, 256, 0, stream>>>(X, H, final_g, final_b, SEQMAX);
    mean_kernel<<<NB, 768, 0, stream>>>(H, MEAN);
    gemm_kernel<<<dim3(EMBED / 64, 1), 256, 0, stream>>>(
        MEAN, head_w1, head_b1, nullptr, HH, NB, EMBED, EMBED, NB, NB, 1);
    gemm_kernel<<<dim3(256 / 64, 1), 256, 0, stream>>>(
        HH, head_w2, head_b2, nullptr, PTCH, NB, 256, EMBED, NB, NB, 0);
    bcast_kernel<<<(NB * IMGSZ * IMGSZ + 255) / 256, 256, 0, stream>>>(PTCH, d_out, flag);
}